// Round 8
// baseline (1167.097 us; speedup 1.0000x reference)
//
#include <hip/hip_runtime.h>
#include <math.h>

static constexpr int Bn  = 64;    // batch
static constexpr int Cc  = 192;   // channels
static constexpr int Nn  = 784;   // H*W
static constexpr int C2c = 384;   // 2C
static constexpr int Kk  = 9;     // knn K

// ===========================================================================
// INDEX PATH — np-f32 bit-exact where values matter (fc1, norm, refine).
// Fast filter (dist_gemm + select16) only proposes candidates; refine_np
// re-ranks them with bit-exact np arithmetic.
// ===========================================================================

// fc1_np: xt[b,o,n] = BN1( einsum_naive + bias ), numpy-f32-exact (no FMA,
// ascending-c accumulation). BIT-CRITICAL — do not alter arithmetic.
__global__ __launch_bounds__(256) void fc1_np(
    const float* __restrict__ x, const float* __restrict__ w,
    const float* __restrict__ bias,
    const float* __restrict__ gg, const float* __restrict__ bb_,
    const float* __restrict__ mm, const float* __restrict__ vv,
    float* __restrict__ xt)
{
    __shared__ float As[16][64];
    __shared__ float Bs[16][64];
    const int b   = blockIdx.z;
    const int n0  = blockIdx.x * 64;
    const int o0  = blockIdx.y * 64;
    const int tid = threadIdx.x;
    const int tx = tid & 15, ty = tid >> 4;
    const int lo = tid & 63, lk4 = tid >> 6;
    const int ln4 = tid & 15, lbk = tid >> 4;
    const float* xb = x + (size_t)b * Cc * Nn;

    float acc[4][4];
#pragma unroll
    for (int i = 0; i < 4; ++i)
#pragma unroll
        for (int j = 0; j < 4; ++j) acc[i][j] = 0.f;

    for (int kt = 0; kt < 12; ++kt) {               // c ascending: kt*16 + kk
        const int k0 = kt * 16;
        float4 av = *reinterpret_cast<const float4*>(&w[(size_t)(o0 + lo) * 192 + k0 + lk4 * 4]);
        As[lk4*4+0][lo] = av.x;
        As[lk4*4+1][lo] = av.y;
        As[lk4*4+2][lo] = av.z;
        As[lk4*4+3][lo] = av.w;
        const int n = n0 + ln4 * 4;
        float4 bv = make_float4(0.f, 0.f, 0.f, 0.f);
        if (n < Nn) bv = *reinterpret_cast<const float4*>(&xb[(size_t)(k0 + lbk) * Nn + n]);
        *reinterpret_cast<float4*>(&Bs[lbk][ln4*4]) = bv;
        __syncthreads();
#pragma unroll
        for (int kk = 0; kk < 16; ++kk) {
            float ar[4], br[4];
#pragma unroll
            for (int i = 0; i < 4; ++i) ar[i] = As[kk][ty*4+i];
#pragma unroll
            for (int j = 0; j < 4; ++j) br[j] = Bs[kk][tx*4+j];
#pragma unroll
            for (int i = 0; i < 4; ++i)
#pragma unroll
                for (int j = 0; j < 4; ++j)
                    acc[i][j] = __fadd_rn(acc[i][j], __fmul_rn(ar[i], br[j]));
        }
        __syncthreads();
    }
    const int n = n0 + tx * 4;
    if (n < Nn) {
#pragma unroll
        for (int i = 0; i < 4; ++i) {
            const int o = o0 + ty * 4 + i;
            const float e  = __fadd_rn(vv[o], 1e-5f);
            const float r1 = __fsqrt_rn(e);
            const float rr = __fdiv_rn(1.f, r1);
            const float s  = __fmul_rn(gg[o], rr);
#pragma unroll
            for (int j = 0; j < 4; ++j) {
                const float h = __fadd_rn(acc[i][j], bias[o]);
                const float t = __fsub_rn(h, mm[o]);
                const float u = __fmul_rn(t, s);
                xt[((size_t)b * Cc + o) * Nn + n + j] = __fadd_rn(u, bb_[o]);
            }
        }
    }
}

// norm_np: numpy-exact. BIT-CRITICAL values. Writes xn (col-major, for the
// filter GEMM) and xnT (row-major [b][n][c], for refine's contiguous reads).
__global__ __launch_bounds__(256) void norm_np(
    const float* __restrict__ xt, float* __restrict__ xn,
    float* __restrict__ xnT, float* __restrict__ sq)
{
    const int idx = blockIdx.x * 256 + threadIdx.x;
    if (idx >= Bn * Nn) return;
    const int n = idx % Nn;
    const int b = idx / Nn;
    const float* p = xt + (size_t)b * Cc * Nn + n;

    float acc = 0.f;
    for (int c = 0; c < Cc; ++c) {
        const float v = p[(size_t)c * Nn];
        acc = __fadd_rn(acc, __fmul_rn(v, v));
    }
    float nrm = __fsqrt_rn(acc);
    nrm = fmaxf(nrm, 1e-12f);

    float* q  = xn  + (size_t)b * Cc * Nn + n;
    float* qt = xnT + ((size_t)b * Nn + n) * Cc;
    for (int c = 0; c < Cc; ++c) {
        const float v = __fdiv_rn(p[(size_t)c * Nn], nrm);
        q[(size_t)c * Nn] = v;
        qt[c] = v;
    }

    float sblk[2];
#pragma unroll
    for (int blk = 0; blk < 2; ++blk) {
        const int base = blk * 96;
        float r[8];
#pragma unroll
        for (int j = 0; j < 8; ++j) {
            const float xv = __fdiv_rn(p[(size_t)(base + j) * Nn], nrm);
            r[j] = __fmul_rn(xv, xv);
        }
        for (int i = 8; i < 96; i += 8) {
#pragma unroll
            for (int j = 0; j < 8; ++j) {
                const float xv = __fdiv_rn(p[(size_t)(base + i + j) * Nn], nrm);
                r[j] = __fadd_rn(r[j], __fmul_rn(xv, xv));
            }
        }
        sblk[blk] = __fadd_rn(__fadd_rn(__fadd_rn(r[0], r[1]), __fadd_rn(r[2], r[3])),
                              __fadd_rn(__fadd_rn(r[4], r[5]), __fadd_rn(r[6], r[7])));
    }
    sq[idx] = __fadd_rn(sblk[0], sblk[1]);
}

// dist_gemm: FAST filter GEMM only — dist[b8][r][m] = -dot(xn_r, xn_m).
// One 64x64 tile per block, fmaf inner loop, register->global write.
__global__ __launch_bounds__(256) void dist_gemm(
    const float* __restrict__ xn, float* __restrict__ dist, int bchunk)
{
    __shared__ float As[16][64];
    __shared__ float Bs[16][64];
    const int bt = blockIdx.x;             // 0..168
    const int rt = bt / 13, mt = bt % 13;
    const int bc = blockIdx.y;             // 0..7
    const int b  = bchunk * 8 + bc;
    const int r0 = rt * 64, m0 = mt * 64;
    const int tid = threadIdx.x;
    const int tx = tid & 15, ty = tid >> 4;
    const int lo = tid & 63, lk4 = tid >> 6;
    const float* xb = xn + (size_t)b * Cc * Nn;

    float acc[4][4];
#pragma unroll
    for (int i = 0; i < 4; ++i)
#pragma unroll
        for (int j = 0; j < 4; ++j) acc[i][j] = 0.f;

    for (int kt = 0; kt < 12; ++kt) {
        const int k0 = kt * 16;
        const int r = r0 + lo, m = m0 + lo;
#pragma unroll
        for (int j = 0; j < 4; ++j) {
            const int kc = k0 + lk4 * 4 + j;
            As[lk4*4+j][lo] = (r < Nn) ? xb[(size_t)kc * Nn + r] : 0.f;
            Bs[lk4*4+j][lo] = (m < Nn) ? xb[(size_t)kc * Nn + m] : 0.f;
        }
        __syncthreads();
#pragma unroll
        for (int kk = 0; kk < 16; ++kk) {
            float4 a  = *reinterpret_cast<const float4*>(&As[kk][ty*4]);
            float4 bq = *reinterpret_cast<const float4*>(&Bs[kk][tx*4]);
            float ar[4] = {a.x, a.y, a.z, a.w};
            float br[4] = {bq.x, bq.y, bq.z, bq.w};
#pragma unroll
            for (int i = 0; i < 4; ++i)
#pragma unroll
                for (int j = 0; j < 4; ++j)
                    acc[i][j] = fmaf(ar[i], br[j], acc[i][j]);
        }
        __syncthreads();
    }
    float* db = dist + (size_t)bc * Nn * Nn;
    const int m = m0 + tx * 4;
    if (m + 3 < Nn) {
#pragma unroll
        for (int i = 0; i < 4; ++i) {
            const int r = r0 + ty * 4 + i;
            if (r < Nn) {
                float4 o = make_float4(-acc[i][0], -acc[i][1], -acc[i][2], -acc[i][3]);
                *reinterpret_cast<float4*>(&db[(size_t)r * Nn + m]) = o;
            }
        }
    }
}

// select16: one wave per row; 784 dists in 13 regs/lane; 16x argmin-extract
// via shfl_xor reduce (value, then lower-index tie-break). No LDS, no scratch.
__global__ __launch_bounds__(256) void select16(
    const float* __restrict__ dist, int* __restrict__ cand, int bchunk)
{
    const int wid = blockIdx.x * 4 + (threadIdx.x >> 6);   // wave id in chunk
    const int L   = threadIdx.x & 63;
    const int r   = wid % Nn;
    const int bc  = wid / Nn;
    const int b   = bchunk * 8 + bc;
    const float* drow = dist + ((size_t)bc * Nn + r) * Nn;

    float v[13];
#pragma unroll
    for (int s = 0; s < 12; ++s) v[s] = drow[s * 64 + L];
    v[12] = (L < 16) ? drow[768 + L] : INFINITY;

    float mv = v[0]; int ms = 0;
#pragma unroll
    for (int s = 1; s < 13; ++s)
        if (v[s] < mv) { mv = v[s]; ms = s; }

    int out[16];
#pragma unroll
    for (int k = 0; k < 16; ++k) {
        float gv = mv; int gi = ms * 64 + L;
#pragma unroll
        for (int off = 1; off < 64; off <<= 1) {
            const float ov = __shfl_xor(gv, off, 64);
            const int   oi = __shfl_xor(gi, off, 64);
            if (ov < gv || (ov == gv && oi < gi)) { gv = ov; gi = oi; }
        }
        out[k] = gi;
        const int ol = gi & 63, os = gi >> 6;
        if (L == ol) {
#pragma unroll
            for (int s = 0; s < 13; ++s) if (s == os) v[s] = INFINITY;
            mv = v[0]; ms = 0;
#pragma unroll
            for (int s = 1; s < 13; ++s)
                if (v[s] < mv) { mv = v[s]; ms = s; }
        }
    }
    if (L == 0) {
        int* op = cand + ((size_t)b * Nn + r) * 16;
#pragma unroll
        for (int k = 0; k < 16; ++k) op[k] = out[k];
    }
}

// refine_np: EXACT np-f32 re-ranking of the 16 candidates per row, reading
// the row-major xnT copy (contiguous 768B per vector, float4 loads; the 4
// lanes of each float4 are accumulated SEQUENTIALLY in ascending c — the
// rounding chain is identical to numpy's scalar loop). BIT-CRITICAL.
__global__ __launch_bounds__(256) void refine_np(
    const float* __restrict__ xnT, const float* __restrict__ sq,
    const int* __restrict__ cand, int* __restrict__ nnidx)
{
    __shared__ float Dd[16][16];
    __shared__ int   Dm[16][16];
    const int b  = blockIdx.y;
    const int rl = threadIdx.x >> 4;
    const int k  = threadIdx.x & 15;
    const int r  = blockIdx.x * 16 + rl;
    const float* sqb = sq + (size_t)b * Nn;

    const int m = cand[((size_t)b * Nn + r) * 16 + k];
    const float4* pr = reinterpret_cast<const float4*>(xnT + ((size_t)b * Nn + r) * Cc);
    const float4* pm = reinterpret_cast<const float4*>(xnT + ((size_t)b * Nn + m) * Cc);
    float dot = 0.f;
#pragma unroll
    for (int c4 = 0; c4 < Cc / 4; ++c4) {
        const float4 a = pr[c4];
        const float4 q = pm[c4];
        dot = __fadd_rn(dot, __fmul_rn(a.x, q.x));
        dot = __fadd_rn(dot, __fmul_rn(a.y, q.y));
        dot = __fadd_rn(dot, __fmul_rn(a.z, q.z));
        dot = __fadd_rn(dot, __fmul_rn(a.w, q.w));
    }
    const float t1 = __fmul_rn(2.f, dot);
    const float t2 = __fsub_rn(sqb[r], t1);
    Dd[rl][k] = __fadd_rn(t2, sqb[m]);
    Dm[rl][k] = m;
    __syncthreads();

    if (k == 0) {
        float dl[16]; int il[16];
#pragma unroll
        for (int j = 0; j < 16; ++j) { dl[j] = Dd[rl][j]; il[j] = Dm[rl][j]; }
        int* op = nnidx + ((size_t)b * Nn + r) * Kk;
        for (int kk = 0; kk < Kk; ++kk) {
            int best = kk;
            for (int j = kk + 1; j < 16; ++j)
                if (dl[j] < dl[best] || (dl[j] == dl[best] && il[j] < il[best])) best = j;
            float td = dl[kk]; dl[kk] = dl[best]; dl[best] = td;
            int ti = il[kk]; il[kk] = il[best]; il[best] = ti;
            op[kk] = il[kk];
        }
    }
}

// ===========================================================================
// VALUE PATH — fast f32 (fmaf ok; error ~1e-5 << threshold 0.14)
// ===========================================================================

__global__ __launch_bounds__(256) void mr_naive(
    const float* __restrict__ xt, const int* __restrict__ nnidx,
    float* __restrict__ st)
{
    const long long idx = (long long)blockIdx.x * 256 + threadIdx.x;
    if (idx >= (long long)Bn * Cc * Nn) return;
    const int n = (int)(idx % Nn);
    const int c = (int)((idx / Nn) % Cc);
    const int b = (int)(idx / ((long long)Cc * Nn));
    const float* row = xt + ((size_t)b * Cc + c) * Nn;
    const float ctr = row[n];
    const int* ip = nnidx + ((size_t)b * Nn + n) * Kk;
    float mx = -INFINITY;
    for (int k = 0; k < Kk; ++k) {
        const float v = __fsub_rn(row[ip[k]], ctr);
        if (v > mx) mx = v;
    }
    st[((size_t)b * C2c + 2 * c) * Nn + n]     = ctr;
    st[((size_t)b * C2c + 2 * c + 1) * Nn + n] = mx;
}

__global__ __launch_bounds__(256) void gconv_kernel(
    const float* __restrict__ st, const float* __restrict__ gw,
    const float* __restrict__ gb,
    const float* __restrict__ gg, const float* __restrict__ bb_,
    const float* __restrict__ mm, const float* __restrict__ vv,
    float* __restrict__ out)
{
    __shared__ float As[16][32];
    __shared__ float Bs[16][64];
    const int b   = blockIdx.z;
    const int n0  = blockIdx.x * 64;
    const int grp = blockIdx.y / 3;
    const int o0  = (blockIdx.y % 3) * 32;
    const int tid = threadIdx.x;
    const int tx = tid & 15, ty = tid >> 4;
    const int lo = tid & 31, lk2 = tid >> 5;
    const int ln4 = tid & 15, lbk = tid >> 4;
    const float* stb = st + (size_t)b * C2c * Nn + (size_t)grp * 96 * Nn;
    const float* wgp = gw + (size_t)grp * 96 * 96;

    float acc[2][4];
#pragma unroll
    for (int i = 0; i < 2; ++i)
#pragma unroll
        for (int j = 0; j < 4; ++j) acc[i][j] = 0.f;

    for (int kt = 0; kt < 6; ++kt) {
        const int k0 = kt * 16;
        float2 av = *reinterpret_cast<const float2*>(&wgp[(size_t)(o0 + lo) * 96 + k0 + lk2 * 2]);
        As[lk2*2+0][lo] = av.x;
        As[lk2*2+1][lo] = av.y;
        const int n = n0 + ln4 * 4;
        float4 bv = make_float4(0.f, 0.f, 0.f, 0.f);
        if (n < Nn) bv = *reinterpret_cast<const float4*>(&stb[(size_t)(k0 + lbk) * Nn + n]);
        *reinterpret_cast<float4*>(&Bs[lbk][ln4*4]) = bv;
        __syncthreads();
#pragma unroll
        for (int kk = 0; kk < 16; ++kk) {
            float2 a  = *reinterpret_cast<const float2*>(&As[kk][ty*2]);
            float4 bq = *reinterpret_cast<const float4*>(&Bs[kk][tx*4]);
            float ar[2] = {a.x, a.y};
            float br[4] = {bq.x, bq.y, bq.z, bq.w};
#pragma unroll
            for (int i = 0; i < 2; ++i)
#pragma unroll
                for (int j = 0; j < 4; ++j)
                    acc[i][j] = fmaf(ar[i], br[j], acc[i][j]);
        }
        __syncthreads();
    }
    const int n = n0 + tx * 4;
    if (n < Nn) {
#pragma unroll
        for (int i = 0; i < 2; ++i) {
            const int oc = grp * 96 + o0 + ty * 2 + i;
            const float s  = gg[oc] * rsqrtf(vv[oc] + 1e-5f);
            const float sh = (gb[oc] - mm[oc]) * s + bb_[oc];
            float r[4];
#pragma unroll
            for (int j = 0; j < 4; ++j) {
                float v = fmaf(acc[i][j], s, sh);
                r[j] = 0.5f * v * (1.f + erff(v * 0.70710678118654752f));
            }
            float4 rv = make_float4(r[0], r[1], r[2], r[3]);
            *reinterpret_cast<float4*>(&out[((size_t)b * C2c + oc) * Nn + n]) = rv;
        }
    }
}

__global__ __launch_bounds__(256) void fc2_kernel(
    const float* __restrict__ gin, const float* __restrict__ w,
    const float* __restrict__ bias,
    const float* __restrict__ gg, const float* __restrict__ bb_,
    const float* __restrict__ mm, const float* __restrict__ vv,
    const float* __restrict__ xres,
    float* __restrict__ out)
{
    __shared__ float As[16][64];
    __shared__ float Bs[16][64];
    const int b   = blockIdx.z;
    const int n0  = blockIdx.x * 64;
    const int o0  = blockIdx.y * 64;
    const int tid = threadIdx.x;
    const int tx = tid & 15, ty = tid >> 4;
    const int lo = tid & 63, lk4 = tid >> 6;
    const int ln4 = tid & 15, lbk = tid >> 4;
    const float* gbp = gin + (size_t)b * C2c * Nn;
    const float* xb  = xres + (size_t)b * Cc * Nn;

    float acc[4][4];
#pragma unroll
    for (int i = 0; i < 4; ++i)
#pragma unroll
        for (int j = 0; j < 4; ++j) acc[i][j] = 0.f;

    for (int kt = 0; kt < 24; ++kt) {
        const int k0 = kt * 16;
        float4 av = *reinterpret_cast<const float4*>(&w[(size_t)(o0 + lo) * 384 + k0 + lk4 * 4]);
        As[lk4*4+0][lo] = av.x;
        As[lk4*4+1][lo] = av.y;
        As[lk4*4+2][lo] = av.z;
        As[lk4*4+3][lo] = av.w;
        const int n = n0 + ln4 * 4;
        float4 bv = make_float4(0.f, 0.f, 0.f, 0.f);
        if (n < Nn) bv = *reinterpret_cast<const float4*>(&gbp[(size_t)(k0 + lbk) * Nn + n]);
        *reinterpret_cast<float4*>(&Bs[lbk][ln4*4]) = bv;
        __syncthreads();
#pragma unroll
        for (int kk = 0; kk < 16; ++kk) {
            float4 a  = *reinterpret_cast<const float4*>(&As[kk][ty*4]);
            float4 bq = *reinterpret_cast<const float4*>(&Bs[kk][tx*4]);
            float ar[4] = {a.x, a.y, a.z, a.w};
            float br[4] = {bq.x, bq.y, bq.z, bq.w};
#pragma unroll
            for (int i = 0; i < 4; ++i)
#pragma unroll
                for (int j = 0; j < 4; ++j)
                    acc[i][j] = fmaf(ar[i], br[j], acc[i][j]);
        }
        __syncthreads();
    }
    const int n = n0 + tx * 4;
    if (n < Nn) {
#pragma unroll
        for (int i = 0; i < 4; ++i) {
            const int o = o0 + ty * 4 + i;
            const float s  = gg[o] * rsqrtf(vv[o] + 1e-5f);
            const float sh = (bias[o] - mm[o]) * s + bb_[o];
            float4 xr = *reinterpret_cast<const float4*>(&xb[(size_t)o * Nn + n]);
            float4 r;
            r.x = fmaf(acc[i][0], s, sh) + xr.x;
            r.y = fmaf(acc[i][1], s, sh) + xr.y;
            r.z = fmaf(acc[i][2], s, sh) + xr.z;
            r.w = fmaf(acc[i][3], s, sh) + xr.w;
            *reinterpret_cast<float4*>(&out[((size_t)b * Cc + o) * Nn + n]) = r;
        }
    }
}

// ---------------------------------------------------------------------------
extern "C" void kernel_launch(void* const* d_in, const int* in_sizes, int n_in,
                              void* d_out, int out_size, void* d_ws, size_t ws_size,
                              hipStream_t stream)
{
    const float* x     = (const float*)d_in[0];
    const float* fc1_w = (const float*)d_in[1];
    const float* fc1_b = (const float*)d_in[2];
    const float* bn1_g = (const float*)d_in[3];
    const float* bn1_b = (const float*)d_in[4];
    const float* bn1_m = (const float*)d_in[5];
    const float* bn1_v = (const float*)d_in[6];
    const float* gc_w  = (const float*)d_in[7];
    const float* gc_b  = (const float*)d_in[8];
    const float* bn2_g = (const float*)d_in[9];
    const float* bn2_b = (const float*)d_in[10];
    const float* bn2_m = (const float*)d_in[11];
    const float* bn2_v = (const float*)d_in[12];
    const float* fc2_w = (const float*)d_in[13];
    const float* fc2_b = (const float*)d_in[14];
    const float* bn3_g = (const float*)d_in[15];
    const float* bn3_b = (const float*)d_in[16];
    const float* bn3_m = (const float*)d_in[17];
    const float* bn3_v = (const float*)d_in[18];

    float* out = (float*)d_out;                  // xt scratch, overwritten by fc2

    // workspace (max concurrent 156 MB, same as proven rounds):
    //   region A [0, 77.07M):
    //       dist8 (19.67M, chunked) | xnT (38.5M @ +19.67M)  — both die
    //       before mr -> st (full region, born at mr)
    //   region B [77.07, 154.14M): xn | sq | cand16 (die after refine) -> gbuf
    //   region C [154.14M, +1.8M): nnidx
    char* wsb = (char*)d_ws;
    const size_t regionBytes = (size_t)Bn * C2c * Nn * 4;   // 77,070,336
    const size_t distBytes   = (size_t)8 * Nn * Nn * 4;     // 19,668,992
    float* dist = (float*)wsb;
    float* xnT  = (float*)(wsb + distBytes);                       // 38,535,168 B
    float* st   = (float*)wsb;
    char*  g2   = wsb + regionBytes;
    float* xnb  = (float*)g2;                                      // 38,535,168 B
    float* sqb  = (float*)(g2 + (size_t)Bn * Cc * Nn * 4);         // 200,704 B
    int*   c16  = (int*)(g2 + (size_t)Bn * Cc * Nn * 4 + 200704);  // 3,211,264 B
    float* gbuf = (float*)g2;                                      // clobbers head (dead)
    int*   nni  = (int*)(wsb + 2 * regionBytes);

    const long long nBCN = (long long)Bn * Cc * Nn;
    const int nBN = Bn * Nn;

    dim3 blk(256);
    fc1_np<<<dim3(13, 3, Bn), blk, 0, stream>>>(
        x, fc1_w, fc1_b, bn1_g, bn1_b, bn1_m, bn1_v, out);
    norm_np<<<dim3((nBN + 255) / 256), blk, 0, stream>>>(out, xnb, xnT, sqb);
    for (int ch = 0; ch < 8; ++ch) {
        dist_gemm<<<dim3(169, 8), blk, 0, stream>>>(xnb, dist, ch);
        select16<<<dim3(8 * Nn / 4), blk, 0, stream>>>(dist, c16, ch);
    }
    refine_np<<<dim3(49, Bn), blk, 0, stream>>>(xnT, sqb, c16, nni);
    mr_naive<<<dim3((unsigned)((nBCN + 255) / 256)), blk, 0, stream>>>(out, nni, st);
    gconv_kernel<<<dim3(13, 12, Bn), blk, 0, stream>>>(
        st, gc_w, gc_b, bn2_g, bn2_b, bn2_m, bn2_v, gbuf);
    fc2_kernel<<<dim3(13, 3, Bn), blk, 0, stream>>>(
        gbuf, fc2_w, fc2_b, bn3_g, bn3_b, bn3_m, bn3_v, x, out);
}

// Round 9
// 1079.119 us; speedup vs baseline: 1.0815x; 1.0815x over previous
//
#include <hip/hip_runtime.h>
#include <math.h>

static constexpr int Bn  = 64;    // batch
static constexpr int Cc  = 192;   // channels
static constexpr int Nn  = 784;   // H*W
static constexpr int C2c = 384;   // 2C
static constexpr int Kk  = 9;     // knn K
#define GAP_DELTA 1e-4f

// ===========================================================================
// INDEX PATH — np-f32 bit-exact where values matter (fc1, norm, refine_amb).
// Fast filter (dist_gemm + select16) proposes candidates + fast dists;
// gap_route resolves clear rows; refine_amb re-ranks knife-edge rows exactly.
// ===========================================================================

// fc1_np: xt[b,o,n] = BN1( einsum_naive + bias ), numpy-f32-exact (no FMA,
// ascending-c accumulation). BIT-CRITICAL — do not alter arithmetic.
__global__ __launch_bounds__(256) void fc1_np(
    const float* __restrict__ x, const float* __restrict__ w,
    const float* __restrict__ bias,
    const float* __restrict__ gg, const float* __restrict__ bb_,
    const float* __restrict__ mm, const float* __restrict__ vv,
    float* __restrict__ xt)
{
    __shared__ float As[16][64];
    __shared__ float Bs[16][64];
    const int b   = blockIdx.z;
    const int n0  = blockIdx.x * 64;
    const int o0  = blockIdx.y * 64;
    const int tid = threadIdx.x;
    const int tx = tid & 15, ty = tid >> 4;
    const int lo = tid & 63, lk4 = tid >> 6;
    const int ln4 = tid & 15, lbk = tid >> 4;
    const float* xb = x + (size_t)b * Cc * Nn;

    float acc[4][4];
#pragma unroll
    for (int i = 0; i < 4; ++i)
#pragma unroll
        for (int j = 0; j < 4; ++j) acc[i][j] = 0.f;

    for (int kt = 0; kt < 12; ++kt) {               // c ascending: kt*16 + kk
        const int k0 = kt * 16;
        float4 av = *reinterpret_cast<const float4*>(&w[(size_t)(o0 + lo) * 192 + k0 + lk4 * 4]);
        As[lk4*4+0][lo] = av.x;
        As[lk4*4+1][lo] = av.y;
        As[lk4*4+2][lo] = av.z;
        As[lk4*4+3][lo] = av.w;
        const int n = n0 + ln4 * 4;
        float4 bv = make_float4(0.f, 0.f, 0.f, 0.f);
        if (n < Nn) bv = *reinterpret_cast<const float4*>(&xb[(size_t)(k0 + lbk) * Nn + n]);
        *reinterpret_cast<float4*>(&Bs[lbk][ln4*4]) = bv;
        __syncthreads();
#pragma unroll
        for (int kk = 0; kk < 16; ++kk) {
            float ar[4], br[4];
#pragma unroll
            for (int i = 0; i < 4; ++i) ar[i] = As[kk][ty*4+i];
#pragma unroll
            for (int j = 0; j < 4; ++j) br[j] = Bs[kk][tx*4+j];
#pragma unroll
            for (int i = 0; i < 4; ++i)
#pragma unroll
                for (int j = 0; j < 4; ++j)
                    acc[i][j] = __fadd_rn(acc[i][j], __fmul_rn(ar[i], br[j]));
        }
        __syncthreads();
    }
    const int n = n0 + tx * 4;
    if (n < Nn) {
#pragma unroll
        for (int i = 0; i < 4; ++i) {
            const int o = o0 + ty * 4 + i;
            const float e  = __fadd_rn(vv[o], 1e-5f);
            const float r1 = __fsqrt_rn(e);
            const float rr = __fdiv_rn(1.f, r1);
            const float s  = __fmul_rn(gg[o], rr);
#pragma unroll
            for (int j = 0; j < 4; ++j) {
                const float h = __fadd_rn(acc[i][j], bias[o]);
                const float t = __fsub_rn(h, mm[o]);
                const float u = __fmul_rn(t, s);
                xt[((size_t)b * Cc + o) * Nn + n + j] = __fadd_rn(u, bb_[o]);
            }
        }
    }
}

// norm_np: numpy-exact. BIT-CRITICAL.
__global__ __launch_bounds__(256) void norm_np(
    const float* __restrict__ xt, float* __restrict__ xn, float* __restrict__ sq)
{
    const int idx = blockIdx.x * 256 + threadIdx.x;
    if (idx >= Bn * Nn) return;
    const int n = idx % Nn;
    const int b = idx / Nn;
    const float* p = xt + (size_t)b * Cc * Nn + n;

    float acc = 0.f;
    for (int c = 0; c < Cc; ++c) {
        const float v = p[(size_t)c * Nn];
        acc = __fadd_rn(acc, __fmul_rn(v, v));
    }
    float nrm = __fsqrt_rn(acc);
    nrm = fmaxf(nrm, 1e-12f);

    float* q = xn + (size_t)b * Cc * Nn + n;
    for (int c = 0; c < Cc; ++c)
        q[(size_t)c * Nn] = __fdiv_rn(p[(size_t)c * Nn], nrm);

    float sblk[2];
#pragma unroll
    for (int blk = 0; blk < 2; ++blk) {
        const int base = blk * 96;
        float r[8];
#pragma unroll
        for (int j = 0; j < 8; ++j) {
            const float xv = __fdiv_rn(p[(size_t)(base + j) * Nn], nrm);
            r[j] = __fmul_rn(xv, xv);
        }
        for (int i = 8; i < 96; i += 8) {
#pragma unroll
            for (int j = 0; j < 8; ++j) {
                const float xv = __fdiv_rn(p[(size_t)(base + i + j) * Nn], nrm);
                r[j] = __fadd_rn(r[j], __fmul_rn(xv, xv));
            }
        }
        sblk[blk] = __fadd_rn(__fadd_rn(__fadd_rn(r[0], r[1]), __fadd_rn(r[2], r[3])),
                              __fadd_rn(__fadd_rn(r[4], r[5]), __fadd_rn(r[6], r[7])));
    }
    sq[idx] = __fadd_rn(sblk[0], sblk[1]);
}

// dist_gemm: FAST filter GEMM only — dist[b8][r][m] = -dot(xn_r, xn_m).
__global__ __launch_bounds__(256) void dist_gemm(
    const float* __restrict__ xn, float* __restrict__ dist, int bchunk)
{
    __shared__ float As[16][64];
    __shared__ float Bs[16][64];
    const int bt = blockIdx.x;             // 0..168
    const int rt = bt / 13, mt = bt % 13;
    const int bc = blockIdx.y;             // 0..7
    const int b  = bchunk * 8 + bc;
    const int r0 = rt * 64, m0 = mt * 64;
    const int tid = threadIdx.x;
    const int tx = tid & 15, ty = tid >> 4;
    const int lo = tid & 63, lk4 = tid >> 6;
    const float* xb = xn + (size_t)b * Cc * Nn;

    float acc[4][4];
#pragma unroll
    for (int i = 0; i < 4; ++i)
#pragma unroll
        for (int j = 0; j < 4; ++j) acc[i][j] = 0.f;

    for (int kt = 0; kt < 12; ++kt) {
        const int k0 = kt * 16;
        const int r = r0 + lo, m = m0 + lo;
#pragma unroll
        for (int j = 0; j < 4; ++j) {
            const int kc = k0 + lk4 * 4 + j;
            As[lk4*4+j][lo] = (r < Nn) ? xb[(size_t)kc * Nn + r] : 0.f;
            Bs[lk4*4+j][lo] = (m < Nn) ? xb[(size_t)kc * Nn + m] : 0.f;
        }
        __syncthreads();
#pragma unroll
        for (int kk = 0; kk < 16; ++kk) {
            float4 a  = *reinterpret_cast<const float4*>(&As[kk][ty*4]);
            float4 bq = *reinterpret_cast<const float4*>(&Bs[kk][tx*4]);
            float ar[4] = {a.x, a.y, a.z, a.w};
            float br[4] = {bq.x, bq.y, bq.z, bq.w};
#pragma unroll
            for (int i = 0; i < 4; ++i)
#pragma unroll
                for (int j = 0; j < 4; ++j)
                    acc[i][j] = fmaf(ar[i], br[j], acc[i][j]);
        }
        __syncthreads();
    }
    float* db = dist + (size_t)bc * Nn * Nn;
    const int m = m0 + tx * 4;
    if (m + 3 < Nn) {
#pragma unroll
        for (int i = 0; i < 4; ++i) {
            const int r = r0 + ty * 4 + i;
            if (r < Nn) {
                float4 o = make_float4(-acc[i][0], -acc[i][1], -acc[i][2], -acc[i][3]);
                *reinterpret_cast<float4*>(&db[(size_t)r * Nn + m]) = o;
            }
        }
    }
}

// select16: one wave per row; 16x argmin-extract via shfl_xor; writes sorted
// candidate indices AND their fast dists.
__global__ __launch_bounds__(256) void select16(
    const float* __restrict__ dist, int* __restrict__ cand,
    float* __restrict__ cdist, int bchunk)
{
    const int wid = blockIdx.x * 4 + (threadIdx.x >> 6);   // wave id in chunk
    const int L   = threadIdx.x & 63;
    const int r   = wid % Nn;
    const int bc  = wid / Nn;
    const int b   = bchunk * 8 + bc;
    const float* drow = dist + ((size_t)bc * Nn + r) * Nn;

    float v[13];
#pragma unroll
    for (int s = 0; s < 12; ++s) v[s] = drow[s * 64 + L];
    v[12] = (L < 16) ? drow[768 + L] : INFINITY;

    float mv = v[0]; int ms = 0;
#pragma unroll
    for (int s = 1; s < 13; ++s)
        if (v[s] < mv) { mv = v[s]; ms = s; }

    int out[16];
    float vals[16];
#pragma unroll
    for (int k = 0; k < 16; ++k) {
        float gv = mv; int gi = ms * 64 + L;
#pragma unroll
        for (int off = 1; off < 64; off <<= 1) {
            const float ov = __shfl_xor(gv, off, 64);
            const int   oi = __shfl_xor(gi, off, 64);
            if (ov < gv || (ov == gv && oi < gi)) { gv = ov; gi = oi; }
        }
        out[k] = gi; vals[k] = gv;
        const int ol = gi & 63, os = gi >> 6;
        if (L == ol) {
#pragma unroll
            for (int s = 0; s < 13; ++s) if (s == os) v[s] = INFINITY;
            mv = v[0]; ms = 0;
#pragma unroll
            for (int s = 1; s < 13; ++s)
                if (v[s] < mv) { mv = v[s]; ms = s; }
        }
    }
    if (L == 0) {
        int*   op = cand  + ((size_t)b * Nn + r) * 16;
        float* dp = cdist + ((size_t)b * Nn + r) * 16;
#pragma unroll
        for (int k = 0; k < 16; ++k) { op[k] = out[k]; dp[k] = vals[k]; }
    }
}

// zero_cnt: reset the ambiguous-row counter each launch (determinism).
__global__ void zero_cnt(int* cnt) { if (threadIdx.x == 0 && blockIdx.x == 0) *cnt = 0; }

// gap_route: per row, if fast-dist gap at the 9/10 boundary exceeds DELTA the
// np-exact top-9 SET provably equals the first 9 fast candidates (output is
// consumed only via max over k, so order is irrelevant). Otherwise append the
// row to the ambiguous list for exact re-ranking.
__global__ __launch_bounds__(256) void gap_route(
    const int* __restrict__ cand, const float* __restrict__ cdist,
    int* __restrict__ nnidx, int* __restrict__ amb, int* __restrict__ cnt)
{
    const int idx = blockIdx.x * 256 + threadIdx.x;
    if (idx >= Bn * Nn) return;
    const float* dp = cdist + (size_t)idx * 16;
    const float d8 = dp[8], d9 = dp[9];
    if (d9 - d8 > GAP_DELTA) {
        const int* cp = cand + (size_t)idx * 16;
        int* op = nnidx + (size_t)idx * Kk;
#pragma unroll
        for (int k = 0; k < Kk; ++k) op[k] = cp[k];
    } else {
        const int pos = atomicAdd(cnt, 1);
        amb[pos] = idx;
    }
}

// refine_amb: EXACT np-f32 re-rank for ambiguous rows only (~1-3%).
// 16 rows per block x 16 threads; grid-stride over the ambiguous list.
// Sequential ascending-c chain on col-major xn (strided reads OK: tiny count).
__global__ __launch_bounds__(256) void refine_amb(
    const float* __restrict__ xn, const float* __restrict__ sq,
    const int* __restrict__ cand, const int* __restrict__ amb,
    const int* __restrict__ cnt, int* __restrict__ nnidx)
{
    __shared__ float Dd[16][16];
    __shared__ int   Dm[16][16];
    const int total = *cnt;
    const int rl = threadIdx.x >> 4;     // row slot in block
    const int k  = threadIdx.x & 15;     // candidate slot

    for (int base = blockIdx.x * 16; base < total; base += gridDim.x * 16) {
        const int slot = base + rl;
        int rowid = 0;
        const bool active = slot < total;
        if (active) rowid = amb[slot];
        const int b = rowid / Nn, r = rowid % Nn;
        const float* xb  = xn + (size_t)b * Cc * Nn;
        const float* sqb = sq + (size_t)b * Nn;

        if (active) {
            const int m = cand[((size_t)b * Nn + r) * 16 + k];
            float dot = 0.f;
            for (int c = 0; c < Cc; ++c)
                dot = __fadd_rn(dot, __fmul_rn(xb[(size_t)c * Nn + r],
                                               xb[(size_t)c * Nn + m]));
            const float t1 = __fmul_rn(2.f, dot);
            const float t2 = __fsub_rn(sqb[r], t1);
            Dd[rl][k] = __fadd_rn(t2, sqb[m]);
            Dm[rl][k] = m;
        }
        __syncthreads();
        if (active && k == 0) {
            float dl[16]; int il[16];
#pragma unroll
            for (int j = 0; j < 16; ++j) { dl[j] = Dd[rl][j]; il[j] = Dm[rl][j]; }
            int* op = nnidx + (size_t)rowid * Kk;
            for (int kk = 0; kk < Kk; ++kk) {
                int best = kk;
                for (int j = kk + 1; j < 16; ++j)
                    if (dl[j] < dl[best] || (dl[j] == dl[best] && il[j] < il[best])) best = j;
                float td = dl[kk]; dl[kk] = dl[best]; dl[best] = td;
                int ti = il[kk]; il[kk] = il[best]; il[best] = ti;
                op[kk] = il[kk];
            }
        }
        __syncthreads();
    }
}

// ===========================================================================
// VALUE PATH — fast f32 (fmaf ok; error ~1e-5 << threshold 0.14)
// ===========================================================================

__global__ __launch_bounds__(256) void mr_naive(
    const float* __restrict__ xt, const int* __restrict__ nnidx,
    float* __restrict__ st)
{
    const long long idx = (long long)blockIdx.x * 256 + threadIdx.x;
    if (idx >= (long long)Bn * Cc * Nn) return;
    const int n = (int)(idx % Nn);
    const int c = (int)((idx / Nn) % Cc);
    const int b = (int)(idx / ((long long)Cc * Nn));
    const float* row = xt + ((size_t)b * Cc + c) * Nn;
    const float ctr = row[n];
    const int* ip = nnidx + ((size_t)b * Nn + n) * Kk;
    float mx = -INFINITY;
    for (int k = 0; k < Kk; ++k) {
        const float v = __fsub_rn(row[ip[k]], ctr);
        if (v > mx) mx = v;
    }
    st[((size_t)b * C2c + 2 * c) * Nn + n]     = ctr;
    st[((size_t)b * C2c + 2 * c + 1) * Nn + n] = mx;
}

__global__ __launch_bounds__(256) void gconv_kernel(
    const float* __restrict__ st, const float* __restrict__ gw,
    const float* __restrict__ gb,
    const float* __restrict__ gg, const float* __restrict__ bb_,
    const float* __restrict__ mm, const float* __restrict__ vv,
    float* __restrict__ out)
{
    __shared__ float As[16][32];
    __shared__ float Bs[16][64];
    const int b   = blockIdx.z;
    const int n0  = blockIdx.x * 64;
    const int grp = blockIdx.y / 3;
    const int o0  = (blockIdx.y % 3) * 32;
    const int tid = threadIdx.x;
    const int tx = tid & 15, ty = tid >> 4;
    const int lo = tid & 31, lk2 = tid >> 5;
    const int ln4 = tid & 15, lbk = tid >> 4;
    const float* stb = st + (size_t)b * C2c * Nn + (size_t)grp * 96 * Nn;
    const float* wgp = gw + (size_t)grp * 96 * 96;

    float acc[2][4];
#pragma unroll
    for (int i = 0; i < 2; ++i)
#pragma unroll
        for (int j = 0; j < 4; ++j) acc[i][j] = 0.f;

    for (int kt = 0; kt < 6; ++kt) {
        const int k0 = kt * 16;
        float2 av = *reinterpret_cast<const float2*>(&wgp[(size_t)(o0 + lo) * 96 + k0 + lk2 * 2]);
        As[lk2*2+0][lo] = av.x;
        As[lk2*2+1][lo] = av.y;
        const int n = n0 + ln4 * 4;
        float4 bv = make_float4(0.f, 0.f, 0.f, 0.f);
        if (n < Nn) bv = *reinterpret_cast<const float4*>(&stb[(size_t)(k0 + lbk) * Nn + n]);
        *reinterpret_cast<float4*>(&Bs[lbk][ln4*4]) = bv;
        __syncthreads();
#pragma unroll
        for (int kk = 0; kk < 16; ++kk) {
            float2 a  = *reinterpret_cast<const float2*>(&As[kk][ty*2]);
            float4 bq = *reinterpret_cast<const float4*>(&Bs[kk][tx*4]);
            float ar[2] = {a.x, a.y};
            float br[4] = {bq.x, bq.y, bq.z, bq.w};
#pragma unroll
            for (int i = 0; i < 2; ++i)
#pragma unroll
                for (int j = 0; j < 4; ++j)
                    acc[i][j] = fmaf(ar[i], br[j], acc[i][j]);
        }
        __syncthreads();
    }
    const int n = n0 + tx * 4;
    if (n < Nn) {
#pragma unroll
        for (int i = 0; i < 2; ++i) {
            const int oc = grp * 96 + o0 + ty * 2 + i;
            const float s  = gg[oc] * rsqrtf(vv[oc] + 1e-5f);
            const float sh = (gb[oc] - mm[oc]) * s + bb_[oc];
            float r[4];
#pragma unroll
            for (int j = 0; j < 4; ++j) {
                float v = fmaf(acc[i][j], s, sh);
                r[j] = 0.5f * v * (1.f + erff(v * 0.70710678118654752f));
            }
            float4 rv = make_float4(r[0], r[1], r[2], r[3]);
            *reinterpret_cast<float4*>(&out[((size_t)b * C2c + oc) * Nn + n]) = rv;
        }
    }
}

__global__ __launch_bounds__(256) void fc2_kernel(
    const float* __restrict__ gin, const float* __restrict__ w,
    const float* __restrict__ bias,
    const float* __restrict__ gg, const float* __restrict__ bb_,
    const float* __restrict__ mm, const float* __restrict__ vv,
    const float* __restrict__ xres,
    float* __restrict__ out)
{
    __shared__ float As[16][64];
    __shared__ float Bs[16][64];
    const int b   = blockIdx.z;
    const int n0  = blockIdx.x * 64;
    const int o0  = blockIdx.y * 64;
    const int tid = threadIdx.x;
    const int tx = tid & 15, ty = tid >> 4;
    const int lo = tid & 63, lk4 = tid >> 6;
    const int ln4 = tid & 15, lbk = tid >> 4;
    const float* gbp = gin + (size_t)b * C2c * Nn;
    const float* xb  = xres + (size_t)b * Cc * Nn;

    float acc[4][4];
#pragma unroll
    for (int i = 0; i < 4; ++i)
#pragma unroll
        for (int j = 0; j < 4; ++j) acc[i][j] = 0.f;

    for (int kt = 0; kt < 24; ++kt) {
        const int k0 = kt * 16;
        float4 av = *reinterpret_cast<const float4*>(&w[(size_t)(o0 + lo) * 384 + k0 + lk4 * 4]);
        As[lk4*4+0][lo] = av.x;
        As[lk4*4+1][lo] = av.y;
        As[lk4*4+2][lo] = av.z;
        As[lk4*4+3][lo] = av.w;
        const int n = n0 + ln4 * 4;
        float4 bv = make_float4(0.f, 0.f, 0.f, 0.f);
        if (n < Nn) bv = *reinterpret_cast<const float4*>(&gbp[(size_t)(k0 + lbk) * Nn + n]);
        *reinterpret_cast<float4*>(&Bs[lbk][ln4*4]) = bv;
        __syncthreads();
#pragma unroll
        for (int kk = 0; kk < 16; ++kk) {
            float4 a  = *reinterpret_cast<const float4*>(&As[kk][ty*4]);
            float4 bq = *reinterpret_cast<const float4*>(&Bs[kk][tx*4]);
            float ar[4] = {a.x, a.y, a.z, a.w};
            float br[4] = {bq.x, bq.y, bq.z, bq.w};
#pragma unroll
            for (int i = 0; i < 4; ++i)
#pragma unroll
                for (int j = 0; j < 4; ++j)
                    acc[i][j] = fmaf(ar[i], br[j], acc[i][j]);
        }
        __syncthreads();
    }
    const int n = n0 + tx * 4;
    if (n < Nn) {
#pragma unroll
        for (int i = 0; i < 4; ++i) {
            const int o = o0 + ty * 4 + i;
            const float s  = gg[o] * rsqrtf(vv[o] + 1e-5f);
            const float sh = (bias[o] - mm[o]) * s + bb_[o];
            float4 xr = *reinterpret_cast<const float4*>(&xb[(size_t)o * Nn + n]);
            float4 r;
            r.x = fmaf(acc[i][0], s, sh) + xr.x;
            r.y = fmaf(acc[i][1], s, sh) + xr.y;
            r.z = fmaf(acc[i][2], s, sh) + xr.z;
            r.w = fmaf(acc[i][3], s, sh) + xr.w;
            *reinterpret_cast<float4*>(&out[((size_t)b * Cc + o) * Nn + n]) = r;
        }
    }
}

// ---------------------------------------------------------------------------
extern "C" void kernel_launch(void* const* d_in, const int* in_sizes, int n_in,
                              void* d_out, int out_size, void* d_ws, size_t ws_size,
                              hipStream_t stream)
{
    const float* x     = (const float*)d_in[0];
    const float* fc1_w = (const float*)d_in[1];
    const float* fc1_b = (const float*)d_in[2];
    const float* bn1_g = (const float*)d_in[3];
    const float* bn1_b = (const float*)d_in[4];
    const float* bn1_m = (const float*)d_in[5];
    const float* bn1_v = (const float*)d_in[6];
    const float* gc_w  = (const float*)d_in[7];
    const float* gc_b  = (const float*)d_in[8];
    const float* bn2_g = (const float*)d_in[9];
    const float* bn2_b = (const float*)d_in[10];
    const float* bn2_m = (const float*)d_in[11];
    const float* bn2_v = (const float*)d_in[12];
    const float* fc2_w = (const float*)d_in[13];
    const float* fc2_b = (const float*)d_in[14];
    const float* bn3_g = (const float*)d_in[15];
    const float* bn3_b = (const float*)d_in[16];
    const float* bn3_m = (const float*)d_in[17];
    const float* bn3_v = (const float*)d_in[18];

    float* out = (float*)d_out;                  // xt scratch, overwritten by fc2

    // workspace (max concurrent ~153 MB):
    //   region A [0, 77.07M):  dist8 (19.67M, chunked; dies after select16)
    //                          -> st (born at mr)
    //   region B [77.07, 154.14M): xn | sq | cand16 | cdist16 (die by refine)
    //                          -> gbuf (born at gconv)
    //   region C [154.14M, +): nnidx (1.81M) | amb (0.2M) | cnt (4B)
    char* wsb = (char*)d_ws;
    const size_t regionBytes = (size_t)Bn * C2c * Nn * 4;   // 77,070,336
    float* dist = (float*)wsb;
    float* st   = (float*)wsb;
    char*  g2   = wsb + regionBytes;
    float* xnb  = (float*)g2;                                      // 38,535,168 B
    float* sqb  = (float*)(g2 + (size_t)Bn * Cc * Nn * 4);         // 200,704 B
    int*   c16  = (int*)(g2 + (size_t)Bn * Cc * Nn * 4 + 200704);  // 3,211,264 B
    float* cd16 = (float*)(g2 + (size_t)Bn * Cc * Nn * 4 + 200704 + 3211264); // 3,211,264 B
    float* gbuf = (float*)g2;                                      // clobbers head (dead)
    char*  g3   = wsb + 2 * regionBytes;
    int*   nni  = (int*)g3;                                        // 1,806,336 B
    int*   amb  = (int*)(g3 + 1806336);                            // 200,704 B
    int*   cnt  = (int*)(g3 + 1806336 + 200704);                   // 4 B

    const long long nBCN = (long long)Bn * Cc * Nn;
    const int nBN = Bn * Nn;

    dim3 blk(256);
    fc1_np<<<dim3(13, 3, Bn), blk, 0, stream>>>(
        x, fc1_w, fc1_b, bn1_g, bn1_b, bn1_m, bn1_v, out);
    norm_np<<<dim3((nBN + 255) / 256), blk, 0, stream>>>(out, xnb, sqb);
    for (int ch = 0; ch < 8; ++ch) {
        dist_gemm<<<dim3(169, 8), blk, 0, stream>>>(xnb, dist, ch);
        select16<<<dim3(8 * Nn / 4), blk, 0, stream>>>(dist, c16, cd16, ch);
    }
    zero_cnt<<<dim3(1), dim3(64), 0, stream>>>(cnt);
    gap_route<<<dim3((nBN + 255) / 256), blk, 0, stream>>>(c16, cd16, nni, amb, cnt);
    refine_amb<<<dim3(196), blk, 0, stream>>>(xnb, sqb, c16, amb, cnt, nni);
    mr_naive<<<dim3((unsigned)((nBCN + 255) / 256)), blk, 0, stream>>>(out, nni, st);
    gconv_kernel<<<dim3(13, 12, Bn), blk, 0, stream>>>(
        st, gc_w, gc_b, bn2_g, bn2_b, bn2_m, bn2_v, gbuf);
    fc2_kernel<<<dim3(13, 3, Bn), blk, 0, stream>>>(
        gbuf, fc2_w, fc2_b, bn3_g, bn3_b, bn3_m, bn3_v, x, out);
}

// Round 10
// 1059.056 us; speedup vs baseline: 1.1020x; 1.0189x over previous
//
#include <hip/hip_runtime.h>
#include <math.h>

static constexpr int Bn  = 64;    // batch
static constexpr int Cc  = 192;   // channels
static constexpr int Nn  = 784;   // H*W
static constexpr int C2c = 384;   // 2C
static constexpr int Kk  = 9;     // knn K
#define GAP_DELTA 1e-4f

// ===========================================================================
// INDEX PATH — np-f32 bit-exact where values matter (fc1, norm, refine_amb).
// ===========================================================================

// fc1_np: BIT-CRITICAL — numpy-f32-exact (no FMA, ascending-c accumulation).
__global__ __launch_bounds__(256) void fc1_np(
    const float* __restrict__ x, const float* __restrict__ w,
    const float* __restrict__ bias,
    const float* __restrict__ gg, const float* __restrict__ bb_,
    const float* __restrict__ mm, const float* __restrict__ vv,
    float* __restrict__ xt)
{
    __shared__ float As[16][64];
    __shared__ float Bs[16][64];
    const int b   = blockIdx.z;
    const int n0  = blockIdx.x * 64;
    const int o0  = blockIdx.y * 64;
    const int tid = threadIdx.x;
    const int tx = tid & 15, ty = tid >> 4;
    const int lo = tid & 63, lk4 = tid >> 6;
    const int ln4 = tid & 15, lbk = tid >> 4;
    const float* xb = x + (size_t)b * Cc * Nn;

    float acc[4][4];
#pragma unroll
    for (int i = 0; i < 4; ++i)
#pragma unroll
        for (int j = 0; j < 4; ++j) acc[i][j] = 0.f;

    for (int kt = 0; kt < 12; ++kt) {               // c ascending: kt*16 + kk
        const int k0 = kt * 16;
        float4 av = *reinterpret_cast<const float4*>(&w[(size_t)(o0 + lo) * 192 + k0 + lk4 * 4]);
        As[lk4*4+0][lo] = av.x;
        As[lk4*4+1][lo] = av.y;
        As[lk4*4+2][lo] = av.z;
        As[lk4*4+3][lo] = av.w;
        const int n = n0 + ln4 * 4;
        float4 bv = make_float4(0.f, 0.f, 0.f, 0.f);
        if (n < Nn) bv = *reinterpret_cast<const float4*>(&xb[(size_t)(k0 + lbk) * Nn + n]);
        *reinterpret_cast<float4*>(&Bs[lbk][ln4*4]) = bv;
        __syncthreads();
#pragma unroll
        for (int kk = 0; kk < 16; ++kk) {
            float ar[4], br[4];
#pragma unroll
            for (int i = 0; i < 4; ++i) ar[i] = As[kk][ty*4+i];
#pragma unroll
            for (int j = 0; j < 4; ++j) br[j] = Bs[kk][tx*4+j];
#pragma unroll
            for (int i = 0; i < 4; ++i)
#pragma unroll
                for (int j = 0; j < 4; ++j)
                    acc[i][j] = __fadd_rn(acc[i][j], __fmul_rn(ar[i], br[j]));
        }
        __syncthreads();
    }
    const int n = n0 + tx * 4;
    if (n < Nn) {
#pragma unroll
        for (int i = 0; i < 4; ++i) {
            const int o = o0 + ty * 4 + i;
            const float e  = __fadd_rn(vv[o], 1e-5f);
            const float r1 = __fsqrt_rn(e);
            const float rr = __fdiv_rn(1.f, r1);
            const float s  = __fmul_rn(gg[o], rr);
#pragma unroll
            for (int j = 0; j < 4; ++j) {
                const float h = __fadd_rn(acc[i][j], bias[o]);
                const float t = __fsub_rn(h, mm[o]);
                const float u = __fmul_rn(t, s);
                xt[((size_t)b * Cc + o) * Nn + n + j] = __fadd_rn(u, bb_[o]);
            }
        }
    }
}

// norm_np: numpy-exact. BIT-CRITICAL.
__global__ __launch_bounds__(256) void norm_np(
    const float* __restrict__ xt, float* __restrict__ xn, float* __restrict__ sq)
{
    const int idx = blockIdx.x * 256 + threadIdx.x;
    if (idx >= Bn * Nn) return;
    const int n = idx % Nn;
    const int b = idx / Nn;
    const float* p = xt + (size_t)b * Cc * Nn + n;

    float acc = 0.f;
    for (int c = 0; c < Cc; ++c) {
        const float v = p[(size_t)c * Nn];
        acc = __fadd_rn(acc, __fmul_rn(v, v));
    }
    float nrm = __fsqrt_rn(acc);
    nrm = fmaxf(nrm, 1e-12f);

    float* q = xn + (size_t)b * Cc * Nn + n;
    for (int c = 0; c < Cc; ++c)
        q[(size_t)c * Nn] = __fdiv_rn(p[(size_t)c * Nn], nrm);

    float sblk[2];
#pragma unroll
    for (int blk = 0; blk < 2; ++blk) {
        const int base = blk * 96;
        float r[8];
#pragma unroll
        for (int j = 0; j < 8; ++j) {
            const float xv = __fdiv_rn(p[(size_t)(base + j) * Nn], nrm);
            r[j] = __fmul_rn(xv, xv);
        }
        for (int i = 8; i < 96; i += 8) {
#pragma unroll
            for (int j = 0; j < 8; ++j) {
                const float xv = __fdiv_rn(p[(size_t)(base + i + j) * Nn], nrm);
                r[j] = __fadd_rn(r[j], __fmul_rn(xv, xv));
            }
        }
        sblk[blk] = __fadd_rn(__fadd_rn(__fadd_rn(r[0], r[1]), __fadd_rn(r[2], r[3])),
                              __fadd_rn(__fadd_rn(r[4], r[5]), __fadd_rn(r[6], r[7])));
    }
    sq[idx] = __fadd_rn(sblk[0], sblk[1]);
}

// dist_gemm: symmetric fast filter — only rt<=mt tiles computed; the mirror
// tile is produced by an LDS transpose. dist[b8][r][m] = -dot(xn_r, xn_m).
__global__ __launch_bounds__(256) void dist_gemm(
    const float* __restrict__ xn, float* __restrict__ dist, int bchunk)
{
    __shared__ float As[16][64];
    __shared__ float Bs[16][64];
    __shared__ float Ds[64][65];
    const int bt = blockIdx.x;             // 0..90 (upper-triangle tiles)
    int rt = 0, rem = bt;
    while (rem >= 13 - rt) { rem -= 13 - rt; ++rt; }
    const int mt = rt + rem;
    const int bc = blockIdx.y;             // 0..7
    const int b  = bchunk * 8 + bc;
    const int r0 = rt * 64, m0 = mt * 64;
    const int tid = threadIdx.x;
    const int tx = tid & 15, ty = tid >> 4;
    const int lo = tid & 63, lk4 = tid >> 6;
    const float* xb = xn + (size_t)b * Cc * Nn;

    float acc[4][4];
#pragma unroll
    for (int i = 0; i < 4; ++i)
#pragma unroll
        for (int j = 0; j < 4; ++j) acc[i][j] = 0.f;

    for (int kt = 0; kt < 12; ++kt) {
        const int k0 = kt * 16;
        const int r = r0 + lo, m = m0 + lo;
#pragma unroll
        for (int j = 0; j < 4; ++j) {
            const int kc = k0 + lk4 * 4 + j;
            As[lk4*4+j][lo] = (r < Nn) ? xb[(size_t)kc * Nn + r] : 0.f;
            Bs[lk4*4+j][lo] = (m < Nn) ? xb[(size_t)kc * Nn + m] : 0.f;
        }
        __syncthreads();
#pragma unroll
        for (int kk = 0; kk < 16; ++kk) {
            float4 a  = *reinterpret_cast<const float4*>(&As[kk][ty*4]);
            float4 bq = *reinterpret_cast<const float4*>(&Bs[kk][tx*4]);
            float ar[4] = {a.x, a.y, a.z, a.w};
            float br[4] = {bq.x, bq.y, bq.z, bq.w};
#pragma unroll
            for (int i = 0; i < 4; ++i)
#pragma unroll
                for (int j = 0; j < 4; ++j)
                    acc[i][j] = fmaf(ar[i], br[j], acc[i][j]);
        }
        __syncthreads();
    }
    float* db = dist + (size_t)bc * Nn * Nn;
    // normal tile: rows r (coalesced float4 along m)
    {
        const int m = m0 + tx * 4;
        if (m < Nn) {
#pragma unroll
            for (int i = 0; i < 4; ++i) {
                const int r = r0 + ty * 4 + i;
                if (r < Nn) {
                    float4 o = make_float4(-acc[i][0], -acc[i][1], -acc[i][2], -acc[i][3]);
                    *reinterpret_cast<float4*>(&db[(size_t)r * Nn + m]) = o;
                }
            }
        }
    }
    // mirror tile (rt<mt): transpose via LDS, then coalesced float4 along r
    if (rt != mt) {
#pragma unroll
        for (int i = 0; i < 4; ++i)
#pragma unroll
            for (int j = 0; j < 4; ++j)
                Ds[ty*4+i][tx*4+j] = -acc[i][j];
        __syncthreads();
        const int rcol = r0 + tx * 4;      // full r-tiles only when rt<mt<=12
#pragma unroll
        for (int i = 0; i < 4; ++i) {
            const int mrow = m0 + ty * 4 + i;
            if (mrow < Nn) {
                float4 o = make_float4(Ds[tx*4+0][ty*4+i], Ds[tx*4+1][ty*4+i],
                                       Ds[tx*4+2][ty*4+i], Ds[tx*4+3][ty*4+i]);
                *reinterpret_cast<float4*>(&db[(size_t)mrow * Nn + rcol]) = o;
            }
        }
    }
}

// select16: one wave per row; 16x argmin-extract via shfl_xor; writes sorted
// candidate indices AND their fast dists.
__global__ __launch_bounds__(256) void select16(
    const float* __restrict__ dist, int* __restrict__ cand,
    float* __restrict__ cdist, int bchunk)
{
    const int wid = blockIdx.x * 4 + (threadIdx.x >> 6);   // wave id in chunk
    const int L   = threadIdx.x & 63;
    const int r   = wid % Nn;
    const int bc  = wid / Nn;
    const int b   = bchunk * 8 + bc;
    const float* drow = dist + ((size_t)bc * Nn + r) * Nn;

    float v[13];
#pragma unroll
    for (int s = 0; s < 12; ++s) v[s] = drow[s * 64 + L];
    v[12] = (L < 16) ? drow[768 + L] : INFINITY;

    float mv = v[0]; int ms = 0;
#pragma unroll
    for (int s = 1; s < 13; ++s)
        if (v[s] < mv) { mv = v[s]; ms = s; }

    int out[16];
    float vals[16];
#pragma unroll
    for (int k = 0; k < 16; ++k) {
        float gv = mv; int gi = ms * 64 + L;
#pragma unroll
        for (int off = 1; off < 64; off <<= 1) {
            const float ov = __shfl_xor(gv, off, 64);
            const int   oi = __shfl_xor(gi, off, 64);
            if (ov < gv || (ov == gv && oi < gi)) { gv = ov; gi = oi; }
        }
        out[k] = gi; vals[k] = gv;
        const int ol = gi & 63, os = gi >> 6;
        if (L == ol) {
#pragma unroll
            for (int s = 0; s < 13; ++s) if (s == os) v[s] = INFINITY;
            mv = v[0]; ms = 0;
#pragma unroll
            for (int s = 1; s < 13; ++s)
                if (v[s] < mv) { mv = v[s]; ms = s; }
        }
    }
    if (L == 0) {
        int*   op = cand  + ((size_t)b * Nn + r) * 16;
        float* dp = cdist + ((size_t)b * Nn + r) * 16;
#pragma unroll
        for (int k = 0; k < 16; ++k) { op[k] = out[k]; dp[k] = vals[k]; }
    }
}

// zero_cnt: reset the ambiguous-row counter each launch (determinism).
__global__ void zero_cnt(int* cnt) { if (threadIdx.x == 0 && blockIdx.x == 0) *cnt = 0; }

// gap_route: clear-gap rows resolved directly from fast candidates; knife-edge
// rows appended to the ambiguous list.
__global__ __launch_bounds__(256) void gap_route(
    const int* __restrict__ cand, const float* __restrict__ cdist,
    int* __restrict__ nnidx, int* __restrict__ amb, int* __restrict__ cnt)
{
    const int idx = blockIdx.x * 256 + threadIdx.x;
    if (idx >= Bn * Nn) return;
    const float* dp = cdist + (size_t)idx * 16;
    const float d8 = dp[8], d9 = dp[9];
    if (d9 - d8 > GAP_DELTA) {
        const int* cp = cand + (size_t)idx * 16;
        int* op = nnidx + (size_t)idx * Kk;
#pragma unroll
        for (int k = 0; k < Kk; ++k) op[k] = cp[k];
    } else {
        const int pos = atomicAdd(cnt, 1);
        amb[pos] = idx;
    }
}

// refine_amb: EXACT np-f32 re-rank for ambiguous rows. The 32 loads of each
// 16-channel chunk are issued independently into registers (latency hiding);
// the adds remain the exact sequential ascending-c chain. BIT-CRITICAL adds.
__global__ __launch_bounds__(256) void refine_amb(
    const float* __restrict__ xn, const float* __restrict__ sq,
    const int* __restrict__ cand, const int* __restrict__ amb,
    const int* __restrict__ cnt, int* __restrict__ nnidx)
{
    __shared__ float Dd[16][16];
    __shared__ int   Dm[16][16];
    const int total = *cnt;
    const int rl = threadIdx.x >> 4;     // row slot in block
    const int k  = threadIdx.x & 15;     // candidate slot

    for (int base = blockIdx.x * 16; base < total; base += gridDim.x * 16) {
        const int slot = base + rl;
        int rowid = 0;
        const bool active = slot < total;
        if (active) rowid = amb[slot];
        const int b = rowid / Nn, r = rowid % Nn;
        const float* xb  = xn + (size_t)b * Cc * Nn;
        const float* sqb = sq + (size_t)b * Nn;

        if (active) {
            const int m = cand[((size_t)b * Nn + r) * 16 + k];
            float dot = 0.f;
            for (int cc = 0; cc < 12; ++cc) {
                float va[16], vb[16];
#pragma unroll
                for (int j = 0; j < 16; ++j) {
                    va[j] = xb[(size_t)(cc * 16 + j) * Nn + r];
                    vb[j] = xb[(size_t)(cc * 16 + j) * Nn + m];
                }
#pragma unroll
                for (int j = 0; j < 16; ++j)
                    dot = __fadd_rn(dot, __fmul_rn(va[j], vb[j]));
            }
            const float t1 = __fmul_rn(2.f, dot);
            const float t2 = __fsub_rn(sqb[r], t1);
            Dd[rl][k] = __fadd_rn(t2, sqb[m]);
            Dm[rl][k] = m;
        }
        __syncthreads();
        if (active && k == 0) {
            float dl[16]; int il[16];
#pragma unroll
            for (int j = 0; j < 16; ++j) { dl[j] = Dd[rl][j]; il[j] = Dm[rl][j]; }
            int* op = nnidx + (size_t)rowid * Kk;
            for (int kk = 0; kk < Kk; ++kk) {
                int best = kk;
                for (int j = kk + 1; j < 16; ++j)
                    if (dl[j] < dl[best] || (dl[j] == dl[best] && il[j] < il[best])) best = j;
                float td = dl[kk]; dl[kk] = dl[best]; dl[best] = td;
                int ti = il[kk]; il[kk] = il[best]; il[best] = ti;
                op[kk] = il[kk];
            }
        }
        __syncthreads();
    }
}

// ===========================================================================
// VALUE PATH — fast f32 (fmaf ok; error ~1e-5 << threshold 0.14)
// ===========================================================================

__global__ __launch_bounds__(256) void mr_naive(
    const float* __restrict__ xt, const int* __restrict__ nnidx,
    float* __restrict__ st)
{
    const long long idx = (long long)blockIdx.x * 256 + threadIdx.x;
    if (idx >= (long long)Bn * Cc * Nn) return;
    const int n = (int)(idx % Nn);
    const int c = (int)((idx / Nn) % Cc);
    const int b = (int)(idx / ((long long)Cc * Nn));
    const float* row = xt + ((size_t)b * Cc + c) * Nn;
    const float ctr = row[n];
    const int* ip = nnidx + ((size_t)b * Nn + n) * Kk;
    float mx = -INFINITY;
    for (int k = 0; k < Kk; ++k) {
        const float v = __fsub_rn(row[ip[k]], ctr);
        if (v > mx) mx = v;
    }
    st[((size_t)b * C2c + 2 * c) * Nn + n]     = ctr;
    st[((size_t)b * C2c + 2 * c + 1) * Nn + n] = mx;
}

__global__ __launch_bounds__(256) void gconv_kernel(
    const float* __restrict__ st, const float* __restrict__ gw,
    const float* __restrict__ gb,
    const float* __restrict__ gg, const float* __restrict__ bb_,
    const float* __restrict__ mm, const float* __restrict__ vv,
    float* __restrict__ out)
{
    __shared__ float As[16][32];
    __shared__ float Bs[16][64];
    const int b   = blockIdx.z;
    const int n0  = blockIdx.x * 64;
    const int grp = blockIdx.y / 3;
    const int o0  = (blockIdx.y % 3) * 32;
    const int tid = threadIdx.x;
    const int tx = tid & 15, ty = tid >> 4;
    const int lo = tid & 31, lk2 = tid >> 5;
    const int ln4 = tid & 15, lbk = tid >> 4;
    const float* stb = st + (size_t)b * C2c * Nn + (size_t)grp * 96 * Nn;
    const float* wgp = gw + (size_t)grp * 96 * 96;

    float acc[2][4];
#pragma unroll
    for (int i = 0; i < 2; ++i)
#pragma unroll
        for (int j = 0; j < 4; ++j) acc[i][j] = 0.f;

    for (int kt = 0; kt < 6; ++kt) {
        const int k0 = kt * 16;
        float2 av = *reinterpret_cast<const float2*>(&wgp[(size_t)(o0 + lo) * 96 + k0 + lk2 * 2]);
        As[lk2*2+0][lo] = av.x;
        As[lk2*2+1][lo] = av.y;
        const int n = n0 + ln4 * 4;
        float4 bv = make_float4(0.f, 0.f, 0.f, 0.f);
        if (n < Nn) bv = *reinterpret_cast<const float4*>(&stb[(size_t)(k0 + lbk) * Nn + n]);
        *reinterpret_cast<float4*>(&Bs[lbk][ln4*4]) = bv;
        __syncthreads();
#pragma unroll
        for (int kk = 0; kk < 16; ++kk) {
            float2 a  = *reinterpret_cast<const float2*>(&As[kk][ty*2]);
            float4 bq = *reinterpret_cast<const float4*>(&Bs[kk][tx*4]);
            float ar[2] = {a.x, a.y};
            float br[4] = {bq.x, bq.y, bq.z, bq.w};
#pragma unroll
            for (int i = 0; i < 2; ++i)
#pragma unroll
                for (int j = 0; j < 4; ++j)
                    acc[i][j] = fmaf(ar[i], br[j], acc[i][j]);
        }
        __syncthreads();
    }
    const int n = n0 + tx * 4;
    if (n < Nn) {
#pragma unroll
        for (int i = 0; i < 2; ++i) {
            const int oc = grp * 96 + o0 + ty * 2 + i;
            const float s  = gg[oc] * rsqrtf(vv[oc] + 1e-5f);
            const float sh = (gb[oc] - mm[oc]) * s + bb_[oc];
            float r[4];
#pragma unroll
            for (int j = 0; j < 4; ++j) {
                float v = fmaf(acc[i][j], s, sh);
                r[j] = 0.5f * v * (1.f + erff(v * 0.70710678118654752f));
            }
            float4 rv = make_float4(r[0], r[1], r[2], r[3]);
            *reinterpret_cast<float4*>(&out[((size_t)b * C2c + oc) * Nn + n]) = rv;
        }
    }
}

// fc2 + BN3 + residual: 64(o) x 128(n) tile, 4x8 per thread.
__global__ __launch_bounds__(256) void fc2_kernel(
    const float* __restrict__ gin, const float* __restrict__ w,
    const float* __restrict__ bias,
    const float* __restrict__ gg, const float* __restrict__ bb_,
    const float* __restrict__ mm, const float* __restrict__ vv,
    const float* __restrict__ xres,
    float* __restrict__ out)
{
    __shared__ float As[16][64];
    __shared__ float Bs[16][128];
    const int b   = blockIdx.z;
    const int n0  = blockIdx.x * 128;
    const int o0  = blockIdx.y * 64;
    const int tid = threadIdx.x;
    const int tx = tid & 15, ty = tid >> 4;
    const int lo = tid & 63, lk4 = tid >> 6;
    const int ln8 = tid & 15, lbk = tid >> 4;
    const float* gbp = gin + (size_t)b * C2c * Nn;
    const float* xb  = xres + (size_t)b * Cc * Nn;

    float acc[4][8];
#pragma unroll
    for (int i = 0; i < 4; ++i)
#pragma unroll
        for (int j = 0; j < 8; ++j) acc[i][j] = 0.f;

    for (int kt = 0; kt < 24; ++kt) {
        const int k0 = kt * 16;
        float4 av = *reinterpret_cast<const float4*>(&w[(size_t)(o0 + lo) * 384 + k0 + lk4 * 4]);
        As[lk4*4+0][lo] = av.x;
        As[lk4*4+1][lo] = av.y;
        As[lk4*4+2][lo] = av.z;
        As[lk4*4+3][lo] = av.w;
        const int n = n0 + ln8 * 8;
        float4 b0 = make_float4(0.f, 0.f, 0.f, 0.f);
        float4 b1 = make_float4(0.f, 0.f, 0.f, 0.f);
        if (n < Nn) {
            b0 = *reinterpret_cast<const float4*>(&gbp[(size_t)(k0 + lbk) * Nn + n]);
            b1 = *reinterpret_cast<const float4*>(&gbp[(size_t)(k0 + lbk) * Nn + n + 4]);
        }
        *reinterpret_cast<float4*>(&Bs[lbk][ln8*8])     = b0;
        *reinterpret_cast<float4*>(&Bs[lbk][ln8*8 + 4]) = b1;
        __syncthreads();
#pragma unroll
        for (int kk = 0; kk < 16; ++kk) {
            float4 a  = *reinterpret_cast<const float4*>(&As[kk][ty*4]);
            float4 q0 = *reinterpret_cast<const float4*>(&Bs[kk][tx*8]);
            float4 q1 = *reinterpret_cast<const float4*>(&Bs[kk][tx*8 + 4]);
            float ar[4] = {a.x, a.y, a.z, a.w};
            float br[8] = {q0.x, q0.y, q0.z, q0.w, q1.x, q1.y, q1.z, q1.w};
#pragma unroll
            for (int i = 0; i < 4; ++i)
#pragma unroll
                for (int j = 0; j < 8; ++j)
                    acc[i][j] = fmaf(ar[i], br[j], acc[i][j]);
        }
        __syncthreads();
    }
    const int n = n0 + tx * 8;
    if (n < Nn) {
#pragma unroll
        for (int i = 0; i < 4; ++i) {
            const int o = o0 + ty * 4 + i;
            const float s  = gg[o] * rsqrtf(vv[o] + 1e-5f);
            const float sh = (bias[o] - mm[o]) * s + bb_[o];
            float4 x0 = *reinterpret_cast<const float4*>(&xb[(size_t)o * Nn + n]);
            float4 x1 = *reinterpret_cast<const float4*>(&xb[(size_t)o * Nn + n + 4]);
            float4 r0, r1;
            r0.x = fmaf(acc[i][0], s, sh) + x0.x;
            r0.y = fmaf(acc[i][1], s, sh) + x0.y;
            r0.z = fmaf(acc[i][2], s, sh) + x0.z;
            r0.w = fmaf(acc[i][3], s, sh) + x0.w;
            r1.x = fmaf(acc[i][4], s, sh) + x1.x;
            r1.y = fmaf(acc[i][5], s, sh) + x1.y;
            r1.z = fmaf(acc[i][6], s, sh) + x1.z;
            r1.w = fmaf(acc[i][7], s, sh) + x1.w;
            *reinterpret_cast<float4*>(&out[((size_t)b * Cc + o) * Nn + n])     = r0;
            *reinterpret_cast<float4*>(&out[((size_t)b * Cc + o) * Nn + n + 4]) = r1;
        }
    }
}

// ---------------------------------------------------------------------------
extern "C" void kernel_launch(void* const* d_in, const int* in_sizes, int n_in,
                              void* d_out, int out_size, void* d_ws, size_t ws_size,
                              hipStream_t stream)
{
    const float* x     = (const float*)d_in[0];
    const float* fc1_w = (const float*)d_in[1];
    const float* fc1_b = (const float*)d_in[2];
    const float* bn1_g = (const float*)d_in[3];
    const float* bn1_b = (const float*)d_in[4];
    const float* bn1_m = (const float*)d_in[5];
    const float* bn1_v = (const float*)d_in[6];
    const float* gc_w  = (const float*)d_in[7];
    const float* gc_b  = (const float*)d_in[8];
    const float* bn2_g = (const float*)d_in[9];
    const float* bn2_b = (const float*)d_in[10];
    const float* bn2_m = (const float*)d_in[11];
    const float* bn2_v = (const float*)d_in[12];
    const float* fc2_w = (const float*)d_in[13];
    const float* fc2_b = (const float*)d_in[14];
    const float* bn3_g = (const float*)d_in[15];
    const float* bn3_b = (const float*)d_in[16];
    const float* bn3_m = (const float*)d_in[17];
    const float* bn3_v = (const float*)d_in[18];

    float* out = (float*)d_out;                  // xt scratch, overwritten by fc2

    // workspace layout (max concurrent ~153 MB, proven):
    //   region A [0, 77.07M):  dist8 (19.67M, chunked; dies after select16)
    //                          -> st (born at mr)
    //   region B [77.07, 154.14M): xn | sq | cand16 | cdist16 (die by refine)
    //                          -> gbuf (born at gconv)
    //   region C [154.14M, +): nnidx (1.81M) | amb (0.2M) | cnt (4B)
    char* wsb = (char*)d_ws;
    const size_t regionBytes = (size_t)Bn * C2c * Nn * 4;   // 77,070,336
    float* dist = (float*)wsb;
    float* st   = (float*)wsb;
    char*  g2   = wsb + regionBytes;
    float* xnb  = (float*)g2;                                      // 38,535,168 B
    float* sqb  = (float*)(g2 + (size_t)Bn * Cc * Nn * 4);         // 200,704 B
    int*   c16  = (int*)(g2 + (size_t)Bn * Cc * Nn * 4 + 200704);  // 3,211,264 B
    float* cd16 = (float*)(g2 + (size_t)Bn * Cc * Nn * 4 + 200704 + 3211264); // 3,211,264 B
    float* gbuf = (float*)g2;                                      // clobbers head (dead)
    char*  g3   = wsb + 2 * regionBytes;
    int*   nni  = (int*)g3;                                        // 1,806,336 B
    int*   amb  = (int*)(g3 + 1806336);                            // 200,704 B
    int*   cnt  = (int*)(g3 + 1806336 + 200704);                   // 4 B

    const long long nBCN = (long long)Bn * Cc * Nn;
    const int nBN = Bn * Nn;

    dim3 blk(256);
    fc1_np<<<dim3(13, 3, Bn), blk, 0, stream>>>(
        x, fc1_w, fc1_b, bn1_g, bn1_b, bn1_m, bn1_v, out);
    norm_np<<<dim3((nBN + 255) / 256), blk, 0, stream>>>(out, xnb, sqb);
    for (int ch = 0; ch < 8; ++ch) {
        dist_gemm<<<dim3(91, 8), blk, 0, stream>>>(xnb, dist, ch);
        select16<<<dim3(8 * Nn / 4), blk, 0, stream>>>(dist, c16, cd16, ch);
    }
    zero_cnt<<<dim3(1), dim3(64), 0, stream>>>(cnt);
    gap_route<<<dim3((nBN + 255) / 256), blk, 0, stream>>>(c16, cd16, nni, amb, cnt);
    refine_amb<<<dim3(196), blk, 0, stream>>>(xnb, sqb, c16, amb, cnt, nni);
    mr_naive<<<dim3((unsigned)((nBCN + 255) / 256)), blk, 0, stream>>>(out, nni, st);
    gconv_kernel<<<dim3(13, 12, Bn), blk, 0, stream>>>(
        st, gc_w, gc_b, bn2_g, bn2_b, bn2_m, bn2_v, gbuf);
    fc2_kernel<<<dim3(7, 3, Bn), blk, 0, stream>>>(
        gbuf, fc2_w, fc2_b, bn3_g, bn3_b, bn3_m, bn3_v, x, out);
}

// Round 11
// 882.164 us; speedup vs baseline: 1.3230x; 1.2005x over previous
//
#include <hip/hip_runtime.h>
#include <math.h>

static constexpr int Bn  = 64;    // batch
static constexpr int Cc  = 192;   // channels
static constexpr int Nn  = 784;   // H*W
static constexpr int C2c = 384;   // 2C
static constexpr int Kk  = 9;     // knn K
#define GAP_DELTA 1e-4f

// ===========================================================================
// INDEX PATH — np-f32 bit-exact where values matter (fc1, norm, refine_amb).
// ===========================================================================

// fc1_np: BIT-CRITICAL — numpy-f32-exact (no FMA, ascending-c accumulation).
// 64(o) x 128(n) tile, 4x8 per thread, split-half n indexing (2-way LDS).
__global__ __launch_bounds__(256) void fc1_np(
    const float* __restrict__ x, const float* __restrict__ w,
    const float* __restrict__ bias,
    const float* __restrict__ gg, const float* __restrict__ bb_,
    const float* __restrict__ mm, const float* __restrict__ vv,
    float* __restrict__ xt)
{
    __shared__ float As[16][64];
    __shared__ float Bs[16][128];
    const int b   = blockIdx.z;
    const int n0  = blockIdx.x * 128;
    const int o0  = blockIdx.y * 64;
    const int tid = threadIdx.x;
    const int tx = tid & 15, ty = tid >> 4;
    const int lo = tid & 63, lk4 = tid >> 6;
    const int ln4 = tid & 15, lbk = tid >> 4;
    const float* xb = x + (size_t)b * Cc * Nn;

    float acc[4][8];
#pragma unroll
    for (int i = 0; i < 4; ++i)
#pragma unroll
        for (int j = 0; j < 8; ++j) acc[i][j] = 0.f;

    for (int kt = 0; kt < 12; ++kt) {               // c ascending: kt*16 + kk
        const int k0 = kt * 16;
        float4 av = *reinterpret_cast<const float4*>(&w[(size_t)(o0 + lo) * 192 + k0 + lk4 * 4]);
        As[lk4*4+0][lo] = av.x;
        As[lk4*4+1][lo] = av.y;
        As[lk4*4+2][lo] = av.z;
        As[lk4*4+3][lo] = av.w;
        const int na = n0 + ln4 * 4;
        const int nb = n0 + 64 + ln4 * 4;
        float4 b0 = make_float4(0.f, 0.f, 0.f, 0.f);
        float4 b1 = make_float4(0.f, 0.f, 0.f, 0.f);
        if (na < Nn) b0 = *reinterpret_cast<const float4*>(&xb[(size_t)(k0 + lbk) * Nn + na]);
        if (nb < Nn) b1 = *reinterpret_cast<const float4*>(&xb[(size_t)(k0 + lbk) * Nn + nb]);
        *reinterpret_cast<float4*>(&Bs[lbk][ln4*4])      = b0;
        *reinterpret_cast<float4*>(&Bs[lbk][64 + ln4*4]) = b1;
        __syncthreads();
#pragma unroll
        for (int kk = 0; kk < 16; ++kk) {
            float ar[4], br[8];
#pragma unroll
            for (int i = 0; i < 4; ++i) ar[i] = As[kk][ty*4+i];
#pragma unroll
            for (int j = 0; j < 4; ++j) br[j]     = Bs[kk][tx*4+j];
#pragma unroll
            for (int j = 0; j < 4; ++j) br[4 + j] = Bs[kk][64 + tx*4+j];
#pragma unroll
            for (int i = 0; i < 4; ++i)
#pragma unroll
                for (int j = 0; j < 8; ++j)
                    acc[i][j] = __fadd_rn(acc[i][j], __fmul_rn(ar[i], br[j]));
        }
        __syncthreads();
    }
    const int na = n0 + tx * 4;
    const int nb = n0 + 64 + tx * 4;
#pragma unroll
    for (int i = 0; i < 4; ++i) {
        const int o = o0 + ty * 4 + i;
        const float e  = __fadd_rn(vv[o], 1e-5f);
        const float r1 = __fsqrt_rn(e);
        const float rr = __fdiv_rn(1.f, r1);
        const float s  = __fmul_rn(gg[o], rr);
        const size_t rowb = ((size_t)b * Cc + o) * Nn;
        if (na < Nn) {
#pragma unroll
            for (int j = 0; j < 4; ++j) {
                const float h = __fadd_rn(acc[i][j], bias[o]);
                const float t = __fsub_rn(h, mm[o]);
                const float u = __fmul_rn(t, s);
                xt[rowb + na + j] = __fadd_rn(u, bb_[o]);
            }
        }
        if (nb < Nn) {
#pragma unroll
            for (int j = 0; j < 4; ++j) {
                const float h = __fadd_rn(acc[i][4 + j], bias[o]);
                const float t = __fsub_rn(h, mm[o]);
                const float u = __fmul_rn(t, s);
                xt[rowb + nb + j] = __fadd_rn(u, bb_[o]);
            }
        }
    }
}

// norm_np: numpy-exact. BIT-CRITICAL. The sq pass reads back the just-written
// xn values (bit-identical to recomputing the division).
__global__ __launch_bounds__(256) void norm_np(
    const float* __restrict__ xt, float* __restrict__ xn, float* __restrict__ sq)
{
    const int idx = blockIdx.x * 256 + threadIdx.x;
    if (idx >= Bn * Nn) return;
    const int n = idx % Nn;
    const int b = idx / Nn;
    const float* p = xt + (size_t)b * Cc * Nn + n;

    float acc = 0.f;
    for (int c = 0; c < Cc; ++c) {
        const float v = p[(size_t)c * Nn];
        acc = __fadd_rn(acc, __fmul_rn(v, v));
    }
    float nrm = __fsqrt_rn(acc);
    nrm = fmaxf(nrm, 1e-12f);

    float* q = xn + (size_t)b * Cc * Nn + n;
    for (int c = 0; c < Cc; ++c)
        q[(size_t)c * Nn] = __fdiv_rn(p[(size_t)c * Nn], nrm);

    float sblk[2];
#pragma unroll
    for (int blk = 0; blk < 2; ++blk) {
        const int base = blk * 96;
        float r[8];
#pragma unroll
        for (int j = 0; j < 8; ++j) {
            const float xv = q[(size_t)(base + j) * Nn];
            r[j] = __fmul_rn(xv, xv);
        }
        for (int i = 8; i < 96; i += 8) {
#pragma unroll
            for (int j = 0; j < 8; ++j) {
                const float xv = q[(size_t)(base + i + j) * Nn];
                r[j] = __fadd_rn(r[j], __fmul_rn(xv, xv));
            }
        }
        sblk[blk] = __fadd_rn(__fadd_rn(__fadd_rn(r[0], r[1]), __fadd_rn(r[2], r[3])),
                              __fadd_rn(__fadd_rn(r[4], r[5]), __fadd_rn(r[6], r[7])));
    }
    sq[idx] = __fadd_rn(sblk[0], sblk[1]);
}

// dist_gemm: symmetric fast filter — only rt<=mt tiles computed; the mirror
// tile is produced by an LDS transpose. dist[b16][r][m] = -dot(xn_r, xn_m).
__global__ __launch_bounds__(256) void dist_gemm(
    const float* __restrict__ xn, float* __restrict__ dist, int bchunk)
{
    __shared__ float As[16][64];
    __shared__ float Bs[16][64];
    __shared__ float Ds[64][65];
    const int bt = blockIdx.x;             // 0..90 (upper-triangle tiles)
    int rt = 0, rem = bt;
    while (rem >= 13 - rt) { rem -= 13 - rt; ++rt; }
    const int mt = rt + rem;
    const int bc = blockIdx.y;             // 0..15
    const int b  = bchunk * 16 + bc;
    const int r0 = rt * 64, m0 = mt * 64;
    const int tid = threadIdx.x;
    const int tx = tid & 15, ty = tid >> 4;
    const int lo = tid & 63, lk4 = tid >> 6;
    const float* xb = xn + (size_t)b * Cc * Nn;

    float acc[4][4];
#pragma unroll
    for (int i = 0; i < 4; ++i)
#pragma unroll
        for (int j = 0; j < 4; ++j) acc[i][j] = 0.f;

    for (int kt = 0; kt < 12; ++kt) {
        const int k0 = kt * 16;
        const int r = r0 + lo, m = m0 + lo;
#pragma unroll
        for (int j = 0; j < 4; ++j) {
            const int kc = k0 + lk4 * 4 + j;
            As[lk4*4+j][lo] = (r < Nn) ? xb[(size_t)kc * Nn + r] : 0.f;
            Bs[lk4*4+j][lo] = (m < Nn) ? xb[(size_t)kc * Nn + m] : 0.f;
        }
        __syncthreads();
#pragma unroll
        for (int kk = 0; kk < 16; ++kk) {
            float4 a  = *reinterpret_cast<const float4*>(&As[kk][ty*4]);
            float4 bq = *reinterpret_cast<const float4*>(&Bs[kk][tx*4]);
            float ar[4] = {a.x, a.y, a.z, a.w};
            float br[4] = {bq.x, bq.y, bq.z, bq.w};
#pragma unroll
            for (int i = 0; i < 4; ++i)
#pragma unroll
                for (int j = 0; j < 4; ++j)
                    acc[i][j] = fmaf(ar[i], br[j], acc[i][j]);
        }
        __syncthreads();
    }
    float* db = dist + (size_t)bc * Nn * Nn;
    // normal tile: rows r (coalesced float4 along m)
    {
        const int m = m0 + tx * 4;
        if (m < Nn) {
#pragma unroll
            for (int i = 0; i < 4; ++i) {
                const int r = r0 + ty * 4 + i;
                if (r < Nn) {
                    float4 o = make_float4(-acc[i][0], -acc[i][1], -acc[i][2], -acc[i][3]);
                    *reinterpret_cast<float4*>(&db[(size_t)r * Nn + m]) = o;
                }
            }
        }
    }
    // mirror tile (rt<mt): transpose via LDS, then coalesced float4 along r
    if (rt != mt) {
#pragma unroll
        for (int i = 0; i < 4; ++i)
#pragma unroll
            for (int j = 0; j < 4; ++j)
                Ds[ty*4+i][tx*4+j] = -acc[i][j];
        __syncthreads();
        const int rcol = r0 + tx * 4;      // full r-tiles only when rt<mt<=12
#pragma unroll
        for (int i = 0; i < 4; ++i) {
            const int mrow = m0 + ty * 4 + i;
            if (mrow < Nn) {
                float4 o = make_float4(Ds[tx*4+0][ty*4+i], Ds[tx*4+1][ty*4+i],
                                       Ds[tx*4+2][ty*4+i], Ds[tx*4+3][ty*4+i]);
                *reinterpret_cast<float4*>(&db[(size_t)mrow * Nn + rcol]) = o;
            }
        }
    }
}

// select16: one wave per row; 16x argmin-extract via shfl_xor; writes sorted
// candidate indices AND their fast dists.
__global__ __launch_bounds__(256) void select16(
    const float* __restrict__ dist, int* __restrict__ cand,
    float* __restrict__ cdist, int bchunk)
{
    const int wid = blockIdx.x * 4 + (threadIdx.x >> 6);   // wave id in chunk
    const int L   = threadIdx.x & 63;
    const int r   = wid % Nn;
    const int bc  = wid / Nn;
    const int b   = bchunk * 16 + bc;
    const float* drow = dist + ((size_t)bc * Nn + r) * Nn;

    float v[13];
#pragma unroll
    for (int s = 0; s < 12; ++s) v[s] = drow[s * 64 + L];
    v[12] = (L < 16) ? drow[768 + L] : INFINITY;

    float mv = v[0]; int ms = 0;
#pragma unroll
    for (int s = 1; s < 13; ++s)
        if (v[s] < mv) { mv = v[s]; ms = s; }

    int out[16];
    float vals[16];
#pragma unroll
    for (int k = 0; k < 16; ++k) {
        float gv = mv; int gi = ms * 64 + L;
#pragma unroll
        for (int off = 1; off < 64; off <<= 1) {
            const float ov = __shfl_xor(gv, off, 64);
            const int   oi = __shfl_xor(gi, off, 64);
            if (ov < gv || (ov == gv && oi < gi)) { gv = ov; gi = oi; }
        }
        out[k] = gi; vals[k] = gv;
        const int ol = gi & 63, os = gi >> 6;
        if (L == ol) {
#pragma unroll
            for (int s = 0; s < 13; ++s) if (s == os) v[s] = INFINITY;
            mv = v[0]; ms = 0;
#pragma unroll
            for (int s = 1; s < 13; ++s)
                if (v[s] < mv) { mv = v[s]; ms = s; }
        }
    }
    if (L == 0) {
        int*   op = cand  + ((size_t)b * Nn + r) * 16;
        float* dp = cdist + ((size_t)b * Nn + r) * 16;
#pragma unroll
        for (int k = 0; k < 16; ++k) { op[k] = out[k]; dp[k] = vals[k]; }
    }
}

// zero_cnt: reset the ambiguous-row counter each launch (determinism).
__global__ void zero_cnt(int* cnt) { if (threadIdx.x == 0 && blockIdx.x == 0) *cnt = 0; }

// gap_route: clear-gap rows resolved directly from fast candidates; knife-edge
// rows appended to the ambiguous list.
__global__ __launch_bounds__(256) void gap_route(
    const int* __restrict__ cand, const float* __restrict__ cdist,
    int* __restrict__ nnidx, int* __restrict__ amb, int* __restrict__ cnt)
{
    const int idx = blockIdx.x * 256 + threadIdx.x;
    if (idx >= Bn * Nn) return;
    const float* dp = cdist + (size_t)idx * 16;
    const float d8 = dp[8], d9 = dp[9];
    if (d9 - d8 > GAP_DELTA) {
        const int* cp = cand + (size_t)idx * 16;
        int* op = nnidx + (size_t)idx * Kk;
#pragma unroll
        for (int k = 0; k < Kk; ++k) op[k] = cp[k];
    } else {
        const int pos = atomicAdd(cnt, 1);
        amb[pos] = idx;
    }
}

// refine_amb: EXACT np-f32 re-rank for ambiguous rows; chunked register
// prefetch (independent loads), exact sequential ascending-c adds.
__global__ __launch_bounds__(256) void refine_amb(
    const float* __restrict__ xn, const float* __restrict__ sq,
    const int* __restrict__ cand, const int* __restrict__ amb,
    const int* __restrict__ cnt, int* __restrict__ nnidx)
{
    __shared__ float Dd[16][16];
    __shared__ int   Dm[16][16];
    const int total = *cnt;
    const int rl = threadIdx.x >> 4;     // row slot in block
    const int k  = threadIdx.x & 15;     // candidate slot

    for (int base = blockIdx.x * 16; base < total; base += gridDim.x * 16) {
        const int slot = base + rl;
        int rowid = 0;
        const bool active = slot < total;
        if (active) rowid = amb[slot];
        const int b = rowid / Nn, r = rowid % Nn;
        const float* xb  = xn + (size_t)b * Cc * Nn;
        const float* sqb = sq + (size_t)b * Nn;

        if (active) {
            const int m = cand[((size_t)b * Nn + r) * 16 + k];
            float dot = 0.f;
            for (int cc = 0; cc < 12; ++cc) {
                float va[16], vb[16];
#pragma unroll
                for (int j = 0; j < 16; ++j) {
                    va[j] = xb[(size_t)(cc * 16 + j) * Nn + r];
                    vb[j] = xb[(size_t)(cc * 16 + j) * Nn + m];
                }
#pragma unroll
                for (int j = 0; j < 16; ++j)
                    dot = __fadd_rn(dot, __fmul_rn(va[j], vb[j]));
            }
            const float t1 = __fmul_rn(2.f, dot);
            const float t2 = __fsub_rn(sqb[r], t1);
            Dd[rl][k] = __fadd_rn(t2, sqb[m]);
            Dm[rl][k] = m;
        }
        __syncthreads();
        if (active && k == 0) {
            float dl[16]; int il[16];
#pragma unroll
            for (int j = 0; j < 16; ++j) { dl[j] = Dd[rl][j]; il[j] = Dm[rl][j]; }
            int* op = nnidx + (size_t)rowid * Kk;
            for (int kk = 0; kk < Kk; ++kk) {
                int best = kk;
                for (int j = kk + 1; j < 16; ++j)
                    if (dl[j] < dl[best] || (dl[j] == dl[best] && il[j] < il[best])) best = j;
                float td = dl[kk]; dl[kk] = dl[best]; dl[best] = td;
                int ti = il[kk]; il[kk] = il[best]; il[best] = ti;
                op[kk] = il[kk];
            }
        }
        __syncthreads();
    }
}

// ===========================================================================
// VALUE PATH — fast f32 (fmaf ok; error ~1e-5 << threshold 0.14)
// ===========================================================================

__global__ __launch_bounds__(256) void mr_naive(
    const float* __restrict__ xt, const int* __restrict__ nnidx,
    float* __restrict__ st)
{
    const long long idx = (long long)blockIdx.x * 256 + threadIdx.x;
    if (idx >= (long long)Bn * Cc * Nn) return;
    const int n = (int)(idx % Nn);
    const int c = (int)((idx / Nn) % Cc);
    const int b = (int)(idx / ((long long)Cc * Nn));
    const float* row = xt + ((size_t)b * Cc + c) * Nn;
    const float ctr = row[n];
    const int* ip = nnidx + ((size_t)b * Nn + n) * Kk;
    float mx = -INFINITY;
    for (int k = 0; k < Kk; ++k) {
        const float v = __fsub_rn(row[ip[k]], ctr);
        if (v > mx) mx = v;
    }
    st[((size_t)b * C2c + 2 * c) * Nn + n]     = ctr;
    st[((size_t)b * C2c + 2 * c + 1) * Nn + n] = mx;
}

__global__ __launch_bounds__(256) void gconv_kernel(
    const float* __restrict__ st, const float* __restrict__ gw,
    const float* __restrict__ gb,
    const float* __restrict__ gg, const float* __restrict__ bb_,
    const float* __restrict__ mm, const float* __restrict__ vv,
    float* __restrict__ out)
{
    __shared__ float As[16][32];
    __shared__ float Bs[16][64];
    const int b   = blockIdx.z;
    const int n0  = blockIdx.x * 64;
    const int grp = blockIdx.y / 3;
    const int o0  = (blockIdx.y % 3) * 32;
    const int tid = threadIdx.x;
    const int tx = tid & 15, ty = tid >> 4;
    const int lo = tid & 31, lk2 = tid >> 5;
    const int ln4 = tid & 15, lbk = tid >> 4;
    const float* stb = st + (size_t)b * C2c * Nn + (size_t)grp * 96 * Nn;
    const float* wgp = gw + (size_t)grp * 96 * 96;

    float acc[2][4];
#pragma unroll
    for (int i = 0; i < 2; ++i)
#pragma unroll
        for (int j = 0; j < 4; ++j) acc[i][j] = 0.f;

    for (int kt = 0; kt < 6; ++kt) {
        const int k0 = kt * 16;
        float2 av = *reinterpret_cast<const float2*>(&wgp[(size_t)(o0 + lo) * 96 + k0 + lk2 * 2]);
        As[lk2*2+0][lo] = av.x;
        As[lk2*2+1][lo] = av.y;
        const int n = n0 + ln4 * 4;
        float4 bv = make_float4(0.f, 0.f, 0.f, 0.f);
        if (n < Nn) bv = *reinterpret_cast<const float4*>(&stb[(size_t)(k0 + lbk) * Nn + n]);
        *reinterpret_cast<float4*>(&Bs[lbk][ln4*4]) = bv;
        __syncthreads();
#pragma unroll
        for (int kk = 0; kk < 16; ++kk) {
            float2 a  = *reinterpret_cast<const float2*>(&As[kk][ty*2]);
            float4 bq = *reinterpret_cast<const float4*>(&Bs[kk][tx*4]);
            float ar[2] = {a.x, a.y};
            float br[4] = {bq.x, bq.y, bq.z, bq.w};
#pragma unroll
            for (int i = 0; i < 2; ++i)
#pragma unroll
                for (int j = 0; j < 4; ++j)
                    acc[i][j] = fmaf(ar[i], br[j], acc[i][j]);
        }
        __syncthreads();
    }
    const int n = n0 + tx * 4;
    if (n < Nn) {
#pragma unroll
        for (int i = 0; i < 2; ++i) {
            const int oc = grp * 96 + o0 + ty * 2 + i;
            const float s  = gg[oc] * rsqrtf(vv[oc] + 1e-5f);
            const float sh = (gb[oc] - mm[oc]) * s + bb_[oc];
            float r[4];
#pragma unroll
            for (int j = 0; j < 4; ++j) {
                float v = fmaf(acc[i][j], s, sh);
                r[j] = 0.5f * v * (1.f + erff(v * 0.70710678118654752f));
            }
            float4 rv = make_float4(r[0], r[1], r[2], r[3]);
            *reinterpret_cast<float4*>(&out[((size_t)b * C2c + oc) * Nn + n]) = rv;
        }
    }
}

// fc2 + BN3 + residual: 64(o) x 128(n) tile, 4x8 per thread, split-half n
// indexing so all LDS accesses keep the free 2-way pattern.
__global__ __launch_bounds__(256) void fc2_kernel(
    const float* __restrict__ gin, const float* __restrict__ w,
    const float* __restrict__ bias,
    const float* __restrict__ gg, const float* __restrict__ bb_,
    const float* __restrict__ mm, const float* __restrict__ vv,
    const float* __restrict__ xres,
    float* __restrict__ out)
{
    __shared__ float As[16][64];
    __shared__ float Bs[16][128];
    const int b   = blockIdx.z;
    const int n0  = blockIdx.x * 128;
    const int o0  = blockIdx.y * 64;
    const int tid = threadIdx.x;
    const int tx = tid & 15, ty = tid >> 4;
    const int lo = tid & 63, lk4 = tid >> 6;
    const int ln4 = tid & 15, lbk = tid >> 4;
    const float* gbp = gin + (size_t)b * C2c * Nn;
    const float* xb  = xres + (size_t)b * Cc * Nn;

    float acc[4][8];
#pragma unroll
    for (int i = 0; i < 4; ++i)
#pragma unroll
        for (int j = 0; j < 8; ++j) acc[i][j] = 0.f;

    for (int kt = 0; kt < 24; ++kt) {
        const int k0 = kt * 16;
        float4 av = *reinterpret_cast<const float4*>(&w[(size_t)(o0 + lo) * 384 + k0 + lk4 * 4]);
        As[lk4*4+0][lo] = av.x;
        As[lk4*4+1][lo] = av.y;
        As[lk4*4+2][lo] = av.z;
        As[lk4*4+3][lo] = av.w;
        const int na = n0 + ln4 * 4;
        const int nb = n0 + 64 + ln4 * 4;
        float4 b0 = make_float4(0.f, 0.f, 0.f, 0.f);
        float4 b1 = make_float4(0.f, 0.f, 0.f, 0.f);
        if (na < Nn) b0 = *reinterpret_cast<const float4*>(&gbp[(size_t)(k0 + lbk) * Nn + na]);
        if (nb < Nn) b1 = *reinterpret_cast<const float4*>(&gbp[(size_t)(k0 + lbk) * Nn + nb]);
        *reinterpret_cast<float4*>(&Bs[lbk][ln4*4])      = b0;
        *reinterpret_cast<float4*>(&Bs[lbk][64 + ln4*4]) = b1;
        __syncthreads();
#pragma unroll
        for (int kk = 0; kk < 16; ++kk) {
            float4 a  = *reinterpret_cast<const float4*>(&As[kk][ty*4]);
            float4 q0 = *reinterpret_cast<const float4*>(&Bs[kk][tx*4]);
            float4 q1 = *reinterpret_cast<const float4*>(&Bs[kk][64 + tx*4]);
            float ar[4] = {a.x, a.y, a.z, a.w};
            float br[8] = {q0.x, q0.y, q0.z, q0.w, q1.x, q1.y, q1.z, q1.w};
#pragma unroll
            for (int i = 0; i < 4; ++i)
#pragma unroll
                for (int j = 0; j < 8; ++j)
                    acc[i][j] = fmaf(ar[i], br[j], acc[i][j]);
        }
        __syncthreads();
    }
    const int na = n0 + tx * 4;
    const int nb = n0 + 64 + tx * 4;
#pragma unroll
    for (int i = 0; i < 4; ++i) {
        const int o = o0 + ty * 4 + i;
        const float s  = gg[o] * rsqrtf(vv[o] + 1e-5f);
        const float sh = (bias[o] - mm[o]) * s + bb_[o];
        const size_t rowb = (size_t)o * Nn;
        if (na < Nn) {
            float4 x0 = *reinterpret_cast<const float4*>(&xb[rowb + na]);
            float4 r0;
            r0.x = fmaf(acc[i][0], s, sh) + x0.x;
            r0.y = fmaf(acc[i][1], s, sh) + x0.y;
            r0.z = fmaf(acc[i][2], s, sh) + x0.z;
            r0.w = fmaf(acc[i][3], s, sh) + x0.w;
            *reinterpret_cast<float4*>(&out[((size_t)b * Cc) * Nn + rowb + na]) = r0;
        }
        if (nb < Nn) {
            float4 x1 = *reinterpret_cast<const float4*>(&xb[rowb + nb]);
            float4 r1;
            r1.x = fmaf(acc[i][4], s, sh) + x1.x;
            r1.y = fmaf(acc[i][5], s, sh) + x1.y;
            r1.z = fmaf(acc[i][6], s, sh) + x1.z;
            r1.w = fmaf(acc[i][7], s, sh) + x1.w;
            *reinterpret_cast<float4*>(&out[((size_t)b * Cc) * Nn + rowb + nb]) = r1;
        }
    }
}

// ---------------------------------------------------------------------------
extern "C" void kernel_launch(void* const* d_in, const int* in_sizes, int n_in,
                              void* d_out, int out_size, void* d_ws, size_t ws_size,
                              hipStream_t stream)
{
    const float* x     = (const float*)d_in[0];
    const float* fc1_w = (const float*)d_in[1];
    const float* fc1_b = (const float*)d_in[2];
    const float* bn1_g = (const float*)d_in[3];
    const float* bn1_b = (const float*)d_in[4];
    const float* bn1_m = (const float*)d_in[5];
    const float* bn1_v = (const float*)d_in[6];
    const float* gc_w  = (const float*)d_in[7];
    const float* gc_b  = (const float*)d_in[8];
    const float* bn2_g = (const float*)d_in[9];
    const float* bn2_b = (const float*)d_in[10];
    const float* bn2_m = (const float*)d_in[11];
    const float* bn2_v = (const float*)d_in[12];
    const float* fc2_w = (const float*)d_in[13];
    const float* fc2_b = (const float*)d_in[14];
    const float* bn3_g = (const float*)d_in[15];
    const float* bn3_b = (const float*)d_in[16];
    const float* bn3_m = (const float*)d_in[17];
    const float* bn3_v = (const float*)d_in[18];

    float* out = (float*)d_out;                  // xt scratch, overwritten by fc2

    // workspace layout (max concurrent ~153 MB, proven):
    //   region A [0, 77.07M):  dist16 (39.34M, 4 chunks; dies after select16)
    //                          -> st (born at mr)
    //   region B [77.07, 154.14M): xn | sq | cand16 | cdist16 (die by refine)
    //                          -> gbuf (born at gconv)
    //   region C [154.14M, +): nnidx (1.81M) | amb (0.2M) | cnt (4B)
    char* wsb = (char*)d_ws;
    const size_t regionBytes = (size_t)Bn * C2c * Nn * 4;   // 77,070,336
    float* dist = (float*)wsb;
    float* st   = (float*)wsb;
    char*  g2   = wsb + regionBytes;
    float* xnb  = (float*)g2;                                      // 38,535,168 B
    float* sqb  = (float*)(g2 + (size_t)Bn * Cc * Nn * 4);         // 200,704 B
    int*   c16  = (int*)(g2 + (size_t)Bn * Cc * Nn * 4 + 200704);  // 3,211,264 B
    float* cd16 = (float*)(g2 + (size_t)Bn * Cc * Nn * 4 + 200704 + 3211264); // 3,211,264 B
    float* gbuf = (float*)g2;                                      // clobbers head (dead)
    char*  g3   = wsb + 2 * regionBytes;
    int*   nni  = (int*)g3;                                        // 1,806,336 B
    int*   amb  = (int*)(g3 + 1806336);                            // 200,704 B
    int*   cnt  = (int*)(g3 + 1806336 + 200704);                   // 4 B

    const long long nBCN = (long long)Bn * Cc * Nn;
    const int nBN = Bn * Nn;

    dim3 blk(256);
    fc1_np<<<dim3(7, 3, Bn), blk, 0, stream>>>(
        x, fc1_w, fc1_b, bn1_g, bn1_b, bn1_m, bn1_v, out);
    norm_np<<<dim3((nBN + 255) / 256), blk, 0, stream>>>(out, xnb, sqb);
    for (int ch = 0; ch < 4; ++ch) {
        dist_gemm<<<dim3(91, 16), blk, 0, stream>>>(xnb, dist, ch);
        select16<<<dim3(16 * Nn / 4), blk, 0, stream>>>(dist, c16, cd16, ch);
    }
    zero_cnt<<<dim3(1), dim3(64), 0, stream>>>(cnt);
    gap_route<<<dim3((nBN + 255) / 256), blk, 0, stream>>>(c16, cd16, nni, amb, cnt);
    refine_amb<<<dim3(196), blk, 0, stream>>>(xnb, sqb, c16, amb, cnt, nni);
    mr_naive<<<dim3((unsigned)((nBCN + 255) / 256)), blk, 0, stream>>>(out, nni, st);
    gconv_kernel<<<dim3(13, 12, Bn), blk, 0, stream>>>(
        st, gc_w, gc_b, bn2_g, bn2_b, bn2_m, bn2_v, gbuf);
    fc2_kernel<<<dim3(7, 3, Bn), blk, 0, stream>>>(
        gbuf, fc2_w, fc2_b, bn3_g, bn3_b, bn3_m, bn3_v, x, out);
}

// Round 12
// 839.496 us; speedup vs baseline: 1.3902x; 1.0508x over previous
//
#include <hip/hip_runtime.h>
#include <math.h>

static constexpr int Bn  = 64;    // batch
static constexpr int Cc  = 192;   // channels
static constexpr int Nn  = 784;   // H*W
static constexpr int C2c = 384;   // 2C
static constexpr int Kk  = 9;     // knn K
#define GAP_DELTA 1e-4f

typedef __attribute__((ext_vector_type(8))) short bf16x8;
typedef __attribute__((ext_vector_type(4))) float f32x4;

__device__ inline unsigned short f2bf(float f) {   // RNE f32 -> bf16
    unsigned int u = __float_as_uint(f);
    return (unsigned short)((u + 0x7FFFu + ((u >> 16) & 1u)) >> 16);
}

// ===========================================================================
// INDEX PATH — np-f32 bit-exact where values matter (fc1, norm, refine_amb).
// ===========================================================================

// fc1_np: BIT-CRITICAL — numpy-f32-exact (no FMA, ascending-c accumulation).
__global__ __launch_bounds__(256) void fc1_np(
    const float* __restrict__ x, const float* __restrict__ w,
    const float* __restrict__ bias,
    const float* __restrict__ gg, const float* __restrict__ bb_,
    const float* __restrict__ mm, const float* __restrict__ vv,
    float* __restrict__ xt)
{
    __shared__ float As[16][64];
    __shared__ float Bs[16][128];
    const int b   = blockIdx.z;
    const int n0  = blockIdx.x * 128;
    const int o0  = blockIdx.y * 64;
    const int tid = threadIdx.x;
    const int tx = tid & 15, ty = tid >> 4;
    const int lo = tid & 63, lk4 = tid >> 6;
    const int ln4 = tid & 15, lbk = tid >> 4;
    const float* xb = x + (size_t)b * Cc * Nn;

    float acc[4][8];
#pragma unroll
    for (int i = 0; i < 4; ++i)
#pragma unroll
        for (int j = 0; j < 8; ++j) acc[i][j] = 0.f;

    for (int kt = 0; kt < 12; ++kt) {               // c ascending: kt*16 + kk
        const int k0 = kt * 16;
        float4 av = *reinterpret_cast<const float4*>(&w[(size_t)(o0 + lo) * 192 + k0 + lk4 * 4]);
        As[lk4*4+0][lo] = av.x;
        As[lk4*4+1][lo] = av.y;
        As[lk4*4+2][lo] = av.z;
        As[lk4*4+3][lo] = av.w;
        const int na = n0 + ln4 * 4;
        const int nb = n0 + 64 + ln4 * 4;
        float4 b0 = make_float4(0.f, 0.f, 0.f, 0.f);
        float4 b1 = make_float4(0.f, 0.f, 0.f, 0.f);
        if (na < Nn) b0 = *reinterpret_cast<const float4*>(&xb[(size_t)(k0 + lbk) * Nn + na]);
        if (nb < Nn) b1 = *reinterpret_cast<const float4*>(&xb[(size_t)(k0 + lbk) * Nn + nb]);
        *reinterpret_cast<float4*>(&Bs[lbk][ln4*4])      = b0;
        *reinterpret_cast<float4*>(&Bs[lbk][64 + ln4*4]) = b1;
        __syncthreads();
#pragma unroll
        for (int kk = 0; kk < 16; ++kk) {
            float ar[4], br[8];
#pragma unroll
            for (int i = 0; i < 4; ++i) ar[i] = As[kk][ty*4+i];
#pragma unroll
            for (int j = 0; j < 4; ++j) br[j]     = Bs[kk][tx*4+j];
#pragma unroll
            for (int j = 0; j < 4; ++j) br[4 + j] = Bs[kk][64 + tx*4+j];
#pragma unroll
            for (int i = 0; i < 4; ++i)
#pragma unroll
                for (int j = 0; j < 8; ++j)
                    acc[i][j] = __fadd_rn(acc[i][j], __fmul_rn(ar[i], br[j]));
        }
        __syncthreads();
    }
    const int na = n0 + tx * 4;
    const int nb = n0 + 64 + tx * 4;
#pragma unroll
    for (int i = 0; i < 4; ++i) {
        const int o = o0 + ty * 4 + i;
        const float e  = __fadd_rn(vv[o], 1e-5f);
        const float r1 = __fsqrt_rn(e);
        const float rr = __fdiv_rn(1.f, r1);
        const float s  = __fmul_rn(gg[o], rr);
        const size_t rowb = ((size_t)b * Cc + o) * Nn;
        if (na < Nn) {
#pragma unroll
            for (int j = 0; j < 4; ++j) {
                const float h = __fadd_rn(acc[i][j], bias[o]);
                const float t = __fsub_rn(h, mm[o]);
                const float u = __fmul_rn(t, s);
                xt[rowb + na + j] = __fadd_rn(u, bb_[o]);
            }
        }
        if (nb < Nn) {
#pragma unroll
            for (int j = 0; j < 4; ++j) {
                const float h = __fadd_rn(acc[i][4 + j], bias[o]);
                const float t = __fsub_rn(h, mm[o]);
                const float u = __fmul_rn(t, s);
                xt[rowb + nb + j] = __fadd_rn(u, bb_[o]);
            }
        }
    }
}

// norm_np: numpy-exact. BIT-CRITICAL.
__global__ __launch_bounds__(256) void norm_np(
    const float* __restrict__ xt, float* __restrict__ xn, float* __restrict__ sq)
{
    const int idx = blockIdx.x * 256 + threadIdx.x;
    if (idx >= Bn * Nn) return;
    const int n = idx % Nn;
    const int b = idx / Nn;
    const float* p = xt + (size_t)b * Cc * Nn + n;

    float acc = 0.f;
    for (int c = 0; c < Cc; ++c) {
        const float v = p[(size_t)c * Nn];
        acc = __fadd_rn(acc, __fmul_rn(v, v));
    }
    float nrm = __fsqrt_rn(acc);
    nrm = fmaxf(nrm, 1e-12f);

    float* q = xn + (size_t)b * Cc * Nn + n;
    for (int c = 0; c < Cc; ++c)
        q[(size_t)c * Nn] = __fdiv_rn(p[(size_t)c * Nn], nrm);

    float sblk[2];
#pragma unroll
    for (int blk = 0; blk < 2; ++blk) {
        const int base = blk * 96;
        float r[8];
#pragma unroll
        for (int j = 0; j < 8; ++j) {
            const float xv = q[(size_t)(base + j) * Nn];
            r[j] = __fmul_rn(xv, xv);
        }
        for (int i = 8; i < 96; i += 8) {
#pragma unroll
            for (int j = 0; j < 8; ++j) {
                const float xv = q[(size_t)(base + i + j) * Nn];
                r[j] = __fadd_rn(r[j], __fmul_rn(xv, xv));
            }
        }
        sblk[blk] = __fadd_rn(__fadd_rn(__fadd_rn(r[0], r[1]), __fadd_rn(r[2], r[3])),
                              __fadd_rn(__fadd_rn(r[4], r[5]), __fadd_rn(r[6], r[7])));
    }
    sq[idx] = __fadd_rn(sblk[0], sblk[1]);
}

// dist_gemm: symmetric fast filter — only rt<=mt tiles computed; the mirror
// tile is produced by an LDS transpose. dist[b16][r][m] = -dot(xn_r, xn_m).
__global__ __launch_bounds__(256) void dist_gemm(
    const float* __restrict__ xn, float* __restrict__ dist, int bchunk)
{
    __shared__ float As[16][64];
    __shared__ float Bs[16][64];
    __shared__ float Ds[64][65];
    const int bt = blockIdx.x;             // 0..90 (upper-triangle tiles)
    int rt = 0, rem = bt;
    while (rem >= 13 - rt) { rem -= 13 - rt; ++rt; }
    const int mt = rt + rem;
    const int bc = blockIdx.y;             // 0..15
    const int b  = bchunk * 16 + bc;
    const int r0 = rt * 64, m0 = mt * 64;
    const int tid = threadIdx.x;
    const int tx = tid & 15, ty = tid >> 4;
    const int lo = tid & 63, lk4 = tid >> 6;
    const float* xb = xn + (size_t)b * Cc * Nn;

    float acc[4][4];
#pragma unroll
    for (int i = 0; i < 4; ++i)
#pragma unroll
        for (int j = 0; j < 4; ++j) acc[i][j] = 0.f;

    for (int kt = 0; kt < 12; ++kt) {
        const int k0 = kt * 16;
        const int r = r0 + lo, m = m0 + lo;
#pragma unroll
        for (int j = 0; j < 4; ++j) {
            const int kc = k0 + lk4 * 4 + j;
            As[lk4*4+j][lo] = (r < Nn) ? xb[(size_t)kc * Nn + r] : 0.f;
            Bs[lk4*4+j][lo] = (m < Nn) ? xb[(size_t)kc * Nn + m] : 0.f;
        }
        __syncthreads();
#pragma unroll
        for (int kk = 0; kk < 16; ++kk) {
            float4 a  = *reinterpret_cast<const float4*>(&As[kk][ty*4]);
            float4 bq = *reinterpret_cast<const float4*>(&Bs[kk][tx*4]);
            float ar[4] = {a.x, a.y, a.z, a.w};
            float br[4] = {bq.x, bq.y, bq.z, bq.w};
#pragma unroll
            for (int i = 0; i < 4; ++i)
#pragma unroll
                for (int j = 0; j < 4; ++j)
                    acc[i][j] = fmaf(ar[i], br[j], acc[i][j]);
        }
        __syncthreads();
    }
    float* db = dist + (size_t)bc * Nn * Nn;
    {
        const int m = m0 + tx * 4;
        if (m < Nn) {
#pragma unroll
            for (int i = 0; i < 4; ++i) {
                const int r = r0 + ty * 4 + i;
                if (r < Nn) {
                    float4 o = make_float4(-acc[i][0], -acc[i][1], -acc[i][2], -acc[i][3]);
                    *reinterpret_cast<float4*>(&db[(size_t)r * Nn + m]) = o;
                }
            }
        }
    }
    if (rt != mt) {
#pragma unroll
        for (int i = 0; i < 4; ++i)
#pragma unroll
            for (int j = 0; j < 4; ++j)
                Ds[ty*4+i][tx*4+j] = -acc[i][j];
        __syncthreads();
        const int rcol = r0 + tx * 4;      // full r-tiles only when rt<mt<=12
#pragma unroll
        for (int i = 0; i < 4; ++i) {
            const int mrow = m0 + ty * 4 + i;
            if (mrow < Nn) {
                float4 o = make_float4(Ds[tx*4+0][ty*4+i], Ds[tx*4+1][ty*4+i],
                                       Ds[tx*4+2][ty*4+i], Ds[tx*4+3][ty*4+i]);
                *reinterpret_cast<float4*>(&db[(size_t)mrow * Nn + rcol]) = o;
            }
        }
    }
}

// select16: one wave per row; 16x argmin-extract via shfl_xor; writes sorted
// candidate indices AND their fast dists.
__global__ __launch_bounds__(256) void select16(
    const float* __restrict__ dist, int* __restrict__ cand,
    float* __restrict__ cdist, int bchunk)
{
    const int wid = blockIdx.x * 4 + (threadIdx.x >> 6);   // wave id in chunk
    const int L   = threadIdx.x & 63;
    const int r   = wid % Nn;
    const int bc  = wid / Nn;
    const int b   = bchunk * 16 + bc;
    const float* drow = dist + ((size_t)bc * Nn + r) * Nn;

    float v[13];
#pragma unroll
    for (int s = 0; s < 12; ++s) v[s] = drow[s * 64 + L];
    v[12] = (L < 16) ? drow[768 + L] : INFINITY;

    float mv = v[0]; int ms = 0;
#pragma unroll
    for (int s = 1; s < 13; ++s)
        if (v[s] < mv) { mv = v[s]; ms = s; }

    int out[16];
    float vals[16];
#pragma unroll
    for (int k = 0; k < 16; ++k) {
        float gv = mv; int gi = ms * 64 + L;
#pragma unroll
        for (int off = 1; off < 64; off <<= 1) {
            const float ov = __shfl_xor(gv, off, 64);
            const int   oi = __shfl_xor(gi, off, 64);
            if (ov < gv || (ov == gv && oi < gi)) { gv = ov; gi = oi; }
        }
        out[k] = gi; vals[k] = gv;
        const int ol = gi & 63, os = gi >> 6;
        if (L == ol) {
#pragma unroll
            for (int s = 0; s < 13; ++s) if (s == os) v[s] = INFINITY;
            mv = v[0]; ms = 0;
#pragma unroll
            for (int s = 1; s < 13; ++s)
                if (v[s] < mv) { mv = v[s]; ms = s; }
        }
    }
    if (L == 0) {
        int*   op = cand  + ((size_t)b * Nn + r) * 16;
        float* dp = cdist + ((size_t)b * Nn + r) * 16;
#pragma unroll
        for (int k = 0; k < 16; ++k) { op[k] = out[k]; dp[k] = vals[k]; }
    }
}

// zero_cnt: reset the ambiguous-row counter each launch (determinism).
__global__ void zero_cnt(int* cnt) { if (threadIdx.x == 0 && blockIdx.x == 0) *cnt = 0; }

// gap_route: clear-gap rows resolved directly from fast candidates; knife-edge
// rows appended to the ambiguous list.
__global__ __launch_bounds__(256) void gap_route(
    const int* __restrict__ cand, const float* __restrict__ cdist,
    int* __restrict__ nnidx, int* __restrict__ amb, int* __restrict__ cnt)
{
    const int idx = blockIdx.x * 256 + threadIdx.x;
    if (idx >= Bn * Nn) return;
    const float* dp = cdist + (size_t)idx * 16;
    const float d8 = dp[8], d9 = dp[9];
    if (d9 - d8 > GAP_DELTA) {
        const int* cp = cand + (size_t)idx * 16;
        int* op = nnidx + (size_t)idx * Kk;
#pragma unroll
        for (int k = 0; k < Kk; ++k) op[k] = cp[k];
    } else {
        const int pos = atomicAdd(cnt, 1);
        amb[pos] = idx;
    }
}

// refine_amb: EXACT np-f32 re-rank for ambiguous rows; chunked register
// prefetch (independent loads), exact sequential ascending-c adds.
__global__ __launch_bounds__(256) void refine_amb(
    const float* __restrict__ xn, const float* __restrict__ sq,
    const int* __restrict__ cand, const int* __restrict__ amb,
    const int* __restrict__ cnt, int* __restrict__ nnidx)
{
    __shared__ float Dd[16][16];
    __shared__ int   Dm[16][16];
    const int total = *cnt;
    const int rl = threadIdx.x >> 4;     // row slot in block
    const int k  = threadIdx.x & 15;     // candidate slot

    for (int base = blockIdx.x * 16; base < total; base += gridDim.x * 16) {
        const int slot = base + rl;
        int rowid = 0;
        const bool active = slot < total;
        if (active) rowid = amb[slot];
        const int b = rowid / Nn, r = rowid % Nn;
        const float* xb  = xn + (size_t)b * Cc * Nn;
        const float* sqb = sq + (size_t)b * Nn;

        if (active) {
            const int m = cand[((size_t)b * Nn + r) * 16 + k];
            float dot = 0.f;
            for (int cc = 0; cc < 12; ++cc) {
                float va[16], vb[16];
#pragma unroll
                for (int j = 0; j < 16; ++j) {
                    va[j] = xb[(size_t)(cc * 16 + j) * Nn + r];
                    vb[j] = xb[(size_t)(cc * 16 + j) * Nn + m];
                }
#pragma unroll
                for (int j = 0; j < 16; ++j)
                    dot = __fadd_rn(dot, __fmul_rn(va[j], vb[j]));
            }
            const float t1 = __fmul_rn(2.f, dot);
            const float t2 = __fsub_rn(sqb[r], t1);
            Dd[rl][k] = __fadd_rn(t2, sqb[m]);
            Dm[rl][k] = m;
        }
        __syncthreads();
        if (active && k == 0) {
            float dl[16]; int il[16];
#pragma unroll
            for (int j = 0; j < 16; ++j) { dl[j] = Dd[rl][j]; il[j] = Dm[rl][j]; }
            int* op = nnidx + (size_t)rowid * Kk;
            for (int kk = 0; kk < Kk; ++kk) {
                int best = kk;
                for (int j = kk + 1; j < 16; ++j)
                    if (dl[j] < dl[best] || (dl[j] == dl[best] && il[j] < il[best])) best = j;
                float td = dl[kk]; dl[kk] = dl[best]; dl[best] = td;
                int ti = il[kk]; il[kk] = il[best]; il[best] = ti;
                op[kk] = il[kk];
            }
        }
        __syncthreads();
    }
}

// ===========================================================================
// VALUE PATH — fast f32/bf16 (error budget 0.14; bf16 contributes ~0.01)
// ===========================================================================

__global__ __launch_bounds__(256) void mr_naive(
    const float* __restrict__ xt, const int* __restrict__ nnidx,
    float* __restrict__ st)
{
    const long long idx = (long long)blockIdx.x * 256 + threadIdx.x;
    if (idx >= (long long)Bn * Cc * Nn) return;
    const int n = (int)(idx % Nn);
    const int c = (int)((idx / Nn) % Cc);
    const int b = (int)(idx / ((long long)Cc * Nn));
    const float* row = xt + ((size_t)b * Cc + c) * Nn;
    const float ctr = row[n];
    const int* ip = nnidx + ((size_t)b * Nn + n) * Kk;
    float mx = -INFINITY;
    for (int k = 0; k < Kk; ++k) {
        const float v = __fsub_rn(row[ip[k]], ctr);
        if (v > mx) mx = v;
    }
    st[((size_t)b * C2c + 2 * c) * Nn + n]     = ctr;
    st[((size_t)b * C2c + 2 * c + 1) * Nn + n] = mx;
}

// wcvt: fc2_w f32 -> bf16 (RNE)
__global__ __launch_bounds__(256) void wcvt(
    const float* __restrict__ w, unsigned short* __restrict__ wbf, int nElem)
{
    const int i = blockIdx.x * 256 + threadIdx.x;
    if (i < nElem) wbf[i] = f2bf(w[i]);
}

// gconv: grouped conv + BN2 + GELU; epilogue writes bf16 TRANSPOSED
// g_bfT[b][n][oc] via an LDS transpose (coalesced 16B stores).
__global__ __launch_bounds__(256) void gconv_kernel(
    const float* __restrict__ st, const float* __restrict__ gw,
    const float* __restrict__ gb,
    const float* __restrict__ gg, const float* __restrict__ bb_,
    const float* __restrict__ mm, const float* __restrict__ vv,
    unsigned short* __restrict__ gT)
{
    __shared__ float As[16][32];
    __shared__ float Bs[16][64];
    __shared__ unsigned short Ts[64][40];   // [n_local][oc_local], pad 40
    const int b   = blockIdx.z;
    const int n0  = blockIdx.x * 64;
    const int grp = blockIdx.y / 3;
    const int o0  = (blockIdx.y % 3) * 32;
    const int tid = threadIdx.x;
    const int tx = tid & 15, ty = tid >> 4;
    const int lo = tid & 31, lk2 = tid >> 5;
    const int ln4 = tid & 15, lbk = tid >> 4;
    const float* stb = st + (size_t)b * C2c * Nn + (size_t)grp * 96 * Nn;
    const float* wgp = gw + (size_t)grp * 96 * 96;

    float acc[2][4];
#pragma unroll
    for (int i = 0; i < 2; ++i)
#pragma unroll
        for (int j = 0; j < 4; ++j) acc[i][j] = 0.f;

    for (int kt = 0; kt < 6; ++kt) {
        const int k0 = kt * 16;
        float2 av = *reinterpret_cast<const float2*>(&wgp[(size_t)(o0 + lo) * 96 + k0 + lk2 * 2]);
        As[lk2*2+0][lo] = av.x;
        As[lk2*2+1][lo] = av.y;
        const int n = n0 + ln4 * 4;
        float4 bv = make_float4(0.f, 0.f, 0.f, 0.f);
        if (n < Nn) bv = *reinterpret_cast<const float4*>(&stb[(size_t)(k0 + lbk) * Nn + n]);
        *reinterpret_cast<float4*>(&Bs[lbk][ln4*4]) = bv;
        __syncthreads();
#pragma unroll
        for (int kk = 0; kk < 16; ++kk) {
            float2 a  = *reinterpret_cast<const float2*>(&As[kk][ty*2]);
            float4 bq = *reinterpret_cast<const float4*>(&Bs[kk][tx*4]);
            float ar[2] = {a.x, a.y};
            float br[4] = {bq.x, bq.y, bq.z, bq.w};
#pragma unroll
            for (int i = 0; i < 2; ++i)
#pragma unroll
                for (int j = 0; j < 4; ++j)
                    acc[i][j] = fmaf(ar[i], br[j], acc[i][j]);
        }
        __syncthreads();
    }
    // BN + GELU -> bf16 into transpose staging LDS
#pragma unroll
    for (int i = 0; i < 2; ++i) {
        const int oc = grp * 96 + o0 + ty * 2 + i;
        const float s  = gg[oc] * rsqrtf(vv[oc] + 1e-5f);
        const float sh = (gb[oc] - mm[oc]) * s + bb_[oc];
#pragma unroll
        for (int j = 0; j < 4; ++j) {
            float v = fmaf(acc[i][j], s, sh);
            float ge = 0.5f * v * (1.f + erff(v * 0.70710678118654752f));
            Ts[tx*4 + j][ty*2 + i] = f2bf(ge);
        }
    }
    __syncthreads();
    // write out: thread t -> row rr = t>>2, part = t&3 (8 bf16 = 16B)
    {
        const int rr = tid >> 2, part = tid & 3;
        const int n = n0 + rr;
        if (n < Nn) {
            const size_t dst = ((size_t)b * Nn + n) * C2c + (size_t)grp * 96 + o0 + part * 8;
            *reinterpret_cast<bf16x8*>(&gT[dst]) =
                *reinterpret_cast<const bf16x8*>(&Ts[rr][part * 8]);
        }
    }
}

// fc2_mfma: out = BN3( g · fc2_w^T ) + x, bf16 MFMA (16x16x32), f32 accum.
// Block 256 = 4 waves; tile 64(o) x 64(n); wave w owns n-range w*16.
__global__ __launch_bounds__(256) void fc2_mfma(
    const unsigned short* __restrict__ gT, const unsigned short* __restrict__ wbf,
    const float* __restrict__ bias,
    const float* __restrict__ gg, const float* __restrict__ bb_,
    const float* __restrict__ mm, const float* __restrict__ vv,
    const float* __restrict__ xres,
    float* __restrict__ out)
{
    const int b   = blockIdx.z;
    const int n0  = blockIdx.x * 64;
    const int o0  = blockIdx.y * 64;
    const int tid = threadIdx.x;
    const int wv  = tid >> 6;
    const int l   = tid & 63;
    const int lm  = l & 15, lk = l >> 4;

    const int ncol = n0 + wv * 16 + lm;
    const int ncl  = (ncol < Nn) ? ncol : (Nn - 1);
    const unsigned short* gRow = gT + ((size_t)b * Nn + ncl) * C2c;

    f32x4 acc[4];
#pragma unroll
    for (int mf = 0; mf < 4; ++mf) acc[mf] = (f32x4){0.f, 0.f, 0.f, 0.f};

    for (int k0 = 0; k0 < C2c; k0 += 32) {
        bf16x8 bfr = *reinterpret_cast<const bf16x8*>(&gRow[k0 + lk * 8]);
#pragma unroll
        for (int mf = 0; mf < 4; ++mf) {
            bf16x8 afr = *reinterpret_cast<const bf16x8*>(
                &wbf[(size_t)(o0 + mf * 16 + lm) * C2c + k0 + lk * 8]);
            acc[mf] = __builtin_amdgcn_mfma_f32_16x16x32_bf16(afr, bfr, acc[mf], 0, 0, 0);
        }
    }
    if (ncol < Nn) {
#pragma unroll
        for (int mf = 0; mf < 4; ++mf) {
#pragma unroll
            for (int r = 0; r < 4; ++r) {
                const int o = o0 + mf * 16 + lk * 4 + r;   // C/D: row=(l>>4)*4+r
                const float s  = gg[o] * rsqrtf(vv[o] + 1e-5f);
                const float sh = (bias[o] - mm[o]) * s + bb_[o];
                const size_t oi = ((size_t)b * Cc + o) * Nn + ncol;  // col=lane&15
                out[oi] = fmaf(acc[mf][r], s, sh) + xres[oi];
            }
        }
    }
}

// ---------------------------------------------------------------------------
extern "C" void kernel_launch(void* const* d_in, const int* in_sizes, int n_in,
                              void* d_out, int out_size, void* d_ws, size_t ws_size,
                              hipStream_t stream)
{
    const float* x     = (const float*)d_in[0];
    const float* fc1_w = (const float*)d_in[1];
    const float* fc1_b = (const float*)d_in[2];
    const float* bn1_g = (const float*)d_in[3];
    const float* bn1_b = (const float*)d_in[4];
    const float* bn1_m = (const float*)d_in[5];
    const float* bn1_v = (const float*)d_in[6];
    const float* gc_w  = (const float*)d_in[7];
    const float* gc_b  = (const float*)d_in[8];
    const float* bn2_g = (const float*)d_in[9];
    const float* bn2_b = (const float*)d_in[10];
    const float* bn2_m = (const float*)d_in[11];
    const float* bn2_v = (const float*)d_in[12];
    const float* fc2_w = (const float*)d_in[13];
    const float* fc2_b = (const float*)d_in[14];
    const float* bn3_g = (const float*)d_in[15];
    const float* bn3_b = (const float*)d_in[16];
    const float* bn3_m = (const float*)d_in[17];
    const float* bn3_v = (const float*)d_in[18];

    float* out = (float*)d_out;                  // xt scratch, overwritten by fc2

    // workspace layout (max concurrent ~156 MB, proven):
    //   region A [0, 77.07M):  dist16 (39.34M, 4 chunks; dies after select16)
    //                          -> st (born at mr)
    //   region B [77.07, 154.14M):
    //       xn (38.5M) | sq | c16 | cd16 (45.16M used; die after refine)
    //       -> g_bfT (bf16 38.5M, born at gconv, aliases xn)
    //       wbf (147KB) parked at +45.16M — never overlapped
    //   region C [154.14M, +): nnidx (1.81M) | amb (0.2M) | cnt
    char* wsb = (char*)d_ws;
    const size_t regionBytes = (size_t)Bn * C2c * Nn * 4;   // 77,070,336
    float* dist = (float*)wsb;
    float* st   = (float*)wsb;
    char*  g2   = wsb + regionBytes;
    float* xnb  = (float*)g2;                                      // 38,535,168 B
    float* sqb  = (float*)(g2 + (size_t)Bn * Cc * Nn * 4);         // 200,704 B
    int*   c16  = (int*)(g2 + (size_t)Bn * Cc * Nn * 4 + 200704);  // 3,211,264 B
    float* cd16 = (float*)(g2 + (size_t)Bn * Cc * Nn * 4 + 200704 + 3211264); // 3,211,264 B
    unsigned short* gT  = (unsigned short*)g2;                     // bf16, aliases xn
    unsigned short* wbf = (unsigned short*)(g2 + 45158912);        // 147,456 B
    char*  g3   = wsb + 2 * regionBytes;
    int*   nni  = (int*)g3;                                        // 1,806,336 B
    int*   amb  = (int*)(g3 + 1806336);                            // 200,704 B
    int*   cnt  = (int*)(g3 + 1806336 + 200704);                   // 4 B

    const long long nBCN = (long long)Bn * Cc * Nn;
    const int nBN = Bn * Nn;

    dim3 blk(256);
    wcvt<<<dim3((Cc * C2c + 255) / 256), blk, 0, stream>>>(fc2_w, wbf, Cc * C2c);
    fc1_np<<<dim3(7, 3, Bn), blk, 0, stream>>>(
        x, fc1_w, fc1_b, bn1_g, bn1_b, bn1_m, bn1_v, out);
    norm_np<<<dim3((nBN + 255) / 256), blk, 0, stream>>>(out, xnb, sqb);
    for (int ch = 0; ch < 4; ++ch) {
        dist_gemm<<<dim3(91, 16), blk, 0, stream>>>(xnb, dist, ch);
        select16<<<dim3(16 * Nn / 4), blk, 0, stream>>>(dist, c16, cd16, ch);
    }
    zero_cnt<<<dim3(1), dim3(64), 0, stream>>>(cnt);
    gap_route<<<dim3((nBN + 255) / 256), blk, 0, stream>>>(c16, cd16, nni, amb, cnt);
    refine_amb<<<dim3(196), blk, 0, stream>>>(xnb, sqb, c16, amb, cnt, nni);
    mr_naive<<<dim3((unsigned)((nBCN + 255) / 256)), blk, 0, stream>>>(out, nni, st);
    gconv_kernel<<<dim3(13, 12, Bn), blk, 0, stream>>>(
        st, gc_w, gc_b, bn2_g, bn2_b, bn2_m, bn2_v, gT);
    fc2_mfma<<<dim3(13, 3, Bn), blk, 0, stream>>>(
        gT, wbf, fc2_b, bn3_g, bn3_b, bn3_m, bn3_v, x, out);
}

// Round 13
// 795.470 us; speedup vs baseline: 1.4672x; 1.0553x over previous
//
#include <hip/hip_runtime.h>
#include <math.h>

static constexpr int Bn  = 64;    // batch
static constexpr int Cc  = 192;   // channels
static constexpr int Nn  = 784;   // H*W
static constexpr int C2c = 384;   // 2C
static constexpr int Kk  = 9;     // knn K
#define GAP_DELTA 1e-4f

typedef __attribute__((ext_vector_type(8))) short bf16x8;
typedef __attribute__((ext_vector_type(4))) float f32x4;

__device__ inline unsigned short f2bf(float f) {   // RNE f32 -> bf16
    unsigned int u = __float_as_uint(f);
    return (unsigned short)((u + 0x7FFFu + ((u >> 16) & 1u)) >> 16);
}

// ===========================================================================
// INDEX PATH — np-f32 bit-exact where values matter (fc1, norm, refine_amb).
// ===========================================================================

// fc1_np: BIT-CRITICAL — numpy-f32-exact (no FMA, ascending-c accumulation).
__global__ __launch_bounds__(256) void fc1_np(
    const float* __restrict__ x, const float* __restrict__ w,
    const float* __restrict__ bias,
    const float* __restrict__ gg, const float* __restrict__ bb_,
    const float* __restrict__ mm, const float* __restrict__ vv,
    float* __restrict__ xt)
{
    __shared__ float As[16][64];
    __shared__ float Bs[16][128];
    const int b   = blockIdx.z;
    const int n0  = blockIdx.x * 128;
    const int o0  = blockIdx.y * 64;
    const int tid = threadIdx.x;
    const int tx = tid & 15, ty = tid >> 4;
    const int lo = tid & 63, lk4 = tid >> 6;
    const int ln4 = tid & 15, lbk = tid >> 4;
    const float* xb = x + (size_t)b * Cc * Nn;

    float acc[4][8];
#pragma unroll
    for (int i = 0; i < 4; ++i)
#pragma unroll
        for (int j = 0; j < 8; ++j) acc[i][j] = 0.f;

    for (int kt = 0; kt < 12; ++kt) {               // c ascending: kt*16 + kk
        const int k0 = kt * 16;
        float4 av = *reinterpret_cast<const float4*>(&w[(size_t)(o0 + lo) * 192 + k0 + lk4 * 4]);
        As[lk4*4+0][lo] = av.x;
        As[lk4*4+1][lo] = av.y;
        As[lk4*4+2][lo] = av.z;
        As[lk4*4+3][lo] = av.w;
        const int na = n0 + ln4 * 4;
        const int nb = n0 + 64 + ln4 * 4;
        float4 b0 = make_float4(0.f, 0.f, 0.f, 0.f);
        float4 b1 = make_float4(0.f, 0.f, 0.f, 0.f);
        if (na < Nn) b0 = *reinterpret_cast<const float4*>(&xb[(size_t)(k0 + lbk) * Nn + na]);
        if (nb < Nn) b1 = *reinterpret_cast<const float4*>(&xb[(size_t)(k0 + lbk) * Nn + nb]);
        *reinterpret_cast<float4*>(&Bs[lbk][ln4*4])      = b0;
        *reinterpret_cast<float4*>(&Bs[lbk][64 + ln4*4]) = b1;
        __syncthreads();
#pragma unroll
        for (int kk = 0; kk < 16; ++kk) {
            float ar[4], br[8];
#pragma unroll
            for (int i = 0; i < 4; ++i) ar[i] = As[kk][ty*4+i];
#pragma unroll
            for (int j = 0; j < 4; ++j) br[j]     = Bs[kk][tx*4+j];
#pragma unroll
            for (int j = 0; j < 4; ++j) br[4 + j] = Bs[kk][64 + tx*4+j];
#pragma unroll
            for (int i = 0; i < 4; ++i)
#pragma unroll
                for (int j = 0; j < 8; ++j)
                    acc[i][j] = __fadd_rn(acc[i][j], __fmul_rn(ar[i], br[j]));
        }
        __syncthreads();
    }
    const int na = n0 + tx * 4;
    const int nb = n0 + 64 + tx * 4;
#pragma unroll
    for (int i = 0; i < 4; ++i) {
        const int o = o0 + ty * 4 + i;
        const float e  = __fadd_rn(vv[o], 1e-5f);
        const float r1 = __fsqrt_rn(e);
        const float rr = __fdiv_rn(1.f, r1);
        const float s  = __fmul_rn(gg[o], rr);
        const size_t rowb = ((size_t)b * Cc + o) * Nn;
        if (na < Nn) {
#pragma unroll
            for (int j = 0; j < 4; ++j) {
                const float h = __fadd_rn(acc[i][j], bias[o]);
                const float t = __fsub_rn(h, mm[o]);
                const float u = __fmul_rn(t, s);
                xt[rowb + na + j] = __fadd_rn(u, bb_[o]);
            }
        }
        if (nb < Nn) {
#pragma unroll
            for (int j = 0; j < 4; ++j) {
                const float h = __fadd_rn(acc[i][4 + j], bias[o]);
                const float t = __fsub_rn(h, mm[o]);
                const float u = __fmul_rn(t, s);
                xt[rowb + nb + j] = __fadd_rn(u, bb_[o]);
            }
        }
    }
}

// norm_np: numpy-exact. BIT-CRITICAL.
__global__ __launch_bounds__(256) void norm_np(
    const float* __restrict__ xt, float* __restrict__ xn, float* __restrict__ sq)
{
    const int idx = blockIdx.x * 256 + threadIdx.x;
    if (idx >= Bn * Nn) return;
    const int n = idx % Nn;
    const int b = idx / Nn;
    const float* p = xt + (size_t)b * Cc * Nn + n;

    float acc = 0.f;
    for (int c = 0; c < Cc; ++c) {
        const float v = p[(size_t)c * Nn];
        acc = __fadd_rn(acc, __fmul_rn(v, v));
    }
    float nrm = __fsqrt_rn(acc);
    nrm = fmaxf(nrm, 1e-12f);

    float* q = xn + (size_t)b * Cc * Nn + n;
    for (int c = 0; c < Cc; ++c)
        q[(size_t)c * Nn] = __fdiv_rn(p[(size_t)c * Nn], nrm);

    float sblk[2];
#pragma unroll
    for (int blk = 0; blk < 2; ++blk) {
        const int base = blk * 96;
        float r[8];
#pragma unroll
        for (int j = 0; j < 8; ++j) {
            const float xv = q[(size_t)(base + j) * Nn];
            r[j] = __fmul_rn(xv, xv);
        }
        for (int i = 8; i < 96; i += 8) {
#pragma unroll
            for (int j = 0; j < 8; ++j) {
                const float xv = q[(size_t)(base + i + j) * Nn];
                r[j] = __fadd_rn(r[j], __fmul_rn(xv, xv));
            }
        }
        sblk[blk] = __fadd_rn(__fadd_rn(__fadd_rn(r[0], r[1]), __fadd_rn(r[2], r[3])),
                              __fadd_rn(__fadd_rn(r[4], r[5]), __fadd_rn(r[6], r[7])));
    }
    sq[idx] = __fadd_rn(sblk[0], sblk[1]);
}

// dist_gemm: symmetric fast filter — only rt<=mt tiles computed; the mirror
// tile is produced by an LDS transpose. dist[b16][r][m] = -dot(xn_r, xn_m).
__global__ __launch_bounds__(256) void dist_gemm(
    const float* __restrict__ xn, float* __restrict__ dist, int bchunk)
{
    __shared__ float As[16][64];
    __shared__ float Bs[16][64];
    __shared__ float Ds[64][65];
    const int bt = blockIdx.x;             // 0..90 (upper-triangle tiles)
    int rt = 0, rem = bt;
    while (rem >= 13 - rt) { rem -= 13 - rt; ++rt; }
    const int mt = rt + rem;
    const int bc = blockIdx.y;             // 0..15
    const int b  = bchunk * 16 + bc;
    const int r0 = rt * 64, m0 = mt * 64;
    const int tid = threadIdx.x;
    const int tx = tid & 15, ty = tid >> 4;
    const int lo = tid & 63, lk4 = tid >> 6;
    const float* xb = xn + (size_t)b * Cc * Nn;

    float acc[4][4];
#pragma unroll
    for (int i = 0; i < 4; ++i)
#pragma unroll
        for (int j = 0; j < 4; ++j) acc[i][j] = 0.f;

    for (int kt = 0; kt < 12; ++kt) {
        const int k0 = kt * 16;
        const int r = r0 + lo, m = m0 + lo;
#pragma unroll
        for (int j = 0; j < 4; ++j) {
            const int kc = k0 + lk4 * 4 + j;
            As[lk4*4+j][lo] = (r < Nn) ? xb[(size_t)kc * Nn + r] : 0.f;
            Bs[lk4*4+j][lo] = (m < Nn) ? xb[(size_t)kc * Nn + m] : 0.f;
        }
        __syncthreads();
#pragma unroll
        for (int kk = 0; kk < 16; ++kk) {
            float4 a  = *reinterpret_cast<const float4*>(&As[kk][ty*4]);
            float4 bq = *reinterpret_cast<const float4*>(&Bs[kk][tx*4]);
            float ar[4] = {a.x, a.y, a.z, a.w};
            float br[4] = {bq.x, bq.y, bq.z, bq.w};
#pragma unroll
            for (int i = 0; i < 4; ++i)
#pragma unroll
                for (int j = 0; j < 4; ++j)
                    acc[i][j] = fmaf(ar[i], br[j], acc[i][j]);
        }
        __syncthreads();
    }
    float* db = dist + (size_t)bc * Nn * Nn;
    {
        const int m = m0 + tx * 4;
        if (m < Nn) {
#pragma unroll
            for (int i = 0; i < 4; ++i) {
                const int r = r0 + ty * 4 + i;
                if (r < Nn) {
                    float4 o = make_float4(-acc[i][0], -acc[i][1], -acc[i][2], -acc[i][3]);
                    *reinterpret_cast<float4*>(&db[(size_t)r * Nn + m]) = o;
                }
            }
        }
    }
    if (rt != mt) {
#pragma unroll
        for (int i = 0; i < 4; ++i)
#pragma unroll
            for (int j = 0; j < 4; ++j)
                Ds[ty*4+i][tx*4+j] = -acc[i][j];
        __syncthreads();
        const int rcol = r0 + tx * 4;      // full r-tiles only when rt<mt<=12
#pragma unroll
        for (int i = 0; i < 4; ++i) {
            const int mrow = m0 + ty * 4 + i;
            if (mrow < Nn) {
                float4 o = make_float4(Ds[tx*4+0][ty*4+i], Ds[tx*4+1][ty*4+i],
                                       Ds[tx*4+2][ty*4+i], Ds[tx*4+3][ty*4+i]);
                *reinterpret_cast<float4*>(&db[(size_t)mrow * Nn + rcol]) = o;
            }
        }
    }
}

// select16: one wave per row; 16x argmin-extract via shfl_xor; writes sorted
// candidate indices AND their fast dists.
__global__ __launch_bounds__(256) void select16(
    const float* __restrict__ dist, int* __restrict__ cand,
    float* __restrict__ cdist, int bchunk)
{
    const int wid = blockIdx.x * 4 + (threadIdx.x >> 6);   // wave id in chunk
    const int L   = threadIdx.x & 63;
    const int r   = wid % Nn;
    const int bc  = wid / Nn;
    const int b   = bchunk * 16 + bc;
    const float* drow = dist + ((size_t)bc * Nn + r) * Nn;

    float v[13];
#pragma unroll
    for (int s = 0; s < 12; ++s) v[s] = drow[s * 64 + L];
    v[12] = (L < 16) ? drow[768 + L] : INFINITY;

    float mv = v[0]; int ms = 0;
#pragma unroll
    for (int s = 1; s < 13; ++s)
        if (v[s] < mv) { mv = v[s]; ms = s; }

    int out[16];
    float vals[16];
#pragma unroll
    for (int k = 0; k < 16; ++k) {
        float gv = mv; int gi = ms * 64 + L;
#pragma unroll
        for (int off = 1; off < 64; off <<= 1) {
            const float ov = __shfl_xor(gv, off, 64);
            const int   oi = __shfl_xor(gi, off, 64);
            if (ov < gv || (ov == gv && oi < gi)) { gv = ov; gi = oi; }
        }
        out[k] = gi; vals[k] = gv;
        const int ol = gi & 63, os = gi >> 6;
        if (L == ol) {
#pragma unroll
            for (int s = 0; s < 13; ++s) if (s == os) v[s] = INFINITY;
            mv = v[0]; ms = 0;
#pragma unroll
            for (int s = 1; s < 13; ++s)
                if (v[s] < mv) { mv = v[s]; ms = s; }
        }
    }
    if (L == 0) {
        int*   op = cand  + ((size_t)b * Nn + r) * 16;
        float* dp = cdist + ((size_t)b * Nn + r) * 16;
#pragma unroll
        for (int k = 0; k < 16; ++k) { op[k] = out[k]; dp[k] = vals[k]; }
    }
}

// zero_cnt: reset the ambiguous-row counter each launch (determinism).
__global__ void zero_cnt(int* cnt) { if (threadIdx.x == 0 && blockIdx.x == 0) *cnt = 0; }

// gap_route: clear-gap rows resolved directly from fast candidates; knife-edge
// rows appended to the ambiguous list.
__global__ __launch_bounds__(256) void gap_route(
    const int* __restrict__ cand, const float* __restrict__ cdist,
    int* __restrict__ nnidx, int* __restrict__ amb, int* __restrict__ cnt)
{
    const int idx = blockIdx.x * 256 + threadIdx.x;
    if (idx >= Bn * Nn) return;
    const float* dp = cdist + (size_t)idx * 16;
    const float d8 = dp[8], d9 = dp[9];
    if (d9 - d8 > GAP_DELTA) {
        const int* cp = cand + (size_t)idx * 16;
        int* op = nnidx + (size_t)idx * Kk;
#pragma unroll
        for (int k = 0; k < Kk; ++k) op[k] = cp[k];
    } else {
        const int pos = atomicAdd(cnt, 1);
        amb[pos] = idx;
    }
}

// refine_amb v2: one BLOCK per ambiguous row. 16 groups x 16 threads; group k
// computes candidate k's products in parallel into LDS; lane j==0 of each
// group then runs the BIT-EXACT sequential ascending-c add chain (identical
// rounding to numpy's scalar loop); thread 0 does the lexicographic top-9.
__global__ __launch_bounds__(256) void refine_amb(
    const float* __restrict__ xn, const float* __restrict__ sq,
    const int* __restrict__ cand, const int* __restrict__ amb,
    const int* __restrict__ cnt, int* __restrict__ nnidx)
{
    __shared__ float prods[16][200];   // [cand][channel], padded
    __shared__ float Dd[16];
    __shared__ int   Dm[16];
    const int total = *cnt;
    const int k = threadIdx.x >> 4;    // candidate slot
    const int j = threadIdx.x & 15;    // channel segment

    for (int row = blockIdx.x; row < total; row += gridDim.x) {
        const int rowid = amb[row];
        const int b = rowid / Nn, r = rowid % Nn;
        const float* xb  = xn + (size_t)b * Cc * Nn;
        const float* sqb = sq + (size_t)b * Nn;
        const int m = cand[(size_t)rowid * 16 + k];

        // parallel scattered loads: channels [12j, 12j+12)
#pragma unroll
        for (int i = 0; i < 12; ++i) {
            const int c = j * 12 + i;
            prods[k][c] = __fmul_rn(xb[(size_t)c * Nn + r], xb[(size_t)c * Nn + m]);
        }
        __syncthreads();
        if (j == 0) {
            float dot = 0.f;
            for (int c = 0; c < Cc; ++c)          // exact sequential chain
                dot = __fadd_rn(dot, prods[k][c]);
            const float t1 = __fmul_rn(2.f, dot);
            const float t2 = __fsub_rn(sqb[r], t1);
            Dd[k] = __fadd_rn(t2, sqb[m]);
            Dm[k] = m;
        }
        __syncthreads();
        if (threadIdx.x == 0) {
            float dl[16]; int il[16];
#pragma unroll
            for (int q = 0; q < 16; ++q) { dl[q] = Dd[q]; il[q] = Dm[q]; }
            int* op = nnidx + (size_t)rowid * Kk;
            for (int kk = 0; kk < Kk; ++kk) {
                int best = kk;
                for (int q = kk + 1; q < 16; ++q)
                    if (dl[q] < dl[best] || (dl[q] == dl[best] && il[q] < il[best])) best = q;
                float td = dl[kk]; dl[kk] = dl[best]; dl[best] = td;
                int ti = il[kk]; il[kk] = il[best]; il[best] = ti;
                op[kk] = il[kk];
            }
        }
        __syncthreads();
    }
}

// ===========================================================================
// VALUE PATH — fast f32/bf16 (error budget 0.14; bf16 contributes ~0.02)
// ===========================================================================

__global__ __launch_bounds__(256) void mr_naive(
    const float* __restrict__ xt, const int* __restrict__ nnidx,
    float* __restrict__ st)
{
    const long long idx = (long long)blockIdx.x * 256 + threadIdx.x;
    if (idx >= (long long)Bn * Cc * Nn) return;
    const int n = (int)(idx % Nn);
    const int c = (int)((idx / Nn) % Cc);
    const int b = (int)(idx / ((long long)Cc * Nn));
    const float* row = xt + ((size_t)b * Cc + c) * Nn;
    const float ctr = row[n];
    const int* ip = nnidx + ((size_t)b * Nn + n) * Kk;
    float mx = -INFINITY;
    for (int k = 0; k < Kk; ++k) {
        const float v = __fsub_rn(row[ip[k]], ctr);
        if (v > mx) mx = v;
    }
    st[((size_t)b * C2c + 2 * c) * Nn + n]     = ctr;
    st[((size_t)b * C2c + 2 * c + 1) * Nn + n] = mx;
}

// wcvt: fc2_w f32 -> bf16 (RNE)
__global__ __launch_bounds__(256) void wcvt(
    const float* __restrict__ w, unsigned short* __restrict__ wbf, int nElem)
{
    const int i = blockIdx.x * 256 + threadIdx.x;
    if (i < nElem) wbf[i] = f2bf(w[i]);
}

// gconv: grouped conv + BN2 + GELU; epilogue writes bf16 TRANSPOSED
// g_bfT[b][n][oc] via an LDS transpose (coalesced 16B stores).
__global__ __launch_bounds__(256) void gconv_kernel(
    const float* __restrict__ st, const float* __restrict__ gw,
    const float* __restrict__ gb,
    const float* __restrict__ gg, const float* __restrict__ bb_,
    const float* __restrict__ mm, const float* __restrict__ vv,
    unsigned short* __restrict__ gT)
{
    __shared__ float As[16][32];
    __shared__ float Bs[16][64];
    __shared__ unsigned short Ts[64][40];   // [n_local][oc_local], pad 40
    const int b   = blockIdx.z;
    const int n0  = blockIdx.x * 64;
    const int grp = blockIdx.y / 3;
    const int o0  = (blockIdx.y % 3) * 32;
    const int tid = threadIdx.x;
    const int tx = tid & 15, ty = tid >> 4;
    const int lo = tid & 31, lk2 = tid >> 5;
    const int ln4 = tid & 15, lbk = tid >> 4;
    const float* stb = st + (size_t)b * C2c * Nn + (size_t)grp * 96 * Nn;
    const float* wgp = gw + (size_t)grp * 96 * 96;

    float acc[2][4];
#pragma unroll
    for (int i = 0; i < 2; ++i)
#pragma unroll
        for (int j = 0; j < 4; ++j) acc[i][j] = 0.f;

    for (int kt = 0; kt < 6; ++kt) {
        const int k0 = kt * 16;
        float2 av = *reinterpret_cast<const float2*>(&wgp[(size_t)(o0 + lo) * 96 + k0 + lk2 * 2]);
        As[lk2*2+0][lo] = av.x;
        As[lk2*2+1][lo] = av.y;
        const int n = n0 + ln4 * 4;
        float4 bv = make_float4(0.f, 0.f, 0.f, 0.f);
        if (n < Nn) bv = *reinterpret_cast<const float4*>(&stb[(size_t)(k0 + lbk) * Nn + n]);
        *reinterpret_cast<float4*>(&Bs[lbk][ln4*4]) = bv;
        __syncthreads();
#pragma unroll
        for (int kk = 0; kk < 16; ++kk) {
            float2 a  = *reinterpret_cast<const float2*>(&As[kk][ty*2]);
            float4 bq = *reinterpret_cast<const float4*>(&Bs[kk][tx*4]);
            float ar[2] = {a.x, a.y};
            float br[4] = {bq.x, bq.y, bq.z, bq.w};
#pragma unroll
            for (int i = 0; i < 2; ++i)
#pragma unroll
                for (int j = 0; j < 4; ++j)
                    acc[i][j] = fmaf(ar[i], br[j], acc[i][j]);
        }
        __syncthreads();
    }
    // BN + GELU -> bf16 into transpose staging LDS
#pragma unroll
    for (int i = 0; i < 2; ++i) {
        const int oc = grp * 96 + o0 + ty * 2 + i;
        const float s  = gg[oc] * rsqrtf(vv[oc] + 1e-5f);
        const float sh = (gb[oc] - mm[oc]) * s + bb_[oc];
#pragma unroll
        for (int j = 0; j < 4; ++j) {
            float v = fmaf(acc[i][j], s, sh);
            float ge = 0.5f * v * (1.f + erff(v * 0.70710678118654752f));
            Ts[tx*4 + j][ty*2 + i] = f2bf(ge);
        }
    }
    __syncthreads();
    // write out: thread t -> row rr = t>>2, part = t&3 (8 bf16 = 16B)
    {
        const int rr = tid >> 2, part = tid & 3;
        const int n = n0 + rr;
        if (n < Nn) {
            const size_t dst = ((size_t)b * Nn + n) * C2c + (size_t)grp * 96 + o0 + part * 8;
            *reinterpret_cast<bf16x8*>(&gT[dst]) =
                *reinterpret_cast<const bf16x8*>(&Ts[rr][part * 8]);
        }
    }
}

// fc2_mfma: out = BN3( g · fc2_w^T ) + x, bf16 MFMA (16x16x32), f32 accum.
// Block 256 = 4 waves; tile 64(o) x 64(n); wave w owns n-range w*16.
__global__ __launch_bounds__(256) void fc2_mfma(
    const unsigned short* __restrict__ gT, const unsigned short* __restrict__ wbf,
    const float* __restrict__ bias,
    const float* __restrict__ gg, const float* __restrict__ bb_,
    const float* __restrict__ mm, const float* __restrict__ vv,
    const float* __restrict__ xres,
    float* __restrict__ out)
{
    const int b   = blockIdx.z;
    const int n0  = blockIdx.x * 64;
    const int o0  = blockIdx.y * 64;
    const int tid = threadIdx.x;
    const int wv  = tid >> 6;
    const int l   = tid & 63;
    const int lm  = l & 15, lk = l >> 4;

    const int ncol = n0 + wv * 16 + lm;
    const int ncl  = (ncol < Nn) ? ncol : (Nn - 1);
    const unsigned short* gRow = gT + ((size_t)b * Nn + ncl) * C2c;

    f32x4 acc[4];
#pragma unroll
    for (int mf = 0; mf < 4; ++mf) acc[mf] = (f32x4){0.f, 0.f, 0.f, 0.f};

    for (int k0 = 0; k0 < C2c; k0 += 32) {
        bf16x8 bfr = *reinterpret_cast<const bf16x8*>(&gRow[k0 + lk * 8]);
#pragma unroll
        for (int mf = 0; mf < 4; ++mf) {
            bf16x8 afr = *reinterpret_cast<const bf16x8*>(
                &wbf[(size_t)(o0 + mf * 16 + lm) * C2c + k0 + lk * 8]);
            acc[mf] = __builtin_amdgcn_mfma_f32_16x16x32_bf16(afr, bfr, acc[mf], 0, 0, 0);
        }
    }
    if (ncol < Nn) {
#pragma unroll
        for (int mf = 0; mf < 4; ++mf) {
#pragma unroll
            for (int r = 0; r < 4; ++r) {
                const int o = o0 + mf * 16 + lk * 4 + r;   // C/D: row=(l>>4)*4+r
                const float s  = gg[o] * rsqrtf(vv[o] + 1e-5f);
                const float sh = (bias[o] - mm[o]) * s + bb_[o];
                const size_t oi = ((size_t)b * Cc + o) * Nn + ncol;  // col=lane&15
                out[oi] = fmaf(acc[mf][r], s, sh) + xres[oi];
            }
        }
    }
}

// ---------------------------------------------------------------------------
extern "C" void kernel_launch(void* const* d_in, const int* in_sizes, int n_in,
                              void* d_out, int out_size, void* d_ws, size_t ws_size,
                              hipStream_t stream)
{
    const float* x     = (const float*)d_in[0];
    const float* fc1_w = (const float*)d_in[1];
    const float* fc1_b = (const float*)d_in[2];
    const float* bn1_g = (const float*)d_in[3];
    const float* bn1_b = (const float*)d_in[4];
    const float* bn1_m = (const float*)d_in[5];
    const float* bn1_v = (const float*)d_in[6];
    const float* gc_w  = (const float*)d_in[7];
    const float* gc_b  = (const float*)d_in[8];
    const float* bn2_g = (const float*)d_in[9];
    const float* bn2_b = (const float*)d_in[10];
    const float* bn2_m = (const float*)d_in[11];
    const float* bn2_v = (const float*)d_in[12];
    const float* fc2_w = (const float*)d_in[13];
    const float* fc2_b = (const float*)d_in[14];
    const float* bn3_g = (const float*)d_in[15];
    const float* bn3_b = (const float*)d_in[16];
    const float* bn3_m = (const float*)d_in[17];
    const float* bn3_v = (const float*)d_in[18];

    float* out = (float*)d_out;                  // xt scratch, overwritten by fc2

    // workspace layout (max concurrent ~156 MB, proven):
    //   region A [0, 77.07M):  dist16 (39.34M, 4 chunks; dies after select16)
    //                          -> st (born at mr)
    //   region B [77.07, 154.14M):
    //       xn (38.5M) | sq | c16 | cd16 (45.16M used; die after refine)
    //       -> g_bfT (bf16 38.5M, born at gconv, aliases xn)
    //       wbf (147KB) parked at +45.16M — never overlapped
    //   region C [154.14M, +): nnidx (1.81M) | amb (0.2M) | cnt
    char* wsb = (char*)d_ws;
    const size_t regionBytes = (size_t)Bn * C2c * Nn * 4;   // 77,070,336
    float* dist = (float*)wsb;
    float* st   = (float*)wsb;
    char*  g2   = wsb + regionBytes;
    float* xnb  = (float*)g2;                                      // 38,535,168 B
    float* sqb  = (float*)(g2 + (size_t)Bn * Cc * Nn * 4);         // 200,704 B
    int*   c16  = (int*)(g2 + (size_t)Bn * Cc * Nn * 4 + 200704);  // 3,211,264 B
    float* cd16 = (float*)(g2 + (size_t)Bn * Cc * Nn * 4 + 200704 + 3211264); // 3,211,264 B
    unsigned short* gT  = (unsigned short*)g2;                     // bf16, aliases xn
    unsigned short* wbf = (unsigned short*)(g2 + 45158912);        // 147,456 B
    char*  g3   = wsb + 2 * regionBytes;
    int*   nni  = (int*)g3;                                        // 1,806,336 B
    int*   amb  = (int*)(g3 + 1806336);                            // 200,704 B
    int*   cnt  = (int*)(g3 + 1806336 + 200704);                   // 4 B

    const long long nBCN = (long long)Bn * Cc * Nn;
    const int nBN = Bn * Nn;

    dim3 blk(256);
    wcvt<<<dim3((Cc * C2c + 255) / 256), blk, 0, stream>>>(fc2_w, wbf, Cc * C2c);
    fc1_np<<<dim3(7, 3, Bn), blk, 0, stream>>>(
        x, fc1_w, fc1_b, bn1_g, bn1_b, bn1_m, bn1_v, out);
    norm_np<<<dim3((nBN + 255) / 256), blk, 0, stream>>>(out, xnb, sqb);
    for (int ch = 0; ch < 4; ++ch) {
        dist_gemm<<<dim3(91, 16), blk, 0, stream>>>(xnb, dist, ch);
        select16<<<dim3(16 * Nn / 4), blk, 0, stream>>>(dist, c16, cd16, ch);
    }
    zero_cnt<<<dim3(1), dim3(64), 0, stream>>>(cnt);
    gap_route<<<dim3((nBN + 255) / 256), blk, 0, stream>>>(c16, cd16, nni, amb, cnt);
    refine_amb<<<dim3(784), blk, 0, stream>>>(xnb, sqb, c16, amb, cnt, nni);
    mr_naive<<<dim3((unsigned)((nBCN + 255) / 256)), blk, 0, stream>>>(out, nni, st);
    gconv_kernel<<<dim3(13, 12, Bn), blk, 0, stream>>>(
        st, gc_w, gc_b, bn2_g, bn2_b, bn2_m, bn2_v, gT);
    fc2_mfma<<<dim3(13, 3, Bn), blk, 0, stream>>>(
        gT, wbf, fc2_b, bn3_g, bn3_b, bn3_m, bn3_v, x, out);
}

// Round 14
// 767.655 us; speedup vs baseline: 1.5203x; 1.0362x over previous
//
#include <hip/hip_runtime.h>
#include <math.h>

static constexpr int Bn  = 64;    // batch
static constexpr int Cc  = 192;   // channels
static constexpr int Nn  = 784;   // H*W
static constexpr int C2c = 384;   // 2C
static constexpr int Kk  = 9;     // knn K
#define GAP_DELTA 1e-4f

typedef __attribute__((ext_vector_type(8))) short bf16x8;
typedef __attribute__((ext_vector_type(4))) float f32x4;

__device__ inline unsigned short f2bf(float f) {   // RNE f32 -> bf16
    unsigned int u = __float_as_uint(f);
    return (unsigned short)((u + 0x7FFFu + ((u >> 16) & 1u)) >> 16);
}

// ===========================================================================
// INDEX PATH — np-f32 bit-exact where values matter (fc1, norm, refine_amb).
// ===========================================================================

// fc1_np: BIT-CRITICAL — numpy-f32-exact (no FMA, ascending-c accumulation).
__global__ __launch_bounds__(256) void fc1_np(
    const float* __restrict__ x, const float* __restrict__ w,
    const float* __restrict__ bias,
    const float* __restrict__ gg, const float* __restrict__ bb_,
    const float* __restrict__ mm, const float* __restrict__ vv,
    float* __restrict__ xt)
{
    __shared__ float As[16][64];
    __shared__ float Bs[16][128];
    const int b   = blockIdx.z;
    const int n0  = blockIdx.x * 128;
    const int o0  = blockIdx.y * 64;
    const int tid = threadIdx.x;
    const int tx = tid & 15, ty = tid >> 4;
    const int lo = tid & 63, lk4 = tid >> 6;
    const int ln4 = tid & 15, lbk = tid >> 4;
    const float* xb = x + (size_t)b * Cc * Nn;

    float acc[4][8];
#pragma unroll
    for (int i = 0; i < 4; ++i)
#pragma unroll
        for (int j = 0; j < 8; ++j) acc[i][j] = 0.f;

    for (int kt = 0; kt < 12; ++kt) {               // c ascending: kt*16 + kk
        const int k0 = kt * 16;
        float4 av = *reinterpret_cast<const float4*>(&w[(size_t)(o0 + lo) * 192 + k0 + lk4 * 4]);
        As[lk4*4+0][lo] = av.x;
        As[lk4*4+1][lo] = av.y;
        As[lk4*4+2][lo] = av.z;
        As[lk4*4+3][lo] = av.w;
        const int na = n0 + ln4 * 4;
        const int nb = n0 + 64 + ln4 * 4;
        float4 b0 = make_float4(0.f, 0.f, 0.f, 0.f);
        float4 b1 = make_float4(0.f, 0.f, 0.f, 0.f);
        if (na < Nn) b0 = *reinterpret_cast<const float4*>(&xb[(size_t)(k0 + lbk) * Nn + na]);
        if (nb < Nn) b1 = *reinterpret_cast<const float4*>(&xb[(size_t)(k0 + lbk) * Nn + nb]);
        *reinterpret_cast<float4*>(&Bs[lbk][ln4*4])      = b0;
        *reinterpret_cast<float4*>(&Bs[lbk][64 + ln4*4]) = b1;
        __syncthreads();
#pragma unroll
        for (int kk = 0; kk < 16; ++kk) {
            float ar[4], br[8];
#pragma unroll
            for (int i = 0; i < 4; ++i) ar[i] = As[kk][ty*4+i];
#pragma unroll
            for (int j = 0; j < 4; ++j) br[j]     = Bs[kk][tx*4+j];
#pragma unroll
            for (int j = 0; j < 4; ++j) br[4 + j] = Bs[kk][64 + tx*4+j];
#pragma unroll
            for (int i = 0; i < 4; ++i)
#pragma unroll
                for (int j = 0; j < 8; ++j)
                    acc[i][j] = __fadd_rn(acc[i][j], __fmul_rn(ar[i], br[j]));
        }
        __syncthreads();
    }
    const int na = n0 + tx * 4;
    const int nb = n0 + 64 + tx * 4;
#pragma unroll
    for (int i = 0; i < 4; ++i) {
        const int o = o0 + ty * 4 + i;
        const float e  = __fadd_rn(vv[o], 1e-5f);
        const float r1 = __fsqrt_rn(e);
        const float rr = __fdiv_rn(1.f, r1);
        const float s  = __fmul_rn(gg[o], rr);
        const size_t rowb = ((size_t)b * Cc + o) * Nn;
        if (na < Nn) {
#pragma unroll
            for (int j = 0; j < 4; ++j) {
                const float h = __fadd_rn(acc[i][j], bias[o]);
                const float t = __fsub_rn(h, mm[o]);
                const float u = __fmul_rn(t, s);
                xt[rowb + na + j] = __fadd_rn(u, bb_[o]);
            }
        }
        if (nb < Nn) {
#pragma unroll
            for (int j = 0; j < 4; ++j) {
                const float h = __fadd_rn(acc[i][4 + j], bias[o]);
                const float t = __fsub_rn(h, mm[o]);
                const float u = __fmul_rn(t, s);
                xt[rowb + nb + j] = __fadd_rn(u, bb_[o]);
            }
        }
    }
}

// norm_np: numpy-exact. BIT-CRITICAL.
__global__ __launch_bounds__(256) void norm_np(
    const float* __restrict__ xt, float* __restrict__ xn, float* __restrict__ sq)
{
    const int idx = blockIdx.x * 256 + threadIdx.x;
    if (idx >= Bn * Nn) return;
    const int n = idx % Nn;
    const int b = idx / Nn;
    const float* p = xt + (size_t)b * Cc * Nn + n;

    float acc = 0.f;
    for (int c = 0; c < Cc; ++c) {
        const float v = p[(size_t)c * Nn];
        acc = __fadd_rn(acc, __fmul_rn(v, v));
    }
    float nrm = __fsqrt_rn(acc);
    nrm = fmaxf(nrm, 1e-12f);

    float* q = xn + (size_t)b * Cc * Nn + n;
    for (int c = 0; c < Cc; ++c)
        q[(size_t)c * Nn] = __fdiv_rn(p[(size_t)c * Nn], nrm);

    float sblk[2];
#pragma unroll
    for (int blk = 0; blk < 2; ++blk) {
        const int base = blk * 96;
        float r[8];
#pragma unroll
        for (int j = 0; j < 8; ++j) {
            const float xv = q[(size_t)(base + j) * Nn];
            r[j] = __fmul_rn(xv, xv);
        }
        for (int i = 8; i < 96; i += 8) {
#pragma unroll
            for (int j = 0; j < 8; ++j) {
                const float xv = q[(size_t)(base + i + j) * Nn];
                r[j] = __fadd_rn(r[j], __fmul_rn(xv, xv));
            }
        }
        sblk[blk] = __fadd_rn(__fadd_rn(__fadd_rn(r[0], r[1]), __fadd_rn(r[2], r[3])),
                              __fadd_rn(__fadd_rn(r[4], r[5]), __fadd_rn(r[6], r[7])));
    }
    sq[idx] = __fadd_rn(sblk[0], sblk[1]);
}

// dist_gemm: symmetric fast filter — only rt<=mt tiles computed; the mirror
// tile is produced by an LDS transpose. dist[b16][r][m] = -dot(xn_r, xn_m).
__global__ __launch_bounds__(256) void dist_gemm(
    const float* __restrict__ xn, float* __restrict__ dist, int bchunk)
{
    __shared__ float As[16][64];
    __shared__ float Bs[16][64];
    __shared__ float Ds[64][65];
    const int bt = blockIdx.x;             // 0..90 (upper-triangle tiles)
    int rt = 0, rem = bt;
    while (rem >= 13 - rt) { rem -= 13 - rt; ++rt; }
    const int mt = rt + rem;
    const int bc = blockIdx.y;             // 0..15
    const int b  = bchunk * 16 + bc;
    const int r0 = rt * 64, m0 = mt * 64;
    const int tid = threadIdx.x;
    const int tx = tid & 15, ty = tid >> 4;
    const int lo = tid & 63, lk4 = tid >> 6;
    const float* xb = xn + (size_t)b * Cc * Nn;

    float acc[4][4];
#pragma unroll
    for (int i = 0; i < 4; ++i)
#pragma unroll
        for (int j = 0; j < 4; ++j) acc[i][j] = 0.f;

    for (int kt = 0; kt < 12; ++kt) {
        const int k0 = kt * 16;
        const int r = r0 + lo, m = m0 + lo;
#pragma unroll
        for (int j = 0; j < 4; ++j) {
            const int kc = k0 + lk4 * 4 + j;
            As[lk4*4+j][lo] = (r < Nn) ? xb[(size_t)kc * Nn + r] : 0.f;
            Bs[lk4*4+j][lo] = (m < Nn) ? xb[(size_t)kc * Nn + m] : 0.f;
        }
        __syncthreads();
#pragma unroll
        for (int kk = 0; kk < 16; ++kk) {
            float4 a  = *reinterpret_cast<const float4*>(&As[kk][ty*4]);
            float4 bq = *reinterpret_cast<const float4*>(&Bs[kk][tx*4]);
            float ar[4] = {a.x, a.y, a.z, a.w};
            float br[4] = {bq.x, bq.y, bq.z, bq.w};
#pragma unroll
            for (int i = 0; i < 4; ++i)
#pragma unroll
                for (int j = 0; j < 4; ++j)
                    acc[i][j] = fmaf(ar[i], br[j], acc[i][j]);
        }
        __syncthreads();
    }
    float* db = dist + (size_t)bc * Nn * Nn;
    {
        const int m = m0 + tx * 4;
        if (m < Nn) {
#pragma unroll
            for (int i = 0; i < 4; ++i) {
                const int r = r0 + ty * 4 + i;
                if (r < Nn) {
                    float4 o = make_float4(-acc[i][0], -acc[i][1], -acc[i][2], -acc[i][3]);
                    *reinterpret_cast<float4*>(&db[(size_t)r * Nn + m]) = o;
                }
            }
        }
    }
    if (rt != mt) {
#pragma unroll
        for (int i = 0; i < 4; ++i)
#pragma unroll
            for (int j = 0; j < 4; ++j)
                Ds[ty*4+i][tx*4+j] = -acc[i][j];
        __syncthreads();
        const int rcol = r0 + tx * 4;      // full r-tiles only when rt<mt<=12
#pragma unroll
        for (int i = 0; i < 4; ++i) {
            const int mrow = m0 + ty * 4 + i;
            if (mrow < Nn) {
                float4 o = make_float4(Ds[tx*4+0][ty*4+i], Ds[tx*4+1][ty*4+i],
                                       Ds[tx*4+2][ty*4+i], Ds[tx*4+3][ty*4+i]);
                *reinterpret_cast<float4*>(&db[(size_t)mrow * Nn + rcol]) = o;
            }
        }
    }
}

// select16: one wave per row; 16x argmin-extract via shfl_xor; writes sorted
// candidate indices AND their fast dists.
__global__ __launch_bounds__(256) void select16(
    const float* __restrict__ dist, int* __restrict__ cand,
    float* __restrict__ cdist, int bchunk)
{
    const int wid = blockIdx.x * 4 + (threadIdx.x >> 6);   // wave id in chunk
    const int L   = threadIdx.x & 63;
    const int r   = wid % Nn;
    const int bc  = wid / Nn;
    const int b   = bchunk * 16 + bc;
    const float* drow = dist + ((size_t)bc * Nn + r) * Nn;

    float v[13];
#pragma unroll
    for (int s = 0; s < 12; ++s) v[s] = drow[s * 64 + L];
    v[12] = (L < 16) ? drow[768 + L] : INFINITY;

    float mv = v[0]; int ms = 0;
#pragma unroll
    for (int s = 1; s < 13; ++s)
        if (v[s] < mv) { mv = v[s]; ms = s; }

    int out[16];
    float vals[16];
#pragma unroll
    for (int k = 0; k < 16; ++k) {
        float gv = mv; int gi = ms * 64 + L;
#pragma unroll
        for (int off = 1; off < 64; off <<= 1) {
            const float ov = __shfl_xor(gv, off, 64);
            const int   oi = __shfl_xor(gi, off, 64);
            if (ov < gv || (ov == gv && oi < gi)) { gv = ov; gi = oi; }
        }
        out[k] = gi; vals[k] = gv;
        const int ol = gi & 63, os = gi >> 6;
        if (L == ol) {
#pragma unroll
            for (int s = 0; s < 13; ++s) if (s == os) v[s] = INFINITY;
            mv = v[0]; ms = 0;
#pragma unroll
            for (int s = 1; s < 13; ++s)
                if (v[s] < mv) { mv = v[s]; ms = s; }
        }
    }
    if (L == 0) {
        int*   op = cand  + ((size_t)b * Nn + r) * 16;
        float* dp = cdist + ((size_t)b * Nn + r) * 16;
#pragma unroll
        for (int k = 0; k < 16; ++k) { op[k] = out[k]; dp[k] = vals[k]; }
    }
}

// zero_cnt: reset the ambiguous-row counter each launch (determinism).
__global__ void zero_cnt(int* cnt) { if (threadIdx.x == 0 && blockIdx.x == 0) *cnt = 0; }

// gap_route: clear-gap rows resolved directly from fast candidates; knife-edge
// rows appended to the ambiguous list.
__global__ __launch_bounds__(256) void gap_route(
    const int* __restrict__ cand, const float* __restrict__ cdist,
    int* __restrict__ nnidx, int* __restrict__ amb, int* __restrict__ cnt)
{
    const int idx = blockIdx.x * 256 + threadIdx.x;
    if (idx >= Bn * Nn) return;
    const float* dp = cdist + (size_t)idx * 16;
    const float d8 = dp[8], d9 = dp[9];
    if (d9 - d8 > GAP_DELTA) {
        const int* cp = cand + (size_t)idx * 16;
        int* op = nnidx + (size_t)idx * Kk;
#pragma unroll
        for (int k = 0; k < Kk; ++k) op[k] = cp[k];
    } else {
        const int pos = atomicAdd(cnt, 1);
        amb[pos] = idx;
    }
}

// refine_amb v2: one BLOCK per ambiguous row. 16 groups x 16 threads; group k
// computes candidate k's products in parallel into LDS; lane j==0 of each
// group runs the BIT-EXACT sequential ascending-c add chain.
__global__ __launch_bounds__(256) void refine_amb(
    const float* __restrict__ xn, const float* __restrict__ sq,
    const int* __restrict__ cand, const int* __restrict__ amb,
    const int* __restrict__ cnt, int* __restrict__ nnidx)
{
    __shared__ float prods[16][200];   // [cand][channel], padded
    __shared__ float Dd[16];
    __shared__ int   Dm[16];
    const int total = *cnt;
    const int k = threadIdx.x >> 4;    // candidate slot
    const int j = threadIdx.x & 15;    // channel segment

    for (int row = blockIdx.x; row < total; row += gridDim.x) {
        const int rowid = amb[row];
        const int b = rowid / Nn, r = rowid % Nn;
        const float* xb  = xn + (size_t)b * Cc * Nn;
        const float* sqb = sq + (size_t)b * Nn;
        const int m = cand[(size_t)rowid * 16 + k];

#pragma unroll
        for (int i = 0; i < 12; ++i) {
            const int c = j * 12 + i;
            prods[k][c] = __fmul_rn(xb[(size_t)c * Nn + r], xb[(size_t)c * Nn + m]);
        }
        __syncthreads();
        if (j == 0) {
            float dot = 0.f;
            for (int c = 0; c < Cc; ++c)          // exact sequential chain
                dot = __fadd_rn(dot, prods[k][c]);
            const float t1 = __fmul_rn(2.f, dot);
            const float t2 = __fsub_rn(sqb[r], t1);
            Dd[k] = __fadd_rn(t2, sqb[m]);
            Dm[k] = m;
        }
        __syncthreads();
        if (threadIdx.x == 0) {
            float dl[16]; int il[16];
#pragma unroll
            for (int q = 0; q < 16; ++q) { dl[q] = Dd[q]; il[q] = Dm[q]; }
            int* op = nnidx + (size_t)rowid * Kk;
            for (int kk = 0; kk < Kk; ++kk) {
                int best = kk;
                for (int q = kk + 1; q < 16; ++q)
                    if (dl[q] < dl[best] || (dl[q] == dl[best] && il[q] < il[best])) best = q;
                float td = dl[kk]; dl[kk] = dl[best]; dl[best] = td;
                int ti = il[kk]; il[kk] = il[best]; il[best] = ti;
                op[kk] = il[kk];
            }
        }
        __syncthreads();
    }
}

// ===========================================================================
// VALUE PATH — fast f32/bf16 (error budget 0.14; bf16 contributes ~0.05)
// ===========================================================================

// mr_pack: st interleave + max-relative, packed bf16, TRANSPOSED layout
// stT[b][n][oc] (oc = 2c interleaved x/mr). Block = 64 n of one batch.
// Two 96-channel passes through a [64][97] u32 LDS tile; coalesced 16B out.
__global__ __launch_bounds__(256) void mr_pack(
    const float* __restrict__ xt, const int* __restrict__ nnidx,
    unsigned int* __restrict__ stT)
{
    __shared__ int idxs[64][10];
    __shared__ unsigned int T32[64][97];
    const int b   = blockIdx.y;
    const int n0  = blockIdx.x * 64;
    const int tid = threadIdx.x;
    const int nl = tid & 63, cq = tid >> 6;

    for (int t = tid; t < 64 * Kk; t += 256) {
        const int nn = t / Kk, k = t % Kk;
        const int n = n0 + nn;
        idxs[nn][k] = (n < Nn) ? nnidx[((size_t)b * Nn + n) * Kk + k] : 0;
    }
    __syncthreads();
    const int n = n0 + nl;
    const float* xb = xt + (size_t)b * Cc * Nn;

    for (int half = 0; half < 2; ++half) {
        const int cbase = half * 96;
        for (int ci = cq; ci < 96; ci += 4) {
            const int c = cbase + ci;
            const float* row = xb + (size_t)c * Nn;
            float ctr = 0.f, mx = 0.f;
            if (n < Nn) {
                ctr = row[n];
                mx = -INFINITY;
#pragma unroll
                for (int k = 0; k < Kk; ++k)
                    mx = fmaxf(mx, __fsub_rn(row[idxs[nl][k]], ctr));
            }
            T32[nl][ci] = (unsigned int)f2bf(ctr) | ((unsigned int)f2bf(mx) << 16);
        }
        __syncthreads();
        for (int t = tid; t < 64 * 24; t += 256) {   // 24 chunks (16B) per row
            const int rr = t / 24, ch = t % 24;
            const int nw = n0 + rr;
            if (nw < Nn) {
                uint4 v;
                v.x = T32[rr][ch*4+0]; v.y = T32[rr][ch*4+1];
                v.z = T32[rr][ch*4+2]; v.w = T32[rr][ch*4+3];
                *reinterpret_cast<uint4*>(
                    &stT[((size_t)b * Nn + nw) * (C2c/2) + cbase + ch*4]) = v;
            }
        }
        __syncthreads();
    }
}

// wcvt: f32 -> bf16 (RNE), generic
__global__ __launch_bounds__(256) void wcvt(
    const float* __restrict__ w, unsigned short* __restrict__ wbf, int nElem)
{
    const int i = blockIdx.x * 256 + threadIdx.x;
    if (i < nElem) wbf[i] = f2bf(w[i]);
}

// gconv_mfma: grouped conv via bf16 MFMA (16x16x32, K=96 in 3 steps)
// + BN2 + exact GELU -> bf16 gT[b][n][oc]. Block = 4 waves = 64 n, one group.
__global__ __launch_bounds__(256) void gconv_mfma(
    const unsigned short* __restrict__ stT, const unsigned short* __restrict__ wbf2,
    const float* __restrict__ gb,
    const float* __restrict__ gg, const float* __restrict__ bb_,
    const float* __restrict__ mm, const float* __restrict__ vv,
    unsigned short* __restrict__ gT)
{
    const int b   = blockIdx.z;
    const int grp = blockIdx.y;
    const int n0  = blockIdx.x * 64;
    const int tid = threadIdx.x;
    const int wv  = tid >> 6;
    const int l   = tid & 63;
    const int lm  = l & 15, lk = l >> 4;

    const int ncol = n0 + wv * 16 + lm;
    const int ncl  = (ncol < Nn) ? ncol : (Nn - 1);
    const unsigned short* gRow = stT + ((size_t)b * Nn + ncl) * C2c + grp * 96;

    f32x4 acc[6];
#pragma unroll
    for (int mf = 0; mf < 6; ++mf) acc[mf] = (f32x4){0.f, 0.f, 0.f, 0.f};

#pragma unroll
    for (int k0 = 0; k0 < 96; k0 += 32) {
        bf16x8 bfr = *reinterpret_cast<const bf16x8*>(&gRow[k0 + lk * 8]);
#pragma unroll
        for (int mf = 0; mf < 6; ++mf) {
            bf16x8 afr = *reinterpret_cast<const bf16x8*>(
                &wbf2[((size_t)grp * 96 + mf * 16 + lm) * 96 + k0 + lk * 8]);
            acc[mf] = __builtin_amdgcn_mfma_f32_16x16x32_bf16(afr, bfr, acc[mf], 0, 0, 0);
        }
    }
    if (ncol < Nn) {
#pragma unroll
        for (int mf = 0; mf < 6; ++mf) {
            unsigned long long pk = 0ull;
#pragma unroll
            for (int r = 0; r < 4; ++r) {
                const int oc = grp * 96 + mf * 16 + lk * 4 + r;   // C/D row
                const float s  = gg[oc] * rsqrtf(vv[oc] + 1e-5f);
                const float sh = (gb[oc] - mm[oc]) * s + bb_[oc];
                float v = fmaf(acc[mf][r], s, sh);
                float ge = 0.5f * v * (1.f + erff(v * 0.70710678118654752f));
                pk |= ((unsigned long long)f2bf(ge)) << (16 * r);
            }
            *reinterpret_cast<unsigned long long*>(
                &gT[((size_t)b * Nn + ncol) * C2c + grp * 96 + mf * 16 + lk * 4]) = pk;
        }
    }
}

// fc2_mfma: out = BN3( g · fc2_w^T ) + x, bf16 MFMA (16x16x32), f32 accum.
__global__ __launch_bounds__(256) void fc2_mfma(
    const unsigned short* __restrict__ gT, const unsigned short* __restrict__ wbf,
    const float* __restrict__ bias,
    const float* __restrict__ gg, const float* __restrict__ bb_,
    const float* __restrict__ mm, const float* __restrict__ vv,
    const float* __restrict__ xres,
    float* __restrict__ out)
{
    const int b   = blockIdx.z;
    const int n0  = blockIdx.x * 64;
    const int o0  = blockIdx.y * 64;
    const int tid = threadIdx.x;
    const int wv  = tid >> 6;
    const int l   = tid & 63;
    const int lm  = l & 15, lk = l >> 4;

    const int ncol = n0 + wv * 16 + lm;
    const int ncl  = (ncol < Nn) ? ncol : (Nn - 1);
    const unsigned short* gRow = gT + ((size_t)b * Nn + ncl) * C2c;

    f32x4 acc[4];
#pragma unroll
    for (int mf = 0; mf < 4; ++mf) acc[mf] = (f32x4){0.f, 0.f, 0.f, 0.f};

    for (int k0 = 0; k0 < C2c; k0 += 32) {
        bf16x8 bfr = *reinterpret_cast<const bf16x8*>(&gRow[k0 + lk * 8]);
#pragma unroll
        for (int mf = 0; mf < 4; ++mf) {
            bf16x8 afr = *reinterpret_cast<const bf16x8*>(
                &wbf[(size_t)(o0 + mf * 16 + lm) * C2c + k0 + lk * 8]);
            acc[mf] = __builtin_amdgcn_mfma_f32_16x16x32_bf16(afr, bfr, acc[mf], 0, 0, 0);
        }
    }
    if (ncol < Nn) {
#pragma unroll
        for (int mf = 0; mf < 4; ++mf) {
#pragma unroll
            for (int r = 0; r < 4; ++r) {
                const int o = o0 + mf * 16 + lk * 4 + r;   // C/D: row=(l>>4)*4+r
                const float s  = gg[o] * rsqrtf(vv[o] + 1e-5f);
                const float sh = (bias[o] - mm[o]) * s + bb_[o];
                const size_t oi = ((size_t)b * Cc + o) * Nn + ncol;  // col=lane&15
                out[oi] = fmaf(acc[mf][r], s, sh) + xres[oi];
            }
        }
    }
}

// ---------------------------------------------------------------------------
extern "C" void kernel_launch(void* const* d_in, const int* in_sizes, int n_in,
                              void* d_out, int out_size, void* d_ws, size_t ws_size,
                              hipStream_t stream)
{
    const float* x     = (const float*)d_in[0];
    const float* fc1_w = (const float*)d_in[1];
    const float* fc1_b = (const float*)d_in[2];
    const float* bn1_g = (const float*)d_in[3];
    const float* bn1_b = (const float*)d_in[4];
    const float* bn1_m = (const float*)d_in[5];
    const float* bn1_v = (const float*)d_in[6];
    const float* gc_w  = (const float*)d_in[7];
    const float* gc_b  = (const float*)d_in[8];
    const float* bn2_g = (const float*)d_in[9];
    const float* bn2_b = (const float*)d_in[10];
    const float* bn2_m = (const float*)d_in[11];
    const float* bn2_v = (const float*)d_in[12];
    const float* fc2_w = (const float*)d_in[13];
    const float* fc2_b = (const float*)d_in[14];
    const float* bn3_g = (const float*)d_in[15];
    const float* bn3_b = (const float*)d_in[16];
    const float* bn3_m = (const float*)d_in[17];
    const float* bn3_v = (const float*)d_in[18];

    float* out = (float*)d_out;                  // xt scratch, overwritten by fc2

    // workspace layout (max concurrent ~156 MB, proven):
    //   region A [0, 77.07M):  dist16 (39.34M, 4 chunks; dies after refine)
    //                          -> stT (bf16 38.5M, born at mr_pack)
    //   region B [77.07, 154.14M):
    //       xn | sq | c16 | cd16 (45.16M; die after refine)
    //       -> gT (bf16 38.5M, born at gconv, aliases xn)
    //       wbf (147KB) @ +45.16M | wbf2 (74KB) after it — never overlapped
    //   region C [154.14M, +): nnidx (1.81M) | amb (0.2M) | cnt
    char* wsb = (char*)d_ws;
    const size_t regionBytes = (size_t)Bn * C2c * Nn * 4;   // 77,070,336
    float* dist = (float*)wsb;
    unsigned int*   stT32 = (unsigned int*)wsb;
    unsigned short* stT   = (unsigned short*)wsb;
    char*  g2   = wsb + regionBytes;
    float* xnb  = (float*)g2;                                      // 38,535,168 B
    float* sqb  = (float*)(g2 + (size_t)Bn * Cc * Nn * 4);         // 200,704 B
    int*   c16  = (int*)(g2 + (size_t)Bn * Cc * Nn * 4 + 200704);  // 3,211,264 B
    float* cd16 = (float*)(g2 + (size_t)Bn * Cc * Nn * 4 + 200704 + 3211264); // 3,211,264 B
    unsigned short* gT   = (unsigned short*)g2;                    // bf16, aliases xn
    unsigned short* wbf  = (unsigned short*)(g2 + 45158912);       // 147,456 B
    unsigned short* wbf2 = (unsigned short*)(g2 + 45158912 + 147456); // 73,728 B
    char*  g3   = wsb + 2 * regionBytes;
    int*   nni  = (int*)g3;                                        // 1,806,336 B
    int*   amb  = (int*)(g3 + 1806336);                            // 200,704 B
    int*   cnt  = (int*)(g3 + 1806336 + 200704);                   // 4 B

    const int nBN = Bn * Nn;

    dim3 blk(256);
    wcvt<<<dim3((Cc * C2c + 255) / 256), blk, 0, stream>>>(fc2_w, wbf, Cc * C2c);
    wcvt<<<dim3((4 * 96 * 96 + 255) / 256), blk, 0, stream>>>(gc_w, wbf2, 4 * 96 * 96);
    fc1_np<<<dim3(7, 3, Bn), blk, 0, stream>>>(
        x, fc1_w, fc1_b, bn1_g, bn1_b, bn1_m, bn1_v, out);
    norm_np<<<dim3((nBN + 255) / 256), blk, 0, stream>>>(out, xnb, sqb);
    for (int ch = 0; ch < 4; ++ch) {
        dist_gemm<<<dim3(91, 16), blk, 0, stream>>>(xnb, dist, ch);
        select16<<<dim3(16 * Nn / 4), blk, 0, stream>>>(dist, c16, cd16, ch);
    }
    zero_cnt<<<dim3(1), dim3(64), 0, stream>>>(cnt);
    gap_route<<<dim3((nBN + 255) / 256), blk, 0, stream>>>(c16, cd16, nni, amb, cnt);
    refine_amb<<<dim3(784), blk, 0, stream>>>(xnb, sqb, c16, amb, cnt, nni);
    mr_pack<<<dim3(13, Bn), blk, 0, stream>>>(out, nni, stT32);
    gconv_mfma<<<dim3(13, 4, Bn), blk, 0, stream>>>(
        stT, wbf2, gc_b, bn2_g, bn2_b, bn2_m, bn2_v, gT);
    fc2_mfma<<<dim3(13, 3, Bn), blk, 0, stream>>>(
        gT, wbf, fc2_b, bn3_g, bn3_b, bn3_m, bn3_v, x, out);
}

// Round 15
// 709.828 us; speedup vs baseline: 1.6442x; 1.0815x over previous
//
#include <hip/hip_runtime.h>
#include <math.h>

static constexpr int Bn  = 64;    // batch
static constexpr int Cc  = 192;   // channels
static constexpr int Nn  = 784;   // H*W
static constexpr int C2c = 384;   // 2C
static constexpr int Kk  = 9;     // knn K
#define GAP_DELTA 1e-4f

typedef __attribute__((ext_vector_type(8))) short bf16x8;
typedef __attribute__((ext_vector_type(4))) float f32x4;

__device__ inline unsigned short f2bf(float f) {   // RNE f32 -> bf16
    unsigned int u = __float_as_uint(f);
    return (unsigned short)((u + 0x7FFFu + ((u >> 16) & 1u)) >> 16);
}

// ===========================================================================
// INDEX PATH — np-f32 bit-exact where values matter (fc1, norm, refine_amb).
// ===========================================================================

// fc1_np: BIT-CRITICAL — numpy-f32-exact (no FMA, ascending-c accumulation).
__global__ __launch_bounds__(256) void fc1_np(
    const float* __restrict__ x, const float* __restrict__ w,
    const float* __restrict__ bias,
    const float* __restrict__ gg, const float* __restrict__ bb_,
    const float* __restrict__ mm, const float* __restrict__ vv,
    float* __restrict__ xt)
{
    __shared__ float As[16][64];
    __shared__ float Bs[16][128];
    const int b   = blockIdx.z;
    const int n0  = blockIdx.x * 128;
    const int o0  = blockIdx.y * 64;
    const int tid = threadIdx.x;
    const int tx = tid & 15, ty = tid >> 4;
    const int lo = tid & 63, lk4 = tid >> 6;
    const int ln4 = tid & 15, lbk = tid >> 4;
    const float* xb = x + (size_t)b * Cc * Nn;

    float acc[4][8];
#pragma unroll
    for (int i = 0; i < 4; ++i)
#pragma unroll
        for (int j = 0; j < 8; ++j) acc[i][j] = 0.f;

    for (int kt = 0; kt < 12; ++kt) {               // c ascending: kt*16 + kk
        const int k0 = kt * 16;
        float4 av = *reinterpret_cast<const float4*>(&w[(size_t)(o0 + lo) * 192 + k0 + lk4 * 4]);
        As[lk4*4+0][lo] = av.x;
        As[lk4*4+1][lo] = av.y;
        As[lk4*4+2][lo] = av.z;
        As[lk4*4+3][lo] = av.w;
        const int na = n0 + ln4 * 4;
        const int nb = n0 + 64 + ln4 * 4;
        float4 b0 = make_float4(0.f, 0.f, 0.f, 0.f);
        float4 b1 = make_float4(0.f, 0.f, 0.f, 0.f);
        if (na < Nn) b0 = *reinterpret_cast<const float4*>(&xb[(size_t)(k0 + lbk) * Nn + na]);
        if (nb < Nn) b1 = *reinterpret_cast<const float4*>(&xb[(size_t)(k0 + lbk) * Nn + nb]);
        *reinterpret_cast<float4*>(&Bs[lbk][ln4*4])      = b0;
        *reinterpret_cast<float4*>(&Bs[lbk][64 + ln4*4]) = b1;
        __syncthreads();
#pragma unroll
        for (int kk = 0; kk < 16; ++kk) {
            float ar[4], br[8];
#pragma unroll
            for (int i = 0; i < 4; ++i) ar[i] = As[kk][ty*4+i];
#pragma unroll
            for (int j = 0; j < 4; ++j) br[j]     = Bs[kk][tx*4+j];
#pragma unroll
            for (int j = 0; j < 4; ++j) br[4 + j] = Bs[kk][64 + tx*4+j];
#pragma unroll
            for (int i = 0; i < 4; ++i)
#pragma unroll
                for (int j = 0; j < 8; ++j)
                    acc[i][j] = __fadd_rn(acc[i][j], __fmul_rn(ar[i], br[j]));
        }
        __syncthreads();
    }
    const int na = n0 + tx * 4;
    const int nb = n0 + 64 + tx * 4;
#pragma unroll
    for (int i = 0; i < 4; ++i) {
        const int o = o0 + ty * 4 + i;
        const float e  = __fadd_rn(vv[o], 1e-5f);
        const float r1 = __fsqrt_rn(e);
        const float rr = __fdiv_rn(1.f, r1);
        const float s  = __fmul_rn(gg[o], rr);
        const size_t rowb = ((size_t)b * Cc + o) * Nn;
        if (na < Nn) {
#pragma unroll
            for (int j = 0; j < 4; ++j) {
                const float h = __fadd_rn(acc[i][j], bias[o]);
                const float t = __fsub_rn(h, mm[o]);
                const float u = __fmul_rn(t, s);
                xt[rowb + na + j] = __fadd_rn(u, bb_[o]);
            }
        }
        if (nb < Nn) {
#pragma unroll
            for (int j = 0; j < 4; ++j) {
                const float h = __fadd_rn(acc[i][4 + j], bias[o]);
                const float t = __fsub_rn(h, mm[o]);
                const float u = __fmul_rn(t, s);
                xt[rowb + nb + j] = __fadd_rn(u, bb_[o]);
            }
        }
    }
}

// norm_np: numpy-exact. BIT-CRITICAL.
__global__ __launch_bounds__(256) void norm_np(
    const float* __restrict__ xt, float* __restrict__ xn, float* __restrict__ sq)
{
    const int idx = blockIdx.x * 256 + threadIdx.x;
    if (idx >= Bn * Nn) return;
    const int n = idx % Nn;
    const int b = idx / Nn;
    const float* p = xt + (size_t)b * Cc * Nn + n;

    float acc = 0.f;
    for (int c = 0; c < Cc; ++c) {
        const float v = p[(size_t)c * Nn];
        acc = __fadd_rn(acc, __fmul_rn(v, v));
    }
    float nrm = __fsqrt_rn(acc);
    nrm = fmaxf(nrm, 1e-12f);

    float* q = xn + (size_t)b * Cc * Nn + n;
    for (int c = 0; c < Cc; ++c)
        q[(size_t)c * Nn] = __fdiv_rn(p[(size_t)c * Nn], nrm);

    float sblk[2];
#pragma unroll
    for (int blk = 0; blk < 2; ++blk) {
        const int base = blk * 96;
        float r[8];
#pragma unroll
        for (int j = 0; j < 8; ++j) {
            const float xv = q[(size_t)(base + j) * Nn];
            r[j] = __fmul_rn(xv, xv);
        }
        for (int i = 8; i < 96; i += 8) {
#pragma unroll
            for (int j = 0; j < 8; ++j) {
                const float xv = q[(size_t)(base + i + j) * Nn];
                r[j] = __fadd_rn(r[j], __fmul_rn(xv, xv));
            }
        }
        sblk[blk] = __fadd_rn(__fadd_rn(__fadd_rn(r[0], r[1]), __fadd_rn(r[2], r[3])),
                              __fadd_rn(__fadd_rn(r[4], r[5]), __fadd_rn(r[6], r[7])));
    }
    sq[idx] = __fadd_rn(sblk[0], sblk[1]);
}

// dist_gemm: symmetric fast filter — only rt<=mt tiles computed; the mirror
// tile is produced by an LDS transpose. dist[b16][r][m] = -dot(xn_r, xn_m).
__global__ __launch_bounds__(256) void dist_gemm(
    const float* __restrict__ xn, float* __restrict__ dist, int bchunk)
{
    __shared__ float As[16][64];
    __shared__ float Bs[16][64];
    __shared__ float Ds[64][65];
    const int bt = blockIdx.x;             // 0..90 (upper-triangle tiles)
    int rt = 0, rem = bt;
    while (rem >= 13 - rt) { rem -= 13 - rt; ++rt; }
    const int mt = rt + rem;
    const int bc = blockIdx.y;             // 0..15
    const int b  = bchunk * 16 + bc;
    const int r0 = rt * 64, m0 = mt * 64;
    const int tid = threadIdx.x;
    const int tx = tid & 15, ty = tid >> 4;
    const int lo = tid & 63, lk4 = tid >> 6;
    const float* xb = xn + (size_t)b * Cc * Nn;

    float acc[4][4];
#pragma unroll
    for (int i = 0; i < 4; ++i)
#pragma unroll
        for (int j = 0; j < 4; ++j) acc[i][j] = 0.f;

    for (int kt = 0; kt < 12; ++kt) {
        const int k0 = kt * 16;
        const int r = r0 + lo, m = m0 + lo;
#pragma unroll
        for (int j = 0; j < 4; ++j) {
            const int kc = k0 + lk4 * 4 + j;
            As[lk4*4+j][lo] = (r < Nn) ? xb[(size_t)kc * Nn + r] : 0.f;
            Bs[lk4*4+j][lo] = (m < Nn) ? xb[(size_t)kc * Nn + m] : 0.f;
        }
        __syncthreads();
#pragma unroll
        for (int kk = 0; kk < 16; ++kk) {
            float4 a  = *reinterpret_cast<const float4*>(&As[kk][ty*4]);
            float4 bq = *reinterpret_cast<const float4*>(&Bs[kk][tx*4]);
            float ar[4] = {a.x, a.y, a.z, a.w};
            float br[4] = {bq.x, bq.y, bq.z, bq.w};
#pragma unroll
            for (int i = 0; i < 4; ++i)
#pragma unroll
                for (int j = 0; j < 4; ++j)
                    acc[i][j] = fmaf(ar[i], br[j], acc[i][j]);
        }
        __syncthreads();
    }
    float* db = dist + (size_t)bc * Nn * Nn;
    {
        const int m = m0 + tx * 4;
        if (m < Nn) {
#pragma unroll
            for (int i = 0; i < 4; ++i) {
                const int r = r0 + ty * 4 + i;
                if (r < Nn) {
                    float4 o = make_float4(-acc[i][0], -acc[i][1], -acc[i][2], -acc[i][3]);
                    *reinterpret_cast<float4*>(&db[(size_t)r * Nn + m]) = o;
                }
            }
        }
    }
    if (rt != mt) {
#pragma unroll
        for (int i = 0; i < 4; ++i)
#pragma unroll
            for (int j = 0; j < 4; ++j)
                Ds[ty*4+i][tx*4+j] = -acc[i][j];
        __syncthreads();
        const int rcol = r0 + tx * 4;      // full r-tiles only when rt<mt<=12
#pragma unroll
        for (int i = 0; i < 4; ++i) {
            const int mrow = m0 + ty * 4 + i;
            if (mrow < Nn) {
                float4 o = make_float4(Ds[tx*4+0][ty*4+i], Ds[tx*4+1][ty*4+i],
                                       Ds[tx*4+2][ty*4+i], Ds[tx*4+3][ty*4+i]);
                *reinterpret_cast<float4*>(&db[(size_t)mrow * Nn + rcol]) = o;
            }
        }
    }
}

// select16: one wave per row; 16x argmin-extract via shfl_xor; writes sorted
// candidate indices AND their fast dists.
__global__ __launch_bounds__(256) void select16(
    const float* __restrict__ dist, int* __restrict__ cand,
    float* __restrict__ cdist, int bchunk)
{
    const int wid = blockIdx.x * 4 + (threadIdx.x >> 6);   // wave id in chunk
    const int L   = threadIdx.x & 63;
    const int r   = wid % Nn;
    const int bc  = wid / Nn;
    const int b   = bchunk * 16 + bc;
    const float* drow = dist + ((size_t)bc * Nn + r) * Nn;

    float v[13];
#pragma unroll
    for (int s = 0; s < 12; ++s) v[s] = drow[s * 64 + L];
    v[12] = (L < 16) ? drow[768 + L] : INFINITY;

    float mv = v[0]; int ms = 0;
#pragma unroll
    for (int s = 1; s < 13; ++s)
        if (v[s] < mv) { mv = v[s]; ms = s; }

    int out[16];
    float vals[16];
#pragma unroll
    for (int k = 0; k < 16; ++k) {
        float gv = mv; int gi = ms * 64 + L;
#pragma unroll
        for (int off = 1; off < 64; off <<= 1) {
            const float ov = __shfl_xor(gv, off, 64);
            const int   oi = __shfl_xor(gi, off, 64);
            if (ov < gv || (ov == gv && oi < gi)) { gv = ov; gi = oi; }
        }
        out[k] = gi; vals[k] = gv;
        const int ol = gi & 63, os = gi >> 6;
        if (L == ol) {
#pragma unroll
            for (int s = 0; s < 13; ++s) if (s == os) v[s] = INFINITY;
            mv = v[0]; ms = 0;
#pragma unroll
            for (int s = 1; s < 13; ++s)
                if (v[s] < mv) { mv = v[s]; ms = s; }
        }
    }
    if (L == 0) {
        int*   op = cand  + ((size_t)b * Nn + r) * 16;
        float* dp = cdist + ((size_t)b * Nn + r) * 16;
#pragma unroll
        for (int k = 0; k < 16; ++k) { op[k] = out[k]; dp[k] = vals[k]; }
    }
}

// zero_cnt: reset the ambiguous-row counter each launch (determinism).
__global__ void zero_cnt(int* cnt) { if (threadIdx.x == 0 && blockIdx.x == 0) *cnt = 0; }

// gap_route: clear-gap rows resolved directly from fast candidates; knife-edge
// rows appended to the ambiguous list.
__global__ __launch_bounds__(256) void gap_route(
    const int* __restrict__ cand, const float* __restrict__ cdist,
    int* __restrict__ nnidx, int* __restrict__ amb, int* __restrict__ cnt)
{
    const int idx = blockIdx.x * 256 + threadIdx.x;
    if (idx >= Bn * Nn) return;
    const float* dp = cdist + (size_t)idx * 16;
    const float d8 = dp[8], d9 = dp[9];
    if (d9 - d8 > GAP_DELTA) {
        const int* cp = cand + (size_t)idx * 16;
        int* op = nnidx + (size_t)idx * Kk;
#pragma unroll
        for (int k = 0; k < Kk; ++k) op[k] = cp[k];
    } else {
        const int pos = atomicAdd(cnt, 1);
        amb[pos] = idx;
    }
}

// refine_amb v2: one BLOCK per ambiguous row. 16 groups x 16 threads; group k
// computes candidate k's products in parallel into LDS; lane j==0 of each
// group runs the BIT-EXACT sequential ascending-c add chain.
__global__ __launch_bounds__(256) void refine_amb(
    const float* __restrict__ xn, const float* __restrict__ sq,
    const int* __restrict__ cand, const int* __restrict__ amb,
    const int* __restrict__ cnt, int* __restrict__ nnidx)
{
    __shared__ float prods[16][200];   // [cand][channel], padded
    __shared__ float Dd[16];
    __shared__ int   Dm[16];
    const int total = *cnt;
    const int k = threadIdx.x >> 4;    // candidate slot
    const int j = threadIdx.x & 15;    // channel segment

    for (int row = blockIdx.x; row < total; row += gridDim.x) {
        const int rowid = amb[row];
        const int b = rowid / Nn, r = rowid % Nn;
        const float* xb  = xn + (size_t)b * Cc * Nn;
        const float* sqb = sq + (size_t)b * Nn;
        const int m = cand[(size_t)rowid * 16 + k];

#pragma unroll
        for (int i = 0; i < 12; ++i) {
            const int c = j * 12 + i;
            prods[k][c] = __fmul_rn(xb[(size_t)c * Nn + r], xb[(size_t)c * Nn + m]);
        }
        __syncthreads();
        if (j == 0) {
            float dot = 0.f;
            for (int c = 0; c < Cc; ++c)          // exact sequential chain
                dot = __fadd_rn(dot, prods[k][c]);
            const float t1 = __fmul_rn(2.f, dot);
            const float t2 = __fsub_rn(sqb[r], t1);
            Dd[k] = __fadd_rn(t2, sqb[m]);
            Dm[k] = m;
        }
        __syncthreads();
        if (threadIdx.x == 0) {
            float dl[16]; int il[16];
#pragma unroll
            for (int q = 0; q < 16; ++q) { dl[q] = Dd[q]; il[q] = Dm[q]; }
            int* op = nnidx + (size_t)rowid * Kk;
            for (int kk = 0; kk < Kk; ++kk) {
                int best = kk;
                for (int q = kk + 1; q < 16; ++q)
                    if (dl[q] < dl[best] || (dl[q] == dl[best] && il[q] < il[best])) best = q;
                float td = dl[kk]; dl[kk] = dl[best]; dl[best] = td;
                int ti = il[kk]; il[kk] = il[best]; il[best] = ti;
                op[kk] = il[kk];
            }
        }
        __syncthreads();
    }
}

// ===========================================================================
// VALUE PATH — fast f32/bf16 (error budget 0.14; bf16 contributes ~0.05)
// ===========================================================================

// mr_pack v3: block = (b, 16-channel chunk). Stage the 16 full xt rows in LDS
// (50KB) so the 9-neighbor gather never touches HBM; each xt element is read
// exactly ONCE. Packed (x,mr) u32 written as one 64B line per (n,chunk).
__global__ __launch_bounds__(256) void mr_pack(
    const float* __restrict__ xt, const int* __restrict__ nnidx,
    unsigned int* __restrict__ stT)
{
    __shared__ float rows[16][784];
    const int b   = blockIdx.y;
    const int c0  = blockIdx.x * 16;
    const int tid = threadIdx.x;
    const float* xb = xt + ((size_t)b * Cc + c0) * Nn;

#pragma unroll
    for (int c = 0; c < 16; ++c)
        for (int n = tid; n < Nn; n += 256)
            rows[c][n] = xb[(size_t)c * Nn + n];
    __syncthreads();

    for (int n = tid; n < Nn; n += 256) {
        const int* ip = nnidx + ((size_t)b * Nn + n) * Kk;
        int idx[Kk];
#pragma unroll
        for (int k = 0; k < Kk; ++k) idx[k] = ip[k];
        unsigned int pk[16];
#pragma unroll
        for (int c = 0; c < 16; ++c) {
            const float ctr = rows[c][n];
            float mx = -INFINITY;
#pragma unroll
            for (int k = 0; k < Kk; ++k)
                mx = fmaxf(mx, __fsub_rn(rows[c][idx[k]], ctr));
            pk[c] = (unsigned int)f2bf(ctr) | ((unsigned int)f2bf(mx) << 16);
        }
        unsigned int* dst = stT + ((size_t)b * Nn + n) * (C2c / 2) + c0;
#pragma unroll
        for (int q = 0; q < 4; ++q) {
            uint4 v = make_uint4(pk[q*4+0], pk[q*4+1], pk[q*4+2], pk[q*4+3]);
            *reinterpret_cast<uint4*>(&dst[q * 4]) = v;
        }
    }
}

// wcvt: f32 -> bf16 (RNE), generic
__global__ __launch_bounds__(256) void wcvt(
    const float* __restrict__ w, unsigned short* __restrict__ wbf, int nElem)
{
    const int i = blockIdx.x * 256 + threadIdx.x;
    if (i < nElem) wbf[i] = f2bf(w[i]);
}

// gconv_mfma: grouped conv via bf16 MFMA (16x16x32, K=96 in 3 steps)
// + BN2 + exact GELU -> bf16 gT[b][n][oc]. Block = 4 waves = 64 n, one group.
__global__ __launch_bounds__(256) void gconv_mfma(
    const unsigned short* __restrict__ stT, const unsigned short* __restrict__ wbf2,
    const float* __restrict__ gb,
    const float* __restrict__ gg, const float* __restrict__ bb_,
    const float* __restrict__ mm, const float* __restrict__ vv,
    unsigned short* __restrict__ gT)
{
    const int b   = blockIdx.z;
    const int grp = blockIdx.y;
    const int n0  = blockIdx.x * 64;
    const int tid = threadIdx.x;
    const int wv  = tid >> 6;
    const int l   = tid & 63;
    const int lm  = l & 15, lk = l >> 4;

    const int ncol = n0 + wv * 16 + lm;
    const int ncl  = (ncol < Nn) ? ncol : (Nn - 1);
    const unsigned short* gRow = stT + ((size_t)b * Nn + ncl) * C2c + grp * 96;

    f32x4 acc[6];
#pragma unroll
    for (int mf = 0; mf < 6; ++mf) acc[mf] = (f32x4){0.f, 0.f, 0.f, 0.f};

#pragma unroll
    for (int k0 = 0; k0 < 96; k0 += 32) {
        bf16x8 bfr = *reinterpret_cast<const bf16x8*>(&gRow[k0 + lk * 8]);
#pragma unroll
        for (int mf = 0; mf < 6; ++mf) {
            bf16x8 afr = *reinterpret_cast<const bf16x8*>(
                &wbf2[((size_t)grp * 96 + mf * 16 + lm) * 96 + k0 + lk * 8]);
            acc[mf] = __builtin_amdgcn_mfma_f32_16x16x32_bf16(afr, bfr, acc[mf], 0, 0, 0);
        }
    }
    if (ncol < Nn) {
#pragma unroll
        for (int mf = 0; mf < 6; ++mf) {
            unsigned long long pk = 0ull;
#pragma unroll
            for (int r = 0; r < 4; ++r) {
                const int oc = grp * 96 + mf * 16 + lk * 4 + r;   // C/D row
                const float s  = gg[oc] * rsqrtf(vv[oc] + 1e-5f);
                const float sh = (gb[oc] - mm[oc]) * s + bb_[oc];
                float v = fmaf(acc[mf][r], s, sh);
                float ge = 0.5f * v * (1.f + erff(v * 0.70710678118654752f));
                pk |= ((unsigned long long)f2bf(ge)) << (16 * r);
            }
            *reinterpret_cast<unsigned long long*>(
                &gT[((size_t)b * Nn + ncol) * C2c + grp * 96 + mf * 16 + lk * 4]) = pk;
        }
    }
}

// fc2_mfma: out = BN3( g · fc2_w^T ) + x, bf16 MFMA (16x16x32), f32 accum.
__global__ __launch_bounds__(256) void fc2_mfma(
    const unsigned short* __restrict__ gT, const unsigned short* __restrict__ wbf,
    const float* __restrict__ bias,
    const float* __restrict__ gg, const float* __restrict__ bb_,
    const float* __restrict__ mm, const float* __restrict__ vv,
    const float* __restrict__ xres,
    float* __restrict__ out)
{
    const int b   = blockIdx.z;
    const int n0  = blockIdx.x * 64;
    const int o0  = blockIdx.y * 64;
    const int tid = threadIdx.x;
    const int wv  = tid >> 6;
    const int l   = tid & 63;
    const int lm  = l & 15, lk = l >> 4;

    const int ncol = n0 + wv * 16 + lm;
    const int ncl  = (ncol < Nn) ? ncol : (Nn - 1);
    const unsigned short* gRow = gT + ((size_t)b * Nn + ncl) * C2c;

    f32x4 acc[4];
#pragma unroll
    for (int mf = 0; mf < 4; ++mf) acc[mf] = (f32x4){0.f, 0.f, 0.f, 0.f};

    for (int k0 = 0; k0 < C2c; k0 += 32) {
        bf16x8 bfr = *reinterpret_cast<const bf16x8*>(&gRow[k0 + lk * 8]);
#pragma unroll
        for (int mf = 0; mf < 4; ++mf) {
            bf16x8 afr = *reinterpret_cast<const bf16x8*>(
                &wbf[(size_t)(o0 + mf * 16 + lm) * C2c + k0 + lk * 8]);
            acc[mf] = __builtin_amdgcn_mfma_f32_16x16x32_bf16(afr, bfr, acc[mf], 0, 0, 0);
        }
    }
    if (ncol < Nn) {
#pragma unroll
        for (int mf = 0; mf < 4; ++mf) {
#pragma unroll
            for (int r = 0; r < 4; ++r) {
                const int o = o0 + mf * 16 + lk * 4 + r;   // C/D: row=(l>>4)*4+r
                const float s  = gg[o] * rsqrtf(vv[o] + 1e-5f);
                const float sh = (bias[o] - mm[o]) * s + bb_[o];
                const size_t oi = ((size_t)b * Cc + o) * Nn + ncol;  // col=lane&15
                out[oi] = fmaf(acc[mf][r], s, sh) + xres[oi];
            }
        }
    }
}

// ---------------------------------------------------------------------------
extern "C" void kernel_launch(void* const* d_in, const int* in_sizes, int n_in,
                              void* d_out, int out_size, void* d_ws, size_t ws_size,
                              hipStream_t stream)
{
    const float* x     = (const float*)d_in[0];
    const float* fc1_w = (const float*)d_in[1];
    const float* fc1_b = (const float*)d_in[2];
    const float* bn1_g = (const float*)d_in[3];
    const float* bn1_b = (const float*)d_in[4];
    const float* bn1_m = (const float*)d_in[5];
    const float* bn1_v = (const float*)d_in[6];
    const float* gc_w  = (const float*)d_in[7];
    const float* gc_b  = (const float*)d_in[8];
    const float* bn2_g = (const float*)d_in[9];
    const float* bn2_b = (const float*)d_in[10];
    const float* bn2_m = (const float*)d_in[11];
    const float* bn2_v = (const float*)d_in[12];
    const float* fc2_w = (const float*)d_in[13];
    const float* fc2_b = (const float*)d_in[14];
    const float* bn3_g = (const float*)d_in[15];
    const float* bn3_b = (const float*)d_in[16];
    const float* bn3_m = (const float*)d_in[17];
    const float* bn3_v = (const float*)d_in[18];

    float* out = (float*)d_out;                  // xt scratch, overwritten by fc2

    // workspace layout (max concurrent ~156 MB, proven):
    //   region A [0, 77.07M):  dist16 (39.34M, 4 chunks; dies after refine)
    //                          -> stT (bf16 38.5M, born at mr_pack)
    //   region B [77.07, 154.14M):
    //       xn | sq | c16 | cd16 (45.16M; die after refine)
    //       -> gT (bf16 38.5M, born at gconv, aliases xn)
    //       wbf (147KB) @ +45.16M | wbf2 (74KB) after it — never overlapped
    //   region C [154.14M, +): nnidx (1.81M) | amb (0.2M) | cnt
    char* wsb = (char*)d_ws;
    const size_t regionBytes = (size_t)Bn * C2c * Nn * 4;   // 77,070,336
    float* dist = (float*)wsb;
    unsigned int*   stT32 = (unsigned int*)wsb;
    unsigned short* stT   = (unsigned short*)wsb;
    char*  g2   = wsb + regionBytes;
    float* xnb  = (float*)g2;                                      // 38,535,168 B
    float* sqb  = (float*)(g2 + (size_t)Bn * Cc * Nn * 4);         // 200,704 B
    int*   c16  = (int*)(g2 + (size_t)Bn * Cc * Nn * 4 + 200704);  // 3,211,264 B
    float* cd16 = (float*)(g2 + (size_t)Bn * Cc * Nn * 4 + 200704 + 3211264); // 3,211,264 B
    unsigned short* gT   = (unsigned short*)g2;                    // bf16, aliases xn
    unsigned short* wbf  = (unsigned short*)(g2 + 45158912);       // 147,456 B
    unsigned short* wbf2 = (unsigned short*)(g2 + 45158912 + 147456); // 73,728 B
    char*  g3   = wsb + 2 * regionBytes;
    int*   nni  = (int*)g3;                                        // 1,806,336 B
    int*   amb  = (int*)(g3 + 1806336);                            // 200,704 B
    int*   cnt  = (int*)(g3 + 1806336 + 200704);                   // 4 B

    const int nBN = Bn * Nn;

    dim3 blk(256);
    wcvt<<<dim3((Cc * C2c + 255) / 256), blk, 0, stream>>>(fc2_w, wbf, Cc * C2c);
    wcvt<<<dim3((4 * 96 * 96 + 255) / 256), blk, 0, stream>>>(gc_w, wbf2, 4 * 96 * 96);
    fc1_np<<<dim3(7, 3, Bn), blk, 0, stream>>>(
        x, fc1_w, fc1_b, bn1_g, bn1_b, bn1_m, bn1_v, out);
    norm_np<<<dim3((nBN + 255) / 256), blk, 0, stream>>>(out, xnb, sqb);
    for (int ch = 0; ch < 4; ++ch) {
        dist_gemm<<<dim3(91, 16), blk, 0, stream>>>(xnb, dist, ch);
        select16<<<dim3(16 * Nn / 4), blk, 0, stream>>>(dist, c16, cd16, ch);
    }
    zero_cnt<<<dim3(1), dim3(64), 0, stream>>>(cnt);
    gap_route<<<dim3((nBN + 255) / 256), blk, 0, stream>>>(c16, cd16, nni, amb, cnt);
    refine_amb<<<dim3(784), blk, 0, stream>>>(xnb, sqb, c16, amb, cnt, nni);
    mr_pack<<<dim3(12, Bn), blk, 0, stream>>>(out, nni, stT32);
    gconv_mfma<<<dim3(13, 4, Bn), blk, 0, stream>>>(
        stT, wbf2, gc_b, bn2_g, bn2_b, bn2_m, bn2_v, gT);
    fc2_mfma<<<dim3(13, 3, Bn), blk, 0, stream>>>(
        gT, wbf, fc2_b, bn3_g, bn3_b, bn3_m, bn3_v, x, out);
}